// Round 1
// baseline (866.053 us; speedup 1.0000x reference)
//
#include <hip/hip_runtime.h>
#include <hip/hip_bf16.h>

#define HIDDIM 128

// ---------------- degree count (int atomics over dst) ----------------
__global__ __launch_bounds__(256) void deg_kernel(const int* __restrict__ ei, int E,
                                                  int* __restrict__ deg) {
    int gid = blockIdx.x * 256 + threadIdx.x;
    if (gid < E) atomicAdd(&deg[ei[E + gid]], 1);
}

// ---------------- single-block exclusive scan over deg -> rowptr, cursor ----------------
__global__ __launch_bounds__(1024) void scan_kernel(const int* __restrict__ deg, int n,
                                                    int* __restrict__ rowptr,
                                                    int* __restrict__ cursor) {
    __shared__ int lds[1024];
    int t = threadIdx.x;
    int chunk = (n + 1023) / 1024;
    int s = t * chunk, e = min(s + chunk, n);
    int sum = 0;
    for (int i = s; i < e; ++i) sum += deg[i];
    lds[t] = sum;
    __syncthreads();
    for (int off = 1; off < 1024; off <<= 1) {
        int v = (t >= off) ? lds[t - off] : 0;
        __syncthreads();
        lds[t] += v;
        __syncthreads();
    }
    int run = lds[t] - sum;  // exclusive prefix of this thread's chunk
    for (int i = s; i < e; ++i) {
        rowptr[i] = run; cursor[i] = run; run += deg[i];
    }
    if (t == 1023) rowptr[n] = lds[1023];
}

// ---------------- dinv = 1/sqrt(deg+1) ----------------
__global__ __launch_bounds__(256) void dinv_kernel(const int* __restrict__ deg, int n,
                                                   float* __restrict__ dinv) {
    int gid = blockIdx.x * 256 + threadIdx.x;
    if (gid < n) dinv[gid] = 1.0f / sqrtf((float)deg[gid] + 1.0f);
}

// ---------------- bin edges into CSR slots ----------------
__global__ __launch_bounds__(256) void bin_kernel(const int* __restrict__ ei, int E,
                                                  int* __restrict__ cursor,
                                                  int* __restrict__ csr_src) {
    int gid = blockIdx.x * 256 + threadIdx.x;
    if (gid < E) {
        int src = ei[gid];
        int dst = ei[E + gid];
        int pos = atomicAdd(&cursor[dst], 1);
        csr_src[pos] = src;
    }
}

// ---------------- transpose the 4 weight matrices: Wt[m][k][o] = W[m][o][k] ----------------
__global__ __launch_bounds__(256) void transpose_w(const float* __restrict__ Win,
                                                   const float* __restrict__ Wc,
                                                   float* __restrict__ Wt) {
    int gid = blockIdx.x * 256 + threadIdx.x;
    if (gid >= 4 * 16384) return;
    int m = gid >> 14;
    int r = gid & 16383;
    int k = r >> 7, o = r & 127;
    const float* src = (m == 0) ? Win : (Wc + (m - 1) * 16384);
    Wt[gid] = src[o * 128 + k];
}

// ---------------- fp32 GEMM: C[n][128] = A[n][128] @ Wt (Wt is [k][o]) (+bias) ----------------
// Block = 256 threads, 32 nodes/block. K chunked by 64 to keep LDS at ~42KB (3 blocks/CU).
// Thread (colg = tid&15, np = tid>>4) computes nodes {2np, 2np+1} x cols {4c..4c+3, 64+4c..}.
// sA stride 72: bank=(8n+k)%32 -> 2 distinct addrs/bank across the 8 node rows of a wave = free.
// sW float4 reads at col 4c (16 lanes x 16B contiguous 256B) = 2 lanes/bank = free.
__global__ __launch_bounds__(256) void gemm128(const float* __restrict__ A,
                                               const float* __restrict__ Wt,
                                               const float* __restrict__ bias,
                                               float* __restrict__ C, int n, int use_bias) {
    __shared__ float sW[64 * 128];
    __shared__ float sA[32 * 72];
    int tid = threadIdx.x;
    int colg = tid & 15;
    int np = tid >> 4;
    int base = blockIdx.x * 32;

    float4 acc00 = make_float4(0, 0, 0, 0), acc01 = make_float4(0, 0, 0, 0);
    float4 acc10 = make_float4(0, 0, 0, 0), acc11 = make_float4(0, 0, 0, 0);

    for (int kc = 0; kc < 2; ++kc) {
        const float4* Wg = (const float4*)(Wt + kc * 64 * 128);
        float4* sW4 = (float4*)sW;
#pragma unroll
        for (int i = 0; i < 8; ++i) sW4[tid + i * 256] = Wg[tid + i * 256];
#pragma unroll
        for (int i = 0; i < 2; ++i) {
            int f = tid * 2 + i;           // 0..511 float4 slots of the A chunk
            int row = f >> 4, kq = f & 15; // 32 rows x 16 float4 (64 k)
            int gn = base + row;
            float4 v = make_float4(0, 0, 0, 0);
            if (gn < n) v = *(const float4*)(A + (size_t)gn * 128 + kc * 64 + kq * 4);
            *(float4*)(sA + row * 72 + kq * 4) = v;
        }
        __syncthreads();
#pragma unroll
        for (int k = 0; k < 64; ++k) {
            float a0 = sA[(np * 2 + 0) * 72 + k];
            float a1 = sA[(np * 2 + 1) * 72 + k];
            float4 w0 = *(const float4*)(sW + k * 128 + colg * 4);
            float4 w1 = *(const float4*)(sW + k * 128 + 64 + colg * 4);
            acc00.x += a0 * w0.x; acc00.y += a0 * w0.y; acc00.z += a0 * w0.z; acc00.w += a0 * w0.w;
            acc01.x += a0 * w1.x; acc01.y += a0 * w1.y; acc01.z += a0 * w1.z; acc01.w += a0 * w1.w;
            acc10.x += a1 * w0.x; acc10.y += a1 * w0.y; acc10.z += a1 * w0.z; acc10.w += a1 * w0.w;
            acc11.x += a1 * w1.x; acc11.y += a1 * w1.y; acc11.z += a1 * w1.z; acc11.w += a1 * w1.w;
        }
        __syncthreads();
    }
    if (use_bias) {
        float4 b0 = *(const float4*)(bias + colg * 4);
        float4 b1v = *(const float4*)(bias + 64 + colg * 4);
        acc00.x += b0.x; acc00.y += b0.y; acc00.z += b0.z; acc00.w += b0.w;
        acc10.x += b0.x; acc10.y += b0.y; acc10.z += b0.z; acc10.w += b0.w;
        acc01.x += b1v.x; acc01.y += b1v.y; acc01.z += b1v.z; acc01.w += b1v.w;
        acc11.x += b1v.x; acc11.y += b1v.y; acc11.z += b1v.z; acc11.w += b1v.w;
    }
    int gn0 = base + np * 2;
    if (gn0 < n) {
        *(float4*)(C + (size_t)gn0 * 128 + colg * 4) = acc00;
        *(float4*)(C + (size_t)gn0 * 128 + 64 + colg * 4) = acc01;
    }
    if (gn0 + 1 < n) {
        *(float4*)(C + (size_t)(gn0 + 1) * 128 + colg * 4) = acc10;
        *(float4*)(C + (size_t)(gn0 + 1) * 128 + 64 + colg * 4) = acc11;
    }
}

// ---------------- fused CSR gather + self-loop + bias + LayerNorm + ReLU + residual ----------------
// One wave per node; lane holds cols {2*lane, 2*lane+1}. h updated in place.
__global__ __launch_bounds__(256) void gather_ln(const float* __restrict__ hw,
                                                 float* __restrict__ h,
                                                 const int* __restrict__ rowptr,
                                                 const int* __restrict__ csr_src,
                                                 const float* __restrict__ dinv,
                                                 const float* __restrict__ bc,
                                                 const float* __restrict__ gamma,
                                                 const float* __restrict__ beta, int n) {
    int wid = (blockIdx.x * 256 + threadIdx.x) >> 6;
    int lane = threadIdx.x & 63;
    if (wid >= n) return;
    int i = wid;
    float di = dinv[i];
    int e0 = rowptr[i], e1 = rowptr[i + 1];
    int c0 = lane * 2;

    // s = hw[i]*di + sum_e hw[src]*dinv[src];  agg = di*s + bc
    float2 s = *(const float2*)(hw + (size_t)i * HIDDIM + c0);
    s.x *= di; s.y *= di;
    for (int e = e0; e < e1; ++e) {
        int src = csr_src[e];
        float w = dinv[src];
        float2 v = *(const float2*)(hw + (size_t)src * HIDDIM + c0);
        s.x += v.x * w; s.y += v.y * w;
    }
    float2 bcv = *(const float2*)(bc + c0);
    float vx = di * s.x + bcv.x;
    float vy = di * s.y + bcv.y;

    float s1 = vx + vy, s2 = vx * vx + vy * vy;
#pragma unroll
    for (int off = 32; off; off >>= 1) {
        s1 += __shfl_xor(s1, off);
        s2 += __shfl_xor(s2, off);
    }
    float mu = s1 * (1.0f / 128.0f);
    float var = s2 * (1.0f / 128.0f) - mu * mu;
    float rs = 1.0f / sqrtf(var + 1e-5f);

    float2 gm = *(const float2*)(gamma + c0);
    float2 bt = *(const float2*)(beta + c0);
    float yx = fmaxf((vx - mu) * rs * gm.x + bt.x, 0.0f);
    float yy = fmaxf((vy - mu) * rs * gm.y + bt.y, 0.0f);

    float2 hv = *(float2*)(h + (size_t)i * HIDDIM + c0);
    hv.x += yx; hv.y += yy;
    *(float2*)(h + (size_t)i * HIDDIM + c0) = hv;
}

// ---------------- mean-pool via atomics ----------------
__global__ __launch_bounds__(256) void pool_kernel(const float* __restrict__ h,
                                                   const int* __restrict__ batch,
                                                   float* __restrict__ pooled,
                                                   float* __restrict__ counts, int n) {
    int gid = blockIdx.x * 256 + threadIdx.x;
    int node = gid >> 5, q = gid & 31;
    if (node >= n) return;
    int b = batch[node];
    float4 v = *(const float4*)(h + (size_t)node * HIDDIM + q * 4);
    float* p = pooled + (size_t)b * HIDDIM + q * 4;
    atomicAdd(p + 0, v.x); atomicAdd(p + 1, v.y);
    atomicAdd(p + 2, v.z); atomicAdd(p + 3, v.w);
    if (q == 0) atomicAdd(&counts[b], 1.0f);
}

// ---------------- final MLP: one wave per graph ----------------
__global__ __launch_bounds__(64) void mlp_kernel(const float* __restrict__ pooled,
                                                 const float* __restrict__ counts,
                                                 const float* __restrict__ W1,
                                                 const float* __restrict__ b1,
                                                 const float* __restrict__ W2,
                                                 const float* __restrict__ b2,
                                                 float* __restrict__ out, int G) {
    int g = blockIdx.x;
    if (g >= G) return;
    int j = threadIdx.x;  // 0..63 hidden units
    float scale = 1.0f / fmaxf(counts[g], 1.0f);
    const float* pr = pooled + (size_t)g * HIDDIM;
    const float* wr = W1 + j * HIDDIM;
    float acc = 0.0f;
#pragma unroll 8
    for (int k = 0; k < HIDDIM; k += 4) {
        float4 p = *(const float4*)(pr + k);
        float4 w = *(const float4*)(wr + k);
        acc += p.x * w.x + p.y * w.y + p.z * w.z + p.w * w.w;
    }
    float h1 = fmaxf(acc * scale + b1[j], 0.0f);
    float c = h1 * W2[j];
#pragma unroll
    for (int off = 32; off; off >>= 1) c += __shfl_xor(c, off);
    if (j == 0) out[g] = c + b2[0];
}

extern "C" void kernel_launch(void* const* d_in, const int* in_sizes, int n_in,
                              void* d_out, int out_size, void* d_ws, size_t ws_size,
                              hipStream_t stream) {
    const float* x      = (const float*)d_in[0];
    const int*   ei     = (const int*)d_in[1];
    const int*   batch  = (const int*)d_in[2];
    const float* W_in   = (const float*)d_in[3];
    const float* b_in   = (const float*)d_in[4];
    const float* Wc     = (const float*)d_in[5];
    const float* bc     = (const float*)d_in[6];
    const float* gamma  = (const float*)d_in[7];
    const float* beta   = (const float*)d_in[8];
    const float* W1     = (const float*)d_in[9];
    const float* b1     = (const float*)d_in[10];
    const float* W2     = (const float*)d_in[11];
    const float* b2     = (const float*)d_in[12];
    float* out = (float*)d_out;

    const int N = in_sizes[2];
    const int E = in_sizes[1] / 2;
    const int G = out_size;  // OUT_DIM == 1

    // workspace carve-up (256B aligned)
    char* ws = (char*)d_ws;
    size_t off = 0;
    auto alloc = [&](size_t bytes) {
        size_t o = off;
        off = (off + bytes + 255) & ~(size_t)255;
        return o;
    };
    int*   deg     = (int*)(ws + alloc((size_t)N * 4));
    int*   rowptr  = (int*)(ws + alloc((size_t)(N + 1) * 4));
    int*   cursor  = (int*)(ws + alloc((size_t)N * 4));
    int*   csr_src = (int*)(ws + alloc((size_t)E * 4));
    float* dinv    = (float*)(ws + alloc((size_t)N * 4));
    float* Wt      = (float*)(ws + alloc((size_t)4 * 16384 * 4));
    float* h       = (float*)(ws + alloc((size_t)N * 128 * 4));
    float* hw      = (float*)(ws + alloc((size_t)N * 128 * 4));
    float* pooled  = (float*)(ws + alloc((size_t)G * 128 * 4));
    float* counts  = (float*)(ws + alloc((size_t)G * 4));
    (void)ws_size; (void)n_in;

    // ---- graph preprocessing (per-call: ws is re-poisoned each launch) ----
    hipMemsetAsync(deg, 0, (size_t)N * 4, stream);
    deg_kernel<<<(E + 255) / 256, 256, 0, stream>>>(ei, E, deg);
    scan_kernel<<<1, 1024, 0, stream>>>(deg, N, rowptr, cursor);
    dinv_kernel<<<(N + 255) / 256, 256, 0, stream>>>(deg, N, dinv);
    bin_kernel<<<(E + 255) / 256, 256, 0, stream>>>(ei, E, cursor, csr_src);
    transpose_w<<<(4 * 16384 + 255) / 256, 256, 0, stream>>>(W_in, Wc, Wt);

    // ---- input projection ----
    int gblocks = (N + 31) / 32;
    gemm128<<<gblocks, 256, 0, stream>>>(x, Wt, b_in, h, N, 1);

    // ---- 3 GCN layers ----
    for (int l = 0; l < 3; ++l) {
        gemm128<<<gblocks, 256, 0, stream>>>(h, Wt + (1 + l) * 16384, nullptr, hw, N, 0);
        gather_ln<<<(N + 3) / 4, 256, 0, stream>>>(hw, h, rowptr, csr_src, dinv,
                                                   bc + l * 128, gamma + l * 128,
                                                   beta + l * 128, N);
    }

    // ---- pooling + MLP head ----
    hipMemsetAsync(pooled, 0, (size_t)G * 128 * 4, stream);
    hipMemsetAsync(counts, 0, (size_t)G * 4, stream);
    pool_kernel<<<((size_t)N * 32 + 255) / 256, 256, 0, stream>>>(h, batch, pooled, counts, N);
    mlp_kernel<<<G, 64, 0, stream>>>(pooled, counts, W1, b1, W2, b2, out, G);
}

// Round 2
// 735.976 us; speedup vs baseline: 1.1767x; 1.1767x over previous
//
#include <hip/hip_runtime.h>
#include <hip/hip_bf16.h>

#define HIDDIM 128

// ---------------- degree count (int atomics over dst) ----------------
__global__ __launch_bounds__(256) void deg_kernel(const int* __restrict__ ei, int E,
                                                  int* __restrict__ deg) {
    int gid = blockIdx.x * 256 + threadIdx.x;
    if (gid < E) atomicAdd(&deg[ei[E + gid]], 1);
}

// ---------------- single-block exclusive scan over deg -> rowptr, cursor ----------------
__global__ __launch_bounds__(1024) void scan_kernel(const int* __restrict__ deg, int n,
                                                    int* __restrict__ rowptr,
                                                    int* __restrict__ cursor) {
    __shared__ int lds[1024];
    int t = threadIdx.x;
    int chunk = (n + 1023) / 1024;
    int s = t * chunk, e = min(s + chunk, n);
    int sum = 0;
    for (int i = s; i < e; ++i) sum += deg[i];
    lds[t] = sum;
    __syncthreads();
    for (int off = 1; off < 1024; off <<= 1) {
        int v = (t >= off) ? lds[t - off] : 0;
        __syncthreads();
        lds[t] += v;
        __syncthreads();
    }
    int run = lds[t] - sum;  // exclusive prefix of this thread's chunk
    for (int i = s; i < e; ++i) {
        rowptr[i] = run; cursor[i] = run; run += deg[i];
    }
    if (t == 1023) rowptr[n] = lds[1023];
}

// ---------------- dinv = 1/sqrt(deg+1) ----------------
__global__ __launch_bounds__(256) void dinv_kernel(const int* __restrict__ deg, int n,
                                                   float* __restrict__ dinv) {
    int gid = blockIdx.x * 256 + threadIdx.x;
    if (gid < n) dinv[gid] = 1.0f / sqrtf((float)deg[gid] + 1.0f);
}

// ---------------- bin edges into CSR slots ----------------
__global__ __launch_bounds__(256) void bin_kernel(const int* __restrict__ ei, int E,
                                                  int* __restrict__ cursor,
                                                  int* __restrict__ csr_src) {
    int gid = blockIdx.x * 256 + threadIdx.x;
    if (gid < E) {
        int src = ei[gid];
        int dst = ei[E + gid];
        int pos = atomicAdd(&cursor[dst], 1);
        csr_src[pos] = src;
    }
}

// ---------------- graph_ptr from sorted batch: gp[g] = first node with batch >= g ----------------
__global__ __launch_bounds__(256) void graph_ptr_kernel(const int* __restrict__ batch, int n,
                                                        int G, int* __restrict__ gp) {
    int i = blockIdx.x * 256 + threadIdx.x;
    if (i >= n) return;
    int bi = batch[i];
    if (i == 0) {
        for (int g = 0; g <= bi; ++g) gp[g] = 0;
    } else {
        int bp = batch[i - 1];
        for (int g = bp + 1; g <= bi; ++g) gp[g] = i;
    }
    if (i == n - 1) {
        for (int g = bi + 1; g <= G; ++g) gp[g] = n;
    }
}

// ---------------- transpose the 4 weight matrices: Wt[m][k][o] = W[m][o][k] ----------------
__global__ __launch_bounds__(256) void transpose_w(const float* __restrict__ Win,
                                                   const float* __restrict__ Wc,
                                                   float* __restrict__ Wt) {
    int gid = blockIdx.x * 256 + threadIdx.x;
    if (gid >= 4 * 16384) return;
    int m = gid >> 14;
    int r = gid & 16383;
    int k = r >> 7, o = r & 127;
    const float* src = (m == 0) ? Win : (Wc + (m - 1) * 16384);
    Wt[gid] = src[o * 128 + k];
}

// ---------------- fp32 GEMM: C[n][128] = A[n][128] @ Wt (Wt is [k][o]) (+bias) ----------------
// Block = 256 threads, 32 nodes/block. K chunked by 64 to keep LDS at ~42KB (3 blocks/CU).
// Thread (colg = tid&15, np = tid>>4) computes nodes {2np, 2np+1} x cols {4c..4c+3, 64+4c..}.
// sA stride 72: bank=(8n+k)%32 -> 2 distinct addrs/bank across the 8 node rows of a wave = free.
// sW float4 reads at col 4c (16 lanes x 16B contiguous 256B) = 2 lanes/bank = free.
__global__ __launch_bounds__(256) void gemm128(const float* __restrict__ A,
                                               const float* __restrict__ Wt,
                                               const float* __restrict__ bias,
                                               float* __restrict__ C, int n, int use_bias) {
    __shared__ float sW[64 * 128];
    __shared__ float sA[32 * 72];
    int tid = threadIdx.x;
    int colg = tid & 15;
    int np = tid >> 4;
    int base = blockIdx.x * 32;

    float4 acc00 = make_float4(0, 0, 0, 0), acc01 = make_float4(0, 0, 0, 0);
    float4 acc10 = make_float4(0, 0, 0, 0), acc11 = make_float4(0, 0, 0, 0);

    for (int kc = 0; kc < 2; ++kc) {
        const float4* Wg = (const float4*)(Wt + kc * 64 * 128);
        float4* sW4 = (float4*)sW;
#pragma unroll
        for (int i = 0; i < 8; ++i) sW4[tid + i * 256] = Wg[tid + i * 256];
#pragma unroll
        for (int i = 0; i < 2; ++i) {
            int f = tid * 2 + i;           // 0..511 float4 slots of the A chunk
            int row = f >> 4, kq = f & 15; // 32 rows x 16 float4 (64 k)
            int gn = base + row;
            float4 v = make_float4(0, 0, 0, 0);
            if (gn < n) v = *(const float4*)(A + (size_t)gn * 128 + kc * 64 + kq * 4);
            *(float4*)(sA + row * 72 + kq * 4) = v;
        }
        __syncthreads();
#pragma unroll
        for (int k = 0; k < 64; ++k) {
            float a0 = sA[(np * 2 + 0) * 72 + k];
            float a1 = sA[(np * 2 + 1) * 72 + k];
            float4 w0 = *(const float4*)(sW + k * 128 + colg * 4);
            float4 w1 = *(const float4*)(sW + k * 128 + 64 + colg * 4);
            acc00.x += a0 * w0.x; acc00.y += a0 * w0.y; acc00.z += a0 * w0.z; acc00.w += a0 * w0.w;
            acc01.x += a0 * w1.x; acc01.y += a0 * w1.y; acc01.z += a0 * w1.z; acc01.w += a0 * w1.w;
            acc10.x += a1 * w0.x; acc10.y += a1 * w0.y; acc10.z += a1 * w0.z; acc10.w += a1 * w0.w;
            acc11.x += a1 * w1.x; acc11.y += a1 * w1.y; acc11.z += a1 * w1.z; acc11.w += a1 * w1.w;
        }
        __syncthreads();
    }
    if (use_bias) {
        float4 b0 = *(const float4*)(bias + colg * 4);
        float4 b1v = *(const float4*)(bias + 64 + colg * 4);
        acc00.x += b0.x; acc00.y += b0.y; acc00.z += b0.z; acc00.w += b0.w;
        acc10.x += b0.x; acc10.y += b0.y; acc10.z += b0.z; acc10.w += b0.w;
        acc01.x += b1v.x; acc01.y += b1v.y; acc01.z += b1v.z; acc01.w += b1v.w;
        acc11.x += b1v.x; acc11.y += b1v.y; acc11.z += b1v.z; acc11.w += b1v.w;
    }
    int gn0 = base + np * 2;
    if (gn0 < n) {
        *(float4*)(C + (size_t)gn0 * 128 + colg * 4) = acc00;
        *(float4*)(C + (size_t)gn0 * 128 + 64 + colg * 4) = acc01;
    }
    if (gn0 + 1 < n) {
        *(float4*)(C + (size_t)(gn0 + 1) * 128 + colg * 4) = acc10;
        *(float4*)(C + (size_t)(gn0 + 1) * 128 + 64 + colg * 4) = acc11;
    }
}

// ---------------- fused CSR gather + self-loop + bias + LayerNorm + ReLU + residual ----------------
// One wave per node; lane holds cols {2*lane, 2*lane+1}. h updated in place.
__global__ __launch_bounds__(256) void gather_ln(const float* __restrict__ hw,
                                                 float* __restrict__ h,
                                                 const int* __restrict__ rowptr,
                                                 const int* __restrict__ csr_src,
                                                 const float* __restrict__ dinv,
                                                 const float* __restrict__ bc,
                                                 const float* __restrict__ gamma,
                                                 const float* __restrict__ beta, int n) {
    int wid = (blockIdx.x * 256 + threadIdx.x) >> 6;
    int lane = threadIdx.x & 63;
    if (wid >= n) return;
    int i = wid;
    float di = dinv[i];
    int e0 = rowptr[i], e1 = rowptr[i + 1];
    int c0 = lane * 2;

    // s = hw[i]*di + sum_e hw[src]*dinv[src];  agg = di*s + bc
    float2 s = *(const float2*)(hw + (size_t)i * HIDDIM + c0);
    s.x *= di; s.y *= di;
    for (int e = e0; e < e1; ++e) {
        int src = csr_src[e];
        float w = dinv[src];
        float2 v = *(const float2*)(hw + (size_t)src * HIDDIM + c0);
        s.x += v.x * w; s.y += v.y * w;
    }
    float2 bcv = *(const float2*)(bc + c0);
    float vx = di * s.x + bcv.x;
    float vy = di * s.y + bcv.y;

    float s1 = vx + vy, s2 = vx * vx + vy * vy;
#pragma unroll
    for (int off = 32; off; off >>= 1) {
        s1 += __shfl_xor(s1, off);
        s2 += __shfl_xor(s2, off);
    }
    float mu = s1 * (1.0f / 128.0f);
    float var = s2 * (1.0f / 128.0f) - mu * mu;
    float rs = 1.0f / sqrtf(var + 1e-5f);

    float2 gm = *(const float2*)(gamma + c0);
    float2 bt = *(const float2*)(beta + c0);
    float yx = fmaxf((vx - mu) * rs * gm.x + bt.x, 0.0f);
    float yy = fmaxf((vy - mu) * rs * gm.y + bt.y, 0.0f);

    float2 hv = *(float2*)(h + (size_t)i * HIDDIM + c0);
    hv.x += yx; hv.y += yy;
    *(float2*)(h + (size_t)i * HIDDIM + c0) = hv;
}

// ---------------- fused segmented mean-pool + MLP head (batch is SORTED) ----------------
// One 128-thread block per graph. Thread t owns column t of the pooled vector.
// Reads of h are coalesced 512 B per node. MLP: pooled -> LDS, wave 0 computes
// the 64 hidden units with LDS-broadcast float4 reads, shuffle-reduce for W2.
__global__ __launch_bounds__(128) void pool_mlp_kernel(const float* __restrict__ h,
                                                       const int* __restrict__ gp,
                                                       const float* __restrict__ W1,
                                                       const float* __restrict__ b1,
                                                       const float* __restrict__ W2,
                                                       const float* __restrict__ b2,
                                                       float* __restrict__ out, int G) {
    __shared__ float sp[128];
    int g = blockIdx.x;
    if (g >= G) return;
    int t = threadIdx.x;
    int s = gp[g], e = gp[g + 1];
    float acc = 0.0f;
    for (int i = s; i < e; ++i) acc += h[(size_t)i * HIDDIM + t];
    float cnt = fmaxf((float)(e - s), 1.0f);
    sp[t] = acc / cnt;
    __syncthreads();
    if (t < 64) {
        const float* wr = W1 + t * HIDDIM;
        float a = 0.0f;
#pragma unroll 8
        for (int k = 0; k < HIDDIM; k += 4) {
            float4 p = *(const float4*)(sp + k);  // same addr all lanes -> LDS broadcast
            float4 w = *(const float4*)(wr + k);
            a += p.x * w.x + p.y * w.y + p.z * w.z + p.w * w.w;
        }
        float h1 = fmaxf(a + b1[t], 0.0f);
        float c = h1 * W2[t];
#pragma unroll
        for (int off = 32; off; off >>= 1) c += __shfl_xor(c, off);
        if (t == 0) out[g] = c + b2[0];
    }
}

extern "C" void kernel_launch(void* const* d_in, const int* in_sizes, int n_in,
                              void* d_out, int out_size, void* d_ws, size_t ws_size,
                              hipStream_t stream) {
    const float* x      = (const float*)d_in[0];
    const int*   ei     = (const int*)d_in[1];
    const int*   batch  = (const int*)d_in[2];
    const float* W_in   = (const float*)d_in[3];
    const float* b_in   = (const float*)d_in[4];
    const float* Wc     = (const float*)d_in[5];
    const float* bc     = (const float*)d_in[6];
    const float* gamma  = (const float*)d_in[7];
    const float* beta   = (const float*)d_in[8];
    const float* W1     = (const float*)d_in[9];
    const float* b1     = (const float*)d_in[10];
    const float* W2     = (const float*)d_in[11];
    const float* b2     = (const float*)d_in[12];
    float* out = (float*)d_out;

    const int N = in_sizes[2];
    const int E = in_sizes[1] / 2;
    const int G = out_size;  // OUT_DIM == 1

    // workspace carve-up (256B aligned)
    char* ws = (char*)d_ws;
    size_t off = 0;
    auto alloc = [&](size_t bytes) {
        size_t o = off;
        off = (off + bytes + 255) & ~(size_t)255;
        return o;
    };
    int*   deg     = (int*)(ws + alloc((size_t)N * 4));
    int*   rowptr  = (int*)(ws + alloc((size_t)(N + 1) * 4));
    int*   cursor  = (int*)(ws + alloc((size_t)N * 4));
    int*   csr_src = (int*)(ws + alloc((size_t)E * 4));
    float* dinv    = (float*)(ws + alloc((size_t)N * 4));
    float* Wt      = (float*)(ws + alloc((size_t)4 * 16384 * 4));
    float* h       = (float*)(ws + alloc((size_t)N * 128 * 4));
    float* hw      = (float*)(ws + alloc((size_t)N * 128 * 4));
    int*   gp      = (int*)(ws + alloc((size_t)(G + 1) * 4));
    (void)ws_size; (void)n_in;

    // ---- graph preprocessing (per-call: ws is re-poisoned each launch) ----
    hipMemsetAsync(deg, 0, (size_t)N * 4, stream);
    deg_kernel<<<(E + 255) / 256, 256, 0, stream>>>(ei, E, deg);
    scan_kernel<<<1, 1024, 0, stream>>>(deg, N, rowptr, cursor);
    dinv_kernel<<<(N + 255) / 256, 256, 0, stream>>>(deg, N, dinv);
    bin_kernel<<<(E + 255) / 256, 256, 0, stream>>>(ei, E, cursor, csr_src);
    graph_ptr_kernel<<<(N + 255) / 256, 256, 0, stream>>>(batch, N, G, gp);
    transpose_w<<<(4 * 16384 + 255) / 256, 256, 0, stream>>>(W_in, Wc, Wt);

    // ---- input projection ----
    int gblocks = (N + 31) / 32;
    gemm128<<<gblocks, 256, 0, stream>>>(x, Wt, b_in, h, N, 1);

    // ---- 3 GCN layers ----
    for (int l = 0; l < 3; ++l) {
        gemm128<<<gblocks, 256, 0, stream>>>(h, Wt + (1 + l) * 16384, nullptr, hw, N, 0);
        gather_ln<<<(N + 3) / 4, 256, 0, stream>>>(hw, h, rowptr, csr_src, dinv,
                                                   bc + l * 128, gamma + l * 128,
                                                   beta + l * 128, N);
    }

    // ---- fused pooling + MLP head ----
    pool_mlp_kernel<<<G, 128, 0, stream>>>(h, gp, W1, b1, W2, b2, out, G);
}

// Round 3
// 624.415 us; speedup vs baseline: 1.3870x; 1.1787x over previous
//
#include <hip/hip_runtime.h>
#include <hip/hip_bf16.h>

#define HIDDIM 128

// ---------------- degree count (int atomics over dst) ----------------
__global__ __launch_bounds__(256) void deg_kernel(const int* __restrict__ ei, int E,
                                                  int* __restrict__ deg) {
    int gid = blockIdx.x * 256 + threadIdx.x;
    if (gid < E) atomicAdd(&deg[ei[E + gid]], 1);
}

// ---------------- hierarchical scan: phase A — per-block sums (1024 elems/block) ----------------
__global__ __launch_bounds__(256) void scan_phaseA(const int* __restrict__ deg, int n,
                                                   int* __restrict__ bsum) {
    int t = threadIdx.x;
    int base = blockIdx.x * 1024 + t * 4;
    int s = 0;
#pragma unroll
    for (int j = 0; j < 4; ++j) {
        int i = base + j;
        if (i < n) s += deg[i];
    }
#pragma unroll
    for (int off = 32; off; off >>= 1) s += __shfl_xor(s, off);
    __shared__ int wsum[4];
    if ((t & 63) == 0) wsum[t >> 6] = s;
    __syncthreads();
    if (t == 0) bsum[blockIdx.x] = wsum[0] + wsum[1] + wsum[2] + wsum[3];
}

// ---------------- phase B — scan the (<=256) block sums; writes rowptr[n] = total ----------------
__global__ __launch_bounds__(256) void scan_phaseB(const int* __restrict__ bsum, int nb,
                                                   int* __restrict__ bpre,
                                                   int* __restrict__ rowptr, int n) {
    int t = threadIdx.x;
    int lane = t & 63, wave = t >> 6;
    int v = (t < nb) ? bsum[t] : 0;
    int inc = v;
#pragma unroll
    for (int off = 1; off < 64; off <<= 1) {
        int u = __shfl_up(inc, off);
        if (lane >= off) inc += u;
    }
    __shared__ int wtot[4];
    if (lane == 63) wtot[wave] = inc;
    __syncthreads();
    int wbase = 0;
    for (int w = 0; w < wave; ++w) wbase += wtot[w];
    inc += wbase;
    if (t < nb) bpre[t] = inc - v;
    if (t == 255) rowptr[n] = inc;
}

// ---------------- phase C — final exclusive scan; fuses dinv = 1/sqrt(deg+1) ----------------
__global__ __launch_bounds__(256) void scan_phaseC(const int* __restrict__ deg, int n,
                                                   const int* __restrict__ bpre,
                                                   int* __restrict__ rowptr,
                                                   int* __restrict__ cursor,
                                                   float* __restrict__ dinv) {
    int t = threadIdx.x;
    int lane = t & 63, wave = t >> 6;
    int base = blockIdx.x * 1024 + t * 4;
    int d[4];
    int s = 0;
#pragma unroll
    for (int j = 0; j < 4; ++j) {
        int i = base + j;
        d[j] = (i < n) ? deg[i] : 0;
        s += d[j];
    }
    int inc = s;
#pragma unroll
    for (int off = 1; off < 64; off <<= 1) {
        int u = __shfl_up(inc, off);
        if (lane >= off) inc += u;
    }
    __shared__ int wtot[4];
    if (lane == 63) wtot[wave] = inc;
    __syncthreads();
    int wbase = 0;
    for (int w = 0; w < wave; ++w) wbase += wtot[w];
    int run = bpre[blockIdx.x] + wbase + (inc - s);  // exclusive base for this thread
#pragma unroll
    for (int j = 0; j < 4; ++j) {
        int i = base + j;
        if (i < n) {
            rowptr[i] = run;
            cursor[i] = run;
            dinv[i] = 1.0f / sqrtf((float)d[j] + 1.0f);
            run += d[j];
        }
    }
}

// ---------------- bin edges into CSR slots ----------------
__global__ __launch_bounds__(256) void bin_kernel(const int* __restrict__ ei, int E,
                                                  int* __restrict__ cursor,
                                                  int* __restrict__ csr_src) {
    int gid = blockIdx.x * 256 + threadIdx.x;
    if (gid < E) {
        int src = ei[gid];
        int dst = ei[E + gid];
        int pos = atomicAdd(&cursor[dst], 1);
        csr_src[pos] = src;
    }
}

// ---------------- graph_ptr from sorted batch: gp[g] = first node with batch >= g ----------------
__global__ __launch_bounds__(256) void graph_ptr_kernel(const int* __restrict__ batch, int n,
                                                        int G, int* __restrict__ gp) {
    int i = blockIdx.x * 256 + threadIdx.x;
    if (i >= n) return;
    int bi = batch[i];
    if (i == 0) {
        for (int g = 0; g <= bi; ++g) gp[g] = 0;
    } else {
        int bp = batch[i - 1];
        for (int g = bp + 1; g <= bi; ++g) gp[g] = i;
    }
    if (i == n - 1) {
        for (int g = bi + 1; g <= G; ++g) gp[g] = n;
    }
}

// ---------------- transpose the 4 weight matrices: Wt[m][k][o] = W[m][o][k] ----------------
__global__ __launch_bounds__(256) void transpose_w(const float* __restrict__ Win,
                                                   const float* __restrict__ Wc,
                                                   float* __restrict__ Wt) {
    int gid = blockIdx.x * 256 + threadIdx.x;
    if (gid >= 4 * 16384) return;
    int m = gid >> 14;
    int r = gid & 16383;
    int k = r >> 7, o = r & 127;
    const float* src = (m == 0) ? Win : (Wc + (m - 1) * 16384);
    Wt[gid] = src[o * 128 + k];
}

// ---------------- fp32 GEMM: C[n][128] = A[n][128] @ Wt (Wt is [k][o]) (+bias) ----------------
// Block = 256 threads, 32 nodes/block. K chunked by 64 to keep LDS at ~42KB (3 blocks/CU).
// Thread (colg = tid&15, np = tid>>4) computes nodes {2np, 2np+1} x cols {4c..4c+3, 64+4c..}.
// sA stride 72: bank=(8n+k)%32 -> 2 distinct addrs/bank across the 8 node rows of a wave = free.
// sW float4 reads at col 4c (16 lanes x 16B contiguous 256B) = 2 lanes/bank = free.
__global__ __launch_bounds__(256) void gemm128(const float* __restrict__ A,
                                               const float* __restrict__ Wt,
                                               const float* __restrict__ bias,
                                               float* __restrict__ C, int n, int use_bias) {
    __shared__ float sW[64 * 128];
    __shared__ float sA[32 * 72];
    int tid = threadIdx.x;
    int colg = tid & 15;
    int np = tid >> 4;
    int base = blockIdx.x * 32;

    float4 acc00 = make_float4(0, 0, 0, 0), acc01 = make_float4(0, 0, 0, 0);
    float4 acc10 = make_float4(0, 0, 0, 0), acc11 = make_float4(0, 0, 0, 0);

    for (int kc = 0; kc < 2; ++kc) {
        const float4* Wg = (const float4*)(Wt + kc * 64 * 128);
        float4* sW4 = (float4*)sW;
#pragma unroll
        for (int i = 0; i < 8; ++i) sW4[tid + i * 256] = Wg[tid + i * 256];
#pragma unroll
        for (int i = 0; i < 2; ++i) {
            int f = tid * 2 + i;           // 0..511 float4 slots of the A chunk
            int row = f >> 4, kq = f & 15; // 32 rows x 16 float4 (64 k)
            int gn = base + row;
            float4 v = make_float4(0, 0, 0, 0);
            if (gn < n) v = *(const float4*)(A + (size_t)gn * 128 + kc * 64 + kq * 4);
            *(float4*)(sA + row * 72 + kq * 4) = v;
        }
        __syncthreads();
#pragma unroll
        for (int k = 0; k < 64; ++k) {
            float a0 = sA[(np * 2 + 0) * 72 + k];
            float a1 = sA[(np * 2 + 1) * 72 + k];
            float4 w0 = *(const float4*)(sW + k * 128 + colg * 4);
            float4 w1 = *(const float4*)(sW + k * 128 + 64 + colg * 4);
            acc00.x += a0 * w0.x; acc00.y += a0 * w0.y; acc00.z += a0 * w0.z; acc00.w += a0 * w0.w;
            acc01.x += a0 * w1.x; acc01.y += a0 * w1.y; acc01.z += a0 * w1.z; acc01.w += a0 * w1.w;
            acc10.x += a1 * w0.x; acc10.y += a1 * w0.y; acc10.z += a1 * w0.z; acc10.w += a1 * w0.w;
            acc11.x += a1 * w1.x; acc11.y += a1 * w1.y; acc11.z += a1 * w1.z; acc11.w += a1 * w1.w;
        }
        __syncthreads();
    }
    if (use_bias) {
        float4 b0 = *(const float4*)(bias + colg * 4);
        float4 b1v = *(const float4*)(bias + 64 + colg * 4);
        acc00.x += b0.x; acc00.y += b0.y; acc00.z += b0.z; acc00.w += b0.w;
        acc10.x += b0.x; acc10.y += b0.y; acc10.z += b0.z; acc10.w += b0.w;
        acc01.x += b1v.x; acc01.y += b1v.y; acc01.z += b1v.z; acc01.w += b1v.w;
        acc11.x += b1v.x; acc11.y += b1v.y; acc11.z += b1v.z; acc11.w += b1v.w;
    }
    int gn0 = base + np * 2;
    if (gn0 < n) {
        *(float4*)(C + (size_t)gn0 * 128 + colg * 4) = acc00;
        *(float4*)(C + (size_t)gn0 * 128 + 64 + colg * 4) = acc01;
    }
    if (gn0 + 1 < n) {
        *(float4*)(C + (size_t)(gn0 + 1) * 128 + colg * 4) = acc10;
        *(float4*)(C + (size_t)(gn0 + 1) * 128 + 64 + colg * 4) = acc11;
    }
}

// ---------------- fused CSR gather + self-loop + bias + LayerNorm + ReLU + residual ----------------
// One wave per node; lane holds cols {2*lane, 2*lane+1}. h updated in place.
__global__ __launch_bounds__(256) void gather_ln(const float* __restrict__ hw,
                                                 float* __restrict__ h,
                                                 const int* __restrict__ rowptr,
                                                 const int* __restrict__ csr_src,
                                                 const float* __restrict__ dinv,
                                                 const float* __restrict__ bc,
                                                 const float* __restrict__ gamma,
                                                 const float* __restrict__ beta, int n) {
    int wid = (blockIdx.x * 256 + threadIdx.x) >> 6;
    int lane = threadIdx.x & 63;
    if (wid >= n) return;
    int i = wid;
    float di = dinv[i];
    int e0 = rowptr[i], e1 = rowptr[i + 1];
    int c0 = lane * 2;

    // s = hw[i]*di + sum_e hw[src]*dinv[src];  agg = di*s + bc
    float2 s = *(const float2*)(hw + (size_t)i * HIDDIM + c0);
    s.x *= di; s.y *= di;
    for (int e = e0; e < e1; ++e) {
        int src = csr_src[e];
        float w = dinv[src];
        float2 v = *(const float2*)(hw + (size_t)src * HIDDIM + c0);
        s.x += v.x * w; s.y += v.y * w;
    }
    float2 bcv = *(const float2*)(bc + c0);
    float vx = di * s.x + bcv.x;
    float vy = di * s.y + bcv.y;

    float s1 = vx + vy, s2 = vx * vx + vy * vy;
#pragma unroll
    for (int off = 32; off; off >>= 1) {
        s1 += __shfl_xor(s1, off);
        s2 += __shfl_xor(s2, off);
    }
    float mu = s1 * (1.0f / 128.0f);
    float var = s2 * (1.0f / 128.0f) - mu * mu;
    float rs = 1.0f / sqrtf(var + 1e-5f);

    float2 gm = *(const float2*)(gamma + c0);
    float2 bt = *(const float2*)(beta + c0);
    float yx = fmaxf((vx - mu) * rs * gm.x + bt.x, 0.0f);
    float yy = fmaxf((vy - mu) * rs * gm.y + bt.y, 0.0f);

    float2 hv = *(float2*)(h + (size_t)i * HIDDIM + c0);
    hv.x += yx; hv.y += yy;
    *(float2*)(h + (size_t)i * HIDDIM + c0) = hv;
}

// ---------------- fused segmented mean-pool + MLP head (batch is SORTED) ----------------
__global__ __launch_bounds__(128) void pool_mlp_kernel(const float* __restrict__ h,
                                                       const int* __restrict__ gp,
                                                       const float* __restrict__ W1,
                                                       const float* __restrict__ b1,
                                                       const float* __restrict__ W2,
                                                       const float* __restrict__ b2,
                                                       float* __restrict__ out, int G) {
    __shared__ float sp[128];
    int g = blockIdx.x;
    if (g >= G) return;
    int t = threadIdx.x;
    int s = gp[g], e = gp[g + 1];
    float acc = 0.0f;
    for (int i = s; i < e; ++i) acc += h[(size_t)i * HIDDIM + t];
    float cnt = fmaxf((float)(e - s), 1.0f);
    sp[t] = acc / cnt;
    __syncthreads();
    if (t < 64) {
        const float* wr = W1 + t * HIDDIM;
        float a = 0.0f;
#pragma unroll 8
        for (int k = 0; k < HIDDIM; k += 4) {
            float4 p = *(const float4*)(sp + k);  // same addr all lanes -> LDS broadcast
            float4 w = *(const float4*)(wr + k);
            a += p.x * w.x + p.y * w.y + p.z * w.z + p.w * w.w;
        }
        float h1 = fmaxf(a + b1[t], 0.0f);
        float c = h1 * W2[t];
#pragma unroll
        for (int off = 32; off; off >>= 1) c += __shfl_xor(c, off);
        if (t == 0) out[g] = c + b2[0];
    }
}

extern "C" void kernel_launch(void* const* d_in, const int* in_sizes, int n_in,
                              void* d_out, int out_size, void* d_ws, size_t ws_size,
                              hipStream_t stream) {
    const float* x      = (const float*)d_in[0];
    const int*   ei     = (const int*)d_in[1];
    const int*   batch  = (const int*)d_in[2];
    const float* W_in   = (const float*)d_in[3];
    const float* b_in   = (const float*)d_in[4];
    const float* Wc     = (const float*)d_in[5];
    const float* bc     = (const float*)d_in[6];
    const float* gamma  = (const float*)d_in[7];
    const float* beta   = (const float*)d_in[8];
    const float* W1     = (const float*)d_in[9];
    const float* b1     = (const float*)d_in[10];
    const float* W2     = (const float*)d_in[11];
    const float* b2     = (const float*)d_in[12];
    float* out = (float*)d_out;

    const int N = in_sizes[2];
    const int E = in_sizes[1] / 2;
    const int G = out_size;  // OUT_DIM == 1
    const int NB = (N + 1023) / 1024;

    // workspace carve-up (256B aligned)
    char* ws = (char*)d_ws;
    size_t off = 0;
    auto alloc = [&](size_t bytes) {
        size_t o = off;
        off = (off + bytes + 255) & ~(size_t)255;
        return o;
    };
    int*   deg     = (int*)(ws + alloc((size_t)N * 4));
    int*   rowptr  = (int*)(ws + alloc((size_t)(N + 1) * 4));
    int*   cursor  = (int*)(ws + alloc((size_t)N * 4));
    int*   csr_src = (int*)(ws + alloc((size_t)E * 4));
    float* dinv    = (float*)(ws + alloc((size_t)N * 4));
    float* Wt      = (float*)(ws + alloc((size_t)4 * 16384 * 4));
    float* h       = (float*)(ws + alloc((size_t)N * 128 * 4));
    float* hw      = (float*)(ws + alloc((size_t)N * 128 * 4));
    int*   gp      = (int*)(ws + alloc((size_t)(G + 1) * 4));
    int*   bsum    = (int*)(ws + alloc((size_t)NB * 4));
    int*   bpre    = (int*)(ws + alloc((size_t)NB * 4));
    (void)ws_size; (void)n_in;

    // ---- graph preprocessing (per-call: ws is re-poisoned each launch) ----
    hipMemsetAsync(deg, 0, (size_t)N * 4, stream);
    deg_kernel<<<(E + 255) / 256, 256, 0, stream>>>(ei, E, deg);
    scan_phaseA<<<NB, 256, 0, stream>>>(deg, N, bsum);
    scan_phaseB<<<1, 256, 0, stream>>>(bsum, NB, bpre, rowptr, N);
    scan_phaseC<<<NB, 256, 0, stream>>>(deg, N, bpre, rowptr, cursor, dinv);
    bin_kernel<<<(E + 255) / 256, 256, 0, stream>>>(ei, E, cursor, csr_src);
    graph_ptr_kernel<<<(N + 255) / 256, 256, 0, stream>>>(batch, N, G, gp);
    transpose_w<<<(4 * 16384 + 255) / 256, 256, 0, stream>>>(W_in, Wc, Wt);

    // ---- input projection ----
    int gblocks = (N + 31) / 32;
    gemm128<<<gblocks, 256, 0, stream>>>(x, Wt, b_in, h, N, 1);

    // ---- 3 GCN layers ----
    for (int l = 0; l < 3; ++l) {
        gemm128<<<gblocks, 256, 0, stream>>>(h, Wt + (1 + l) * 16384, nullptr, hw, N, 0);
        gather_ln<<<(N + 3) / 4, 256, 0, stream>>>(hw, h, rowptr, csr_src, dinv,
                                                   bc + l * 128, gamma + l * 128,
                                                   beta + l * 128, N);
    }

    // ---- fused pooling + MLP head ----
    pool_mlp_kernel<<<G, 128, 0, stream>>>(h, gp, W1, b1, W2, b2, out, G);
}

// Round 4
// 547.970 us; speedup vs baseline: 1.5805x; 1.1395x over previous
//
#include <hip/hip_runtime.h>
#include <hip/hip_bf16.h>

#define HIDDIM 128

// ---------------- degree count (int atomics over dst) ----------------
__global__ __launch_bounds__(256) void deg_kernel(const int* __restrict__ ei, int E,
                                                  int* __restrict__ deg) {
    int gid = blockIdx.x * 256 + threadIdx.x;
    if (gid < E) atomicAdd(&deg[ei[E + gid]], 1);
}

// ---------------- hierarchical scan: phase A — per-block sums (1024 elems/block) ----------------
__global__ __launch_bounds__(256) void scan_phaseA(const int* __restrict__ deg, int n,
                                                   int* __restrict__ bsum) {
    int t = threadIdx.x;
    int base = blockIdx.x * 1024 + t * 4;
    int s = 0;
#pragma unroll
    for (int j = 0; j < 4; ++j) {
        int i = base + j;
        if (i < n) s += deg[i];
    }
#pragma unroll
    for (int off = 32; off; off >>= 1) s += __shfl_xor(s, off);
    __shared__ int wsum[4];
    if ((t & 63) == 0) wsum[t >> 6] = s;
    __syncthreads();
    if (t == 0) bsum[blockIdx.x] = wsum[0] + wsum[1] + wsum[2] + wsum[3];
}

// ---------------- phase B — scan the (<=256) block sums; writes rowptr[n] = total ----------------
__global__ __launch_bounds__(256) void scan_phaseB(const int* __restrict__ bsum, int nb,
                                                   int* __restrict__ bpre,
                                                   int* __restrict__ rowptr, int n) {
    int t = threadIdx.x;
    int lane = t & 63, wave = t >> 6;
    int v = (t < nb) ? bsum[t] : 0;
    int inc = v;
#pragma unroll
    for (int off = 1; off < 64; off <<= 1) {
        int u = __shfl_up(inc, off);
        if (lane >= off) inc += u;
    }
    __shared__ int wtot[4];
    if (lane == 63) wtot[wave] = inc;
    __syncthreads();
    int wbase = 0;
    for (int w = 0; w < wave; ++w) wbase += wtot[w];
    inc += wbase;
    if (t < nb) bpre[t] = inc - v;
    if (t == 255) rowptr[n] = inc;
}

// ---------------- phase C — final exclusive scan; fuses dinv = 1/sqrt(deg+1) ----------------
__global__ __launch_bounds__(256) void scan_phaseC(const int* __restrict__ deg, int n,
                                                   const int* __restrict__ bpre,
                                                   int* __restrict__ rowptr,
                                                   int* __restrict__ cursor,
                                                   float* __restrict__ dinv) {
    int t = threadIdx.x;
    int lane = t & 63, wave = t >> 6;
    int base = blockIdx.x * 1024 + t * 4;
    int d[4];
    int s = 0;
#pragma unroll
    for (int j = 0; j < 4; ++j) {
        int i = base + j;
        d[j] = (i < n) ? deg[i] : 0;
        s += d[j];
    }
    int inc = s;
#pragma unroll
    for (int off = 1; off < 64; off <<= 1) {
        int u = __shfl_up(inc, off);
        if (lane >= off) inc += u;
    }
    __shared__ int wtot[4];
    if (lane == 63) wtot[wave] = inc;
    __syncthreads();
    int wbase = 0;
    for (int w = 0; w < wave; ++w) wbase += wtot[w];
    int run = bpre[blockIdx.x] + wbase + (inc - s);  // exclusive base for this thread
#pragma unroll
    for (int j = 0; j < 4; ++j) {
        int i = base + j;
        if (i < n) {
            rowptr[i] = run;
            cursor[i] = run;
            dinv[i] = 1.0f / sqrtf((float)d[j] + 1.0f);
            run += d[j];
        }
    }
}

// ---------------- bin edges into CSR slots ----------------
__global__ __launch_bounds__(256) void bin_kernel(const int* __restrict__ ei, int E,
                                                  int* __restrict__ cursor,
                                                  int* __restrict__ csr_src) {
    int gid = blockIdx.x * 256 + threadIdx.x;
    if (gid < E) {
        int src = ei[gid];
        int dst = ei[E + gid];
        int pos = atomicAdd(&cursor[dst], 1);
        csr_src[pos] = src;
    }
}

// ---------------- graph_ptr from sorted batch: gp[g] = first node with batch >= g ----------------
__global__ __launch_bounds__(256) void graph_ptr_kernel(const int* __restrict__ batch, int n,
                                                        int G, int* __restrict__ gp) {
    int i = blockIdx.x * 256 + threadIdx.x;
    if (i >= n) return;
    int bi = batch[i];
    if (i == 0) {
        for (int g = 0; g <= bi; ++g) gp[g] = 0;
    } else {
        int bp = batch[i - 1];
        for (int g = bp + 1; g <= bi; ++g) gp[g] = i;
    }
    if (i == n - 1) {
        for (int g = bi + 1; g <= G; ++g) gp[g] = n;
    }
}

// ---------------- transpose the 4 weight matrices: Wt[m][k][o] = W[m][o][k] ----------------
__global__ __launch_bounds__(256) void transpose_w(const float* __restrict__ Win,
                                                   const float* __restrict__ Wc,
                                                   float* __restrict__ Wt) {
    int gid = blockIdx.x * 256 + threadIdx.x;
    if (gid >= 4 * 16384) return;
    int m = gid >> 14;
    int r = gid & 16383;
    int k = r >> 7, o = r & 127;
    const float* src = (m == 0) ? Win : (Wc + (m - 1) * 16384);
    Wt[gid] = src[o * 128 + k];
}

// ---------------- fp32 GEMM: C[n][128] = A[n][128] @ Wt (Wt is [k][o]) ----------------
// Optional bias add; optional per-row scale (C[i] *= scale[i]) for the GCN dinv pre-scaling.
__global__ __launch_bounds__(256) void gemm128(const float* __restrict__ A,
                                               const float* __restrict__ Wt,
                                               const float* __restrict__ bias,
                                               const float* __restrict__ scale,
                                               float* __restrict__ C, int n, int use_bias,
                                               int use_scale) {
    __shared__ float sW[64 * 128];
    __shared__ float sA[32 * 72];
    int tid = threadIdx.x;
    int colg = tid & 15;
    int np = tid >> 4;
    int base = blockIdx.x * 32;

    float4 acc00 = make_float4(0, 0, 0, 0), acc01 = make_float4(0, 0, 0, 0);
    float4 acc10 = make_float4(0, 0, 0, 0), acc11 = make_float4(0, 0, 0, 0);

    for (int kc = 0; kc < 2; ++kc) {
        const float4* Wg = (const float4*)(Wt + kc * 64 * 128);
        float4* sW4 = (float4*)sW;
#pragma unroll
        for (int i = 0; i < 8; ++i) sW4[tid + i * 256] = Wg[tid + i * 256];
#pragma unroll
        for (int i = 0; i < 2; ++i) {
            int f = tid * 2 + i;           // 0..511 float4 slots of the A chunk
            int row = f >> 4, kq = f & 15; // 32 rows x 16 float4 (64 k)
            int gn = base + row;
            float4 v = make_float4(0, 0, 0, 0);
            if (gn < n) v = *(const float4*)(A + (size_t)gn * 128 + kc * 64 + kq * 4);
            *(float4*)(sA + row * 72 + kq * 4) = v;
        }
        __syncthreads();
#pragma unroll
        for (int k = 0; k < 64; ++k) {
            float a0 = sA[(np * 2 + 0) * 72 + k];
            float a1 = sA[(np * 2 + 1) * 72 + k];
            float4 w0 = *(const float4*)(sW + k * 128 + colg * 4);
            float4 w1 = *(const float4*)(sW + k * 128 + 64 + colg * 4);
            acc00.x += a0 * w0.x; acc00.y += a0 * w0.y; acc00.z += a0 * w0.z; acc00.w += a0 * w0.w;
            acc01.x += a0 * w1.x; acc01.y += a0 * w1.y; acc01.z += a0 * w1.z; acc01.w += a0 * w1.w;
            acc10.x += a1 * w0.x; acc10.y += a1 * w0.y; acc10.z += a1 * w0.z; acc10.w += a1 * w0.w;
            acc11.x += a1 * w1.x; acc11.y += a1 * w1.y; acc11.z += a1 * w1.z; acc11.w += a1 * w1.w;
        }
        __syncthreads();
    }
    if (use_bias) {
        float4 b0 = *(const float4*)(bias + colg * 4);
        float4 b1v = *(const float4*)(bias + 64 + colg * 4);
        acc00.x += b0.x; acc00.y += b0.y; acc00.z += b0.z; acc00.w += b0.w;
        acc10.x += b0.x; acc10.y += b0.y; acc10.z += b0.z; acc10.w += b0.w;
        acc01.x += b1v.x; acc01.y += b1v.y; acc01.z += b1v.z; acc01.w += b1v.w;
        acc11.x += b1v.x; acc11.y += b1v.y; acc11.z += b1v.z; acc11.w += b1v.w;
    }
    int gn0 = base + np * 2;
    if (use_scale) {
        if (gn0 < n) {
            float s0 = scale[gn0];
            acc00.x *= s0; acc00.y *= s0; acc00.z *= s0; acc00.w *= s0;
            acc01.x *= s0; acc01.y *= s0; acc01.z *= s0; acc01.w *= s0;
        }
        if (gn0 + 1 < n) {
            float s1 = scale[gn0 + 1];
            acc10.x *= s1; acc10.y *= s1; acc10.z *= s1; acc10.w *= s1;
            acc11.x *= s1; acc11.y *= s1; acc11.z *= s1; acc11.w *= s1;
        }
    }
    if (gn0 < n) {
        *(float4*)(C + (size_t)gn0 * 128 + colg * 4) = acc00;
        *(float4*)(C + (size_t)gn0 * 128 + 64 + colg * 4) = acc01;
    }
    if (gn0 + 1 < n) {
        *(float4*)(C + (size_t)(gn0 + 1) * 128 + colg * 4) = acc10;
        *(float4*)(C + (size_t)(gn0 + 1) * 128 + 64 + colg * 4) = acc11;
    }
}

// ---------------- fused CSR gather + self-loop + bias + LayerNorm + ReLU + residual ----------------
// hws rows are PRE-SCALED by dinv[row] (done in gemm128 epilogue), so the edge loop is a
// pure sum of rows. One wave per node; lane holds cols {2*lane, 2*lane+1}.
// Edge loop is 8-way software-pipelined: 8 independent 512B row fetches in flight per wave
// (was 1 -> latency-chain bound at 95us). Accumulation order is unchanged (sequential adds).
__global__ __launch_bounds__(256) void gather_ln(const float* __restrict__ hws,
                                                 float* __restrict__ h,
                                                 const int* __restrict__ rowptr,
                                                 const int* __restrict__ csr_src,
                                                 const float* __restrict__ dinv,
                                                 const float* __restrict__ bc,
                                                 const float* __restrict__ gamma,
                                                 const float* __restrict__ beta, int n) {
    int wid = (blockIdx.x * 256 + threadIdx.x) >> 6;
    int lane = threadIdx.x & 63;
    if (wid >= n) return;
    int i = wid;
    float di = dinv[i];
    int e0 = rowptr[i], e1 = rowptr[i + 1];
    int c0 = lane * 2;
    const float* hb = hws + c0;

    // s = hws[i] + sum_e hws[src];  agg = di*s + bc   (hws already carries dinv[row])
    float2 s = *(const float2*)(hb + (size_t)i * HIDDIM);
    int e = e0;
    for (; e + 8 <= e1; e += 8) {
        int i0 = csr_src[e + 0], i1 = csr_src[e + 1], i2 = csr_src[e + 2], i3 = csr_src[e + 3];
        int i4 = csr_src[e + 4], i5 = csr_src[e + 5], i6 = csr_src[e + 6], i7 = csr_src[e + 7];
        float2 v0 = *(const float2*)(hb + (size_t)i0 * HIDDIM);
        float2 v1 = *(const float2*)(hb + (size_t)i1 * HIDDIM);
        float2 v2 = *(const float2*)(hb + (size_t)i2 * HIDDIM);
        float2 v3 = *(const float2*)(hb + (size_t)i3 * HIDDIM);
        float2 v4 = *(const float2*)(hb + (size_t)i4 * HIDDIM);
        float2 v5 = *(const float2*)(hb + (size_t)i5 * HIDDIM);
        float2 v6 = *(const float2*)(hb + (size_t)i6 * HIDDIM);
        float2 v7 = *(const float2*)(hb + (size_t)i7 * HIDDIM);
        s.x += v0.x; s.y += v0.y;  s.x += v1.x; s.y += v1.y;
        s.x += v2.x; s.y += v2.y;  s.x += v3.x; s.y += v3.y;
        s.x += v4.x; s.y += v4.y;  s.x += v5.x; s.y += v5.y;
        s.x += v6.x; s.y += v6.y;  s.x += v7.x; s.y += v7.y;
    }
    if (e + 4 <= e1) {
        int i0 = csr_src[e + 0], i1 = csr_src[e + 1], i2 = csr_src[e + 2], i3 = csr_src[e + 3];
        float2 v0 = *(const float2*)(hb + (size_t)i0 * HIDDIM);
        float2 v1 = *(const float2*)(hb + (size_t)i1 * HIDDIM);
        float2 v2 = *(const float2*)(hb + (size_t)i2 * HIDDIM);
        float2 v3 = *(const float2*)(hb + (size_t)i3 * HIDDIM);
        s.x += v0.x; s.y += v0.y;  s.x += v1.x; s.y += v1.y;
        s.x += v2.x; s.y += v2.y;  s.x += v3.x; s.y += v3.y;
        e += 4;
    }
    for (; e < e1; ++e) {
        int sc = csr_src[e];
        float2 v = *(const float2*)(hb + (size_t)sc * HIDDIM);
        s.x += v.x; s.y += v.y;
    }
    float2 bcv = *(const float2*)(bc + c0);
    float vx = di * s.x + bcv.x;
    float vy = di * s.y + bcv.y;

    float s1 = vx + vy, s2 = vx * vx + vy * vy;
#pragma unroll
    for (int off = 32; off; off >>= 1) {
        s1 += __shfl_xor(s1, off);
        s2 += __shfl_xor(s2, off);
    }
    float mu = s1 * (1.0f / 128.0f);
    float var = s2 * (1.0f / 128.0f) - mu * mu;
    float rs = 1.0f / sqrtf(var + 1e-5f);

    float2 gm = *(const float2*)(gamma + c0);
    float2 bt = *(const float2*)(beta + c0);
    float yx = fmaxf((vx - mu) * rs * gm.x + bt.x, 0.0f);
    float yy = fmaxf((vy - mu) * rs * gm.y + bt.y, 0.0f);

    float2 hv = *(float2*)(h + (size_t)i * HIDDIM + c0);
    hv.x += yx; hv.y += yy;
    *(float2*)(h + (size_t)i * HIDDIM + c0) = hv;
}

// ---------------- fused segmented mean-pool + MLP head (batch is SORTED) ----------------
__global__ __launch_bounds__(128) void pool_mlp_kernel(const float* __restrict__ h,
                                                       const int* __restrict__ gp,
                                                       const float* __restrict__ W1,
                                                       const float* __restrict__ b1,
                                                       const float* __restrict__ W2,
                                                       const float* __restrict__ b2,
                                                       float* __restrict__ out, int G) {
    __shared__ float sp[128];
    int g = blockIdx.x;
    if (g >= G) return;
    int t = threadIdx.x;
    int s = gp[g], e = gp[g + 1];
    float acc = 0.0f;
    for (int i = s; i < e; ++i) acc += h[(size_t)i * HIDDIM + t];
    float cnt = fmaxf((float)(e - s), 1.0f);
    sp[t] = acc / cnt;
    __syncthreads();
    if (t < 64) {
        const float* wr = W1 + t * HIDDIM;
        float a = 0.0f;
#pragma unroll 8
        for (int k = 0; k < HIDDIM; k += 4) {
            float4 p = *(const float4*)(sp + k);  // same addr all lanes -> LDS broadcast
            float4 w = *(const float4*)(wr + k);
            a += p.x * w.x + p.y * w.y + p.z * w.z + p.w * w.w;
        }
        float h1 = fmaxf(a + b1[t], 0.0f);
        float c = h1 * W2[t];
#pragma unroll
        for (int off = 32; off; off >>= 1) c += __shfl_xor(c, off);
        if (t == 0) out[g] = c + b2[0];
    }
}

extern "C" void kernel_launch(void* const* d_in, const int* in_sizes, int n_in,
                              void* d_out, int out_size, void* d_ws, size_t ws_size,
                              hipStream_t stream) {
    const float* x      = (const float*)d_in[0];
    const int*   ei     = (const int*)d_in[1];
    const int*   batch  = (const int*)d_in[2];
    const float* W_in   = (const float*)d_in[3];
    const float* b_in   = (const float*)d_in[4];
    const float* Wc     = (const float*)d_in[5];
    const float* bc     = (const float*)d_in[6];
    const float* gamma  = (const float*)d_in[7];
    const float* beta   = (const float*)d_in[8];
    const float* W1     = (const float*)d_in[9];
    const float* b1     = (const float*)d_in[10];
    const float* W2     = (const float*)d_in[11];
    const float* b2     = (const float*)d_in[12];
    float* out = (float*)d_out;

    const int N = in_sizes[2];
    const int E = in_sizes[1] / 2;
    const int G = out_size;  // OUT_DIM == 1
    const int NB = (N + 1023) / 1024;

    // workspace carve-up (256B aligned)
    char* ws = (char*)d_ws;
    size_t off = 0;
    auto alloc = [&](size_t bytes) {
        size_t o = off;
        off = (off + bytes + 255) & ~(size_t)255;
        return o;
    };
    int*   deg     = (int*)(ws + alloc((size_t)N * 4));
    int*   rowptr  = (int*)(ws + alloc((size_t)(N + 1) * 4));
    int*   cursor  = (int*)(ws + alloc((size_t)N * 4));
    int*   csr_src = (int*)(ws + alloc((size_t)E * 4));
    float* dinv    = (float*)(ws + alloc((size_t)N * 4));
    float* Wt      = (float*)(ws + alloc((size_t)4 * 16384 * 4));
    float* h       = (float*)(ws + alloc((size_t)N * 128 * 4));
    float* hws     = (float*)(ws + alloc((size_t)N * 128 * 4));
    int*   gp      = (int*)(ws + alloc((size_t)(G + 1) * 4));
    int*   bsum    = (int*)(ws + alloc((size_t)NB * 4));
    int*   bpre    = (int*)(ws + alloc((size_t)NB * 4));
    (void)ws_size; (void)n_in;

    // ---- graph preprocessing (per-call: ws is re-poisoned each launch) ----
    hipMemsetAsync(deg, 0, (size_t)N * 4, stream);
    deg_kernel<<<(E + 255) / 256, 256, 0, stream>>>(ei, E, deg);
    scan_phaseA<<<NB, 256, 0, stream>>>(deg, N, bsum);
    scan_phaseB<<<1, 256, 0, stream>>>(bsum, NB, bpre, rowptr, N);
    scan_phaseC<<<NB, 256, 0, stream>>>(deg, N, bpre, rowptr, cursor, dinv);
    bin_kernel<<<(E + 255) / 256, 256, 0, stream>>>(ei, E, cursor, csr_src);
    graph_ptr_kernel<<<(N + 255) / 256, 256, 0, stream>>>(batch, N, G, gp);
    transpose_w<<<(4 * 16384 + 255) / 256, 256, 0, stream>>>(W_in, Wc, Wt);

    // ---- input projection ----
    int gblocks = (N + 31) / 32;
    gemm128<<<gblocks, 256, 0, stream>>>(x, Wt, b_in, nullptr, h, N, 1, 0);

    // ---- 3 GCN layers ----
    for (int l = 0; l < 3; ++l) {
        // hws = (h @ Wc[l]^T) * dinv[row]  (pre-scaled for the gather)
        gemm128<<<gblocks, 256, 0, stream>>>(h, Wt + (1 + l) * 16384, nullptr, dinv, hws, N, 0, 1);
        gather_ln<<<(N + 3) / 4, 256, 0, stream>>>(hws, h, rowptr, csr_src, dinv,
                                                   bc + l * 128, gamma + l * 128,
                                                   beta + l * 128, N);
    }

    // ---- fused pooling + MLP head ----
    pool_mlp_kernel<<<G, 128, 0, stream>>>(h, gp, W1, b1, W2, b2, out, G);
}

// Round 5
// 472.868 us; speedup vs baseline: 1.8315x; 1.1588x over previous
//
#include <hip/hip_runtime.h>
#include <hip/hip_bf16.h>

#define HIDDIM 128

typedef short bf16x8 __attribute__((ext_vector_type(8)));
typedef float f32x4 __attribute__((ext_vector_type(4)));

__device__ inline unsigned short f2bf(float f) {
    unsigned u = __float_as_uint(f);
    unsigned r = (u + 0x7fffu + ((u >> 16) & 1u)) >> 16;  // RNE
    return (unsigned short)r;
}
__device__ inline float bf2f(unsigned short s) {
    return __uint_as_float(((unsigned)s) << 16);
}

// ---------------- degree count (int atomics over dst) ----------------
__global__ __launch_bounds__(256) void deg_kernel(const int* __restrict__ ei, int E,
                                                  int* __restrict__ deg) {
    int gid = blockIdx.x * 256 + threadIdx.x;
    if (gid < E) atomicAdd(&deg[ei[E + gid]], 1);
}

// ---------------- hierarchical scan: phase A — per-block sums (1024 elems/block) ----------------
__global__ __launch_bounds__(256) void scan_phaseA(const int* __restrict__ deg, int n,
                                                   int* __restrict__ bsum) {
    int t = threadIdx.x;
    int base = blockIdx.x * 1024 + t * 4;
    int s = 0;
#pragma unroll
    for (int j = 0; j < 4; ++j) {
        int i = base + j;
        if (i < n) s += deg[i];
    }
#pragma unroll
    for (int off = 32; off; off >>= 1) s += __shfl_xor(s, off);
    __shared__ int wsum[4];
    if ((t & 63) == 0) wsum[t >> 6] = s;
    __syncthreads();
    if (t == 0) bsum[blockIdx.x] = wsum[0] + wsum[1] + wsum[2] + wsum[3];
}

// ---------------- phase B — scan the (<=256) block sums; writes rowptr[n] = total ----------------
__global__ __launch_bounds__(256) void scan_phaseB(const int* __restrict__ bsum, int nb,
                                                   int* __restrict__ bpre,
                                                   int* __restrict__ rowptr, int n) {
    int t = threadIdx.x;
    int lane = t & 63, wave = t >> 6;
    int v = (t < nb) ? bsum[t] : 0;
    int inc = v;
#pragma unroll
    for (int off = 1; off < 64; off <<= 1) {
        int u = __shfl_up(inc, off);
        if (lane >= off) inc += u;
    }
    __shared__ int wtot[4];
    if (lane == 63) wtot[wave] = inc;
    __syncthreads();
    int wbase = 0;
    for (int w = 0; w < wave; ++w) wbase += wtot[w];
    inc += wbase;
    if (t < nb) bpre[t] = inc - v;
    if (t == 255) rowptr[n] = inc;
}

// ---------------- phase C — final exclusive scan; fuses dinv = 1/sqrt(deg+1) ----------------
__global__ __launch_bounds__(256) void scan_phaseC(const int* __restrict__ deg, int n,
                                                   const int* __restrict__ bpre,
                                                   int* __restrict__ rowptr,
                                                   int* __restrict__ cursor,
                                                   float* __restrict__ dinv) {
    int t = threadIdx.x;
    int lane = t & 63, wave = t >> 6;
    int base = blockIdx.x * 1024 + t * 4;
    int d[4];
    int s = 0;
#pragma unroll
    for (int j = 0; j < 4; ++j) {
        int i = base + j;
        d[j] = (i < n) ? deg[i] : 0;
        s += d[j];
    }
    int inc = s;
#pragma unroll
    for (int off = 1; off < 64; off <<= 1) {
        int u = __shfl_up(inc, off);
        if (lane >= off) inc += u;
    }
    __shared__ int wtot[4];
    if (lane == 63) wtot[wave] = inc;
    __syncthreads();
    int wbase = 0;
    for (int w = 0; w < wave; ++w) wbase += wtot[w];
    int run = bpre[blockIdx.x] + wbase + (inc - s);  // exclusive base for this thread
#pragma unroll
    for (int j = 0; j < 4; ++j) {
        int i = base + j;
        if (i < n) {
            rowptr[i] = run;
            cursor[i] = run;
            dinv[i] = 1.0f / sqrtf((float)d[j] + 1.0f);
            run += d[j];
        }
    }
}

// ---------------- bin edges into CSR slots ----------------
__global__ __launch_bounds__(256) void bin_kernel(const int* __restrict__ ei, int E,
                                                  int* __restrict__ cursor,
                                                  int* __restrict__ csr_src) {
    int gid = blockIdx.x * 256 + threadIdx.x;
    if (gid < E) {
        int src = ei[gid];
        int dst = ei[E + gid];
        int pos = atomicAdd(&cursor[dst], 1);
        csr_src[pos] = src;
    }
}

// ---------------- graph_ptr from sorted batch: gp[g] = first node with batch >= g ----------------
__global__ __launch_bounds__(256) void graph_ptr_kernel(const int* __restrict__ batch, int n,
                                                        int G, int* __restrict__ gp) {
    int i = blockIdx.x * 256 + threadIdx.x;
    if (i >= n) return;
    int bi = batch[i];
    if (i == 0) {
        for (int g = 0; g <= bi; ++g) gp[g] = 0;
    } else {
        int bp = batch[i - 1];
        for (int g = bp + 1; g <= bi; ++g) gp[g] = i;
    }
    if (i == n - 1) {
        for (int g = bi + 1; g <= G; ++g) gp[g] = n;
    }
}

// ---------------- prep: W -> hi/lo bf16 fragments in MFMA-ready layout ----------------
// For matrix m (0=W_in, 1..3=Wc[l]): B[k][o] = W[o][k]. Fragment layout for 16x16x32:
// lane = kg*16 + oc (kg=lane>>4, oc=lane&15) holds B[kk*32+kg*8+j][t*16+oc], j=0..7.
// Storage: Wfrag[m*32768 + r] (hi) and [m*32768 + 16384 + r] (lo),
// r = t*2048 + kk*512 + lane*8 + j  -> (t,kk,lane) groups are 16B-contiguous.
__global__ __launch_bounds__(256) void prep_wfrag(const float* __restrict__ Win,
                                                  const float* __restrict__ Wc,
                                                  unsigned short* __restrict__ Wfrag) {
    int gid = blockIdx.x * 256 + threadIdx.x;
    if (gid >= 4 * 16384) return;
    int m = gid >> 14;
    int r = gid & 16383;
    int t = r >> 11;
    int kk = (r >> 9) & 3;
    int lane = (r >> 3) & 63;
    int j = r & 7;
    int kg = lane >> 4, oc = lane & 15;
    int o = t * 16 + oc;
    int k = kk * 32 + kg * 8 + j;
    const float* src = (m == 0) ? Win : (Wc + (m - 1) * 16384);
    float w = src[o * 128 + k];
    unsigned short hi = f2bf(w);
    unsigned short lo = f2bf(w - bf2f(hi));
    Wfrag[m * 32768 + r] = hi;
    Wfrag[m * 32768 + 16384 + r] = lo;
}

// ---------------- MFMA GEMM: C[n][128] = A[n][128] @ W^T via split-bf16 (hi/lo) ----------------
// 3-term product: a_hi*w_hi + a_hi*w_lo + a_lo*w_hi (error ~2^-16 rel; lo*lo dropped).
// Block = 256 thr = 4 waves; wave w owns rows blk*64+w*16 .. +15, all 128 cols.
// B (hi+lo, 64 KB) staged once in LDS; A fragments loaded global->reg (wave reads
// 16 rows x 32 consecutive k -> maps directly to the fragment layout).
// C/D layout (verified m89): col=lane&15, row=(lane>>4)*4+reg.
__global__ __launch_bounds__(256) void gemm_mfma(const float* __restrict__ A,
                                                 const unsigned short* __restrict__ Wfrag,
                                                 const float* __restrict__ bias,
                                                 const float* __restrict__ scale,
                                                 float* __restrict__ C, int n, int use_bias,
                                                 int use_scale) {
    __shared__ unsigned short sB[32768];  // 64 KB: hi [0..16383], lo [16384..32767]
    int tid = threadIdx.x;
    int wave = tid >> 6;
    int lane = tid & 63;
    int wbase = blockIdx.x * 64 + wave * 16;

    // stage B fragments (hi+lo) into LDS: 4096 float4 / 256 threads = 16 iters
    {
        const float4* src = (const float4*)Wfrag;
        float4* dst = (float4*)sB;
#pragma unroll
        for (int i = 0; i < 16; ++i) dst[tid + i * 256] = src[tid + i * 256];
    }
    __syncthreads();

    f32x4 acc[8];
#pragma unroll
    for (int t = 0; t < 8; ++t) acc[t] = (f32x4){0.f, 0.f, 0.f, 0.f};

    int arow = wbase + (lane & 15);
    int kg8 = (lane >> 4) * 8;

#pragma unroll
    for (int kk = 0; kk < 4; ++kk) {
        // A fragment: 8 consecutive k at [arow][kk*32 + kg8]
        float4 v0 = {0.f, 0.f, 0.f, 0.f}, v1 = {0.f, 0.f, 0.f, 0.f};
        if (arow < n) {
            const float* ap = A + (size_t)arow * 128 + kk * 32 + kg8;
            v0 = *(const float4*)(ap);
            v1 = *(const float4*)(ap + 4);
        }
        float fs[8] = {v0.x, v0.y, v0.z, v0.w, v1.x, v1.y, v1.z, v1.w};
        bf16x8 ahi, alo;
#pragma unroll
        for (int j = 0; j < 8; ++j) {
            unsigned short h = f2bf(fs[j]);
            ahi[j] = (short)h;
            alo[j] = (short)f2bf(fs[j] - bf2f(h));
        }
#pragma unroll
        for (int t = 0; t < 8; ++t) {
            int boff = ((t * 4 + kk) * 64 + lane) * 8;  // in shorts
            bf16x8 bhi = *(const bf16x8*)(sB + boff);
            bf16x8 blo = *(const bf16x8*)(sB + 16384 + boff);
            acc[t] = __builtin_amdgcn_mfma_f32_16x16x32_bf16(ahi, bhi, acc[t], 0, 0, 0);
            acc[t] = __builtin_amdgcn_mfma_f32_16x16x32_bf16(ahi, blo, acc[t], 0, 0, 0);
            acc[t] = __builtin_amdgcn_mfma_f32_16x16x32_bf16(alo, bhi, acc[t], 0, 0, 0);
        }
    }

    // epilogue: optional bias[col] add, optional scale[row] mul, scalar stores
    int colbase = lane & 15;
    int rquad = (lane >> 4) * 4;
    float bvs[8];
#pragma unroll
    for (int t = 0; t < 8; ++t) bvs[t] = use_bias ? bias[t * 16 + colbase] : 0.0f;
#pragma unroll
    for (int r = 0; r < 4; ++r) {
        int gr = wbase + rquad + r;
        if (gr >= n) continue;
        float s = use_scale ? scale[gr] : 1.0f;
        float* crow = C + (size_t)gr * 128;
#pragma unroll
        for (int t = 0; t < 8; ++t) {
            crow[t * 16 + colbase] = (acc[t][r] + bvs[t]) * s;
        }
    }
}

// ---------------- fused CSR gather + self-loop + bias + LayerNorm + ReLU + residual ----------------
// hws rows are PRE-SCALED by dinv[row] (gemm epilogue). 8-deep MLP edge loop.
__global__ __launch_bounds__(256) void gather_ln(const float* __restrict__ hws,
                                                 float* __restrict__ h,
                                                 const int* __restrict__ rowptr,
                                                 const int* __restrict__ csr_src,
                                                 const float* __restrict__ dinv,
                                                 const float* __restrict__ bc,
                                                 const float* __restrict__ gamma,
                                                 const float* __restrict__ beta, int n) {
    int wid = (blockIdx.x * 256 + threadIdx.x) >> 6;
    int lane = threadIdx.x & 63;
    if (wid >= n) return;
    int i = wid;
    float di = dinv[i];
    int e0 = rowptr[i], e1 = rowptr[i + 1];
    int c0 = lane * 2;
    const float* hb = hws + c0;

    float2 s = *(const float2*)(hb + (size_t)i * HIDDIM);
    int e = e0;
    for (; e + 8 <= e1; e += 8) {
        int i0 = csr_src[e + 0], i1 = csr_src[e + 1], i2 = csr_src[e + 2], i3 = csr_src[e + 3];
        int i4 = csr_src[e + 4], i5 = csr_src[e + 5], i6 = csr_src[e + 6], i7 = csr_src[e + 7];
        float2 v0 = *(const float2*)(hb + (size_t)i0 * HIDDIM);
        float2 v1 = *(const float2*)(hb + (size_t)i1 * HIDDIM);
        float2 v2 = *(const float2*)(hb + (size_t)i2 * HIDDIM);
        float2 v3 = *(const float2*)(hb + (size_t)i3 * HIDDIM);
        float2 v4 = *(const float2*)(hb + (size_t)i4 * HIDDIM);
        float2 v5 = *(const float2*)(hb + (size_t)i5 * HIDDIM);
        float2 v6 = *(const float2*)(hb + (size_t)i6 * HIDDIM);
        float2 v7 = *(const float2*)(hb + (size_t)i7 * HIDDIM);
        s.x += v0.x; s.y += v0.y;  s.x += v1.x; s.y += v1.y;
        s.x += v2.x; s.y += v2.y;  s.x += v3.x; s.y += v3.y;
        s.x += v4.x; s.y += v4.y;  s.x += v5.x; s.y += v5.y;
        s.x += v6.x; s.y += v6.y;  s.x += v7.x; s.y += v7.y;
    }
    if (e + 4 <= e1) {
        int i0 = csr_src[e + 0], i1 = csr_src[e + 1], i2 = csr_src[e + 2], i3 = csr_src[e + 3];
        float2 v0 = *(const float2*)(hb + (size_t)i0 * HIDDIM);
        float2 v1 = *(const float2*)(hb + (size_t)i1 * HIDDIM);
        float2 v2 = *(const float2*)(hb + (size_t)i2 * HIDDIM);
        float2 v3 = *(const float2*)(hb + (size_t)i3 * HIDDIM);
        s.x += v0.x; s.y += v0.y;  s.x += v1.x; s.y += v1.y;
        s.x += v2.x; s.y += v2.y;  s.x += v3.x; s.y += v3.y;
        e += 4;
    }
    for (; e < e1; ++e) {
        int sc = csr_src[e];
        float2 v = *(const float2*)(hb + (size_t)sc * HIDDIM);
        s.x += v.x; s.y += v.y;
    }
    float2 bcv = *(const float2*)(bc + c0);
    float vx = di * s.x + bcv.x;
    float vy = di * s.y + bcv.y;

    float s1 = vx + vy, s2 = vx * vx + vy * vy;
#pragma unroll
    for (int off = 32; off; off >>= 1) {
        s1 += __shfl_xor(s1, off);
        s2 += __shfl_xor(s2, off);
    }
    float mu = s1 * (1.0f / 128.0f);
    float var = s2 * (1.0f / 128.0f) - mu * mu;
    float rs = 1.0f / sqrtf(var + 1e-5f);

    float2 gm = *(const float2*)(gamma + c0);
    float2 bt = *(const float2*)(beta + c0);
    float yx = fmaxf((vx - mu) * rs * gm.x + bt.x, 0.0f);
    float yy = fmaxf((vy - mu) * rs * gm.y + bt.y, 0.0f);

    float2 hv = *(float2*)(h + (size_t)i * HIDDIM + c0);
    hv.x += yx; hv.y += yy;
    *(float2*)(h + (size_t)i * HIDDIM + c0) = hv;
}

// ---------------- fused segmented mean-pool + MLP head (batch is SORTED) ----------------
__global__ __launch_bounds__(128) void pool_mlp_kernel(const float* __restrict__ h,
                                                       const int* __restrict__ gp,
                                                       const float* __restrict__ W1,
                                                       const float* __restrict__ b1,
                                                       const float* __restrict__ W2,
                                                       const float* __restrict__ b2,
                                                       float* __restrict__ out, int G) {
    __shared__ float sp[128];
    int g = blockIdx.x;
    if (g >= G) return;
    int t = threadIdx.x;
    int s = gp[g], e = gp[g + 1];
    float acc = 0.0f;
    for (int i = s; i < e; ++i) acc += h[(size_t)i * HIDDIM + t];
    float cnt = fmaxf((float)(e - s), 1.0f);
    sp[t] = acc / cnt;
    __syncthreads();
    if (t < 64) {
        const float* wr = W1 + t * HIDDIM;
        float a = 0.0f;
#pragma unroll 8
        for (int k = 0; k < HIDDIM; k += 4) {
            float4 p = *(const float4*)(sp + k);  // same addr all lanes -> LDS broadcast
            float4 w = *(const float4*)(wr + k);
            a += p.x * w.x + p.y * w.y + p.z * w.z + p.w * w.w;
        }
        float h1 = fmaxf(a + b1[t], 0.0f);
        float c = h1 * W2[t];
#pragma unroll
        for (int off = 32; off; off >>= 1) c += __shfl_xor(c, off);
        if (t == 0) out[g] = c + b2[0];
    }
}

extern "C" void kernel_launch(void* const* d_in, const int* in_sizes, int n_in,
                              void* d_out, int out_size, void* d_ws, size_t ws_size,
                              hipStream_t stream) {
    const float* x      = (const float*)d_in[0];
    const int*   ei     = (const int*)d_in[1];
    const int*   batch  = (const int*)d_in[2];
    const float* W_in   = (const float*)d_in[3];
    const float* b_in   = (const float*)d_in[4];
    const float* Wc     = (const float*)d_in[5];
    const float* bc     = (const float*)d_in[6];
    const float* gamma  = (const float*)d_in[7];
    const float* beta   = (const float*)d_in[8];
    const float* W1     = (const float*)d_in[9];
    const float* b1     = (const float*)d_in[10];
    const float* W2     = (const float*)d_in[11];
    const float* b2     = (const float*)d_in[12];
    float* out = (float*)d_out;

    const int N = in_sizes[2];
    const int E = in_sizes[1] / 2;
    const int G = out_size;  // OUT_DIM == 1
    const int NB = (N + 1023) / 1024;

    // workspace carve-up (256B aligned)
    char* ws = (char*)d_ws;
    size_t off = 0;
    auto alloc = [&](size_t bytes) {
        size_t o = off;
        off = (off + bytes + 255) & ~(size_t)255;
        return o;
    };
    int*   deg     = (int*)(ws + alloc((size_t)N * 4));
    int*   rowptr  = (int*)(ws + alloc((size_t)(N + 1) * 4));
    int*   cursor  = (int*)(ws + alloc((size_t)N * 4));
    int*   csr_src = (int*)(ws + alloc((size_t)E * 4));
    float* dinv    = (float*)(ws + alloc((size_t)N * 4));
    unsigned short* Wfrag = (unsigned short*)(ws + alloc((size_t)4 * 32768 * 2));
    float* h       = (float*)(ws + alloc((size_t)N * 128 * 4));
    float* hws     = (float*)(ws + alloc((size_t)N * 128 * 4));
    int*   gp      = (int*)(ws + alloc((size_t)(G + 1) * 4));
    int*   bsum    = (int*)(ws + alloc((size_t)NB * 4));
    int*   bpre    = (int*)(ws + alloc((size_t)NB * 4));
    (void)ws_size; (void)n_in;

    // ---- graph preprocessing (per-call: ws is re-poisoned each launch) ----
    hipMemsetAsync(deg, 0, (size_t)N * 4, stream);
    deg_kernel<<<(E + 255) / 256, 256, 0, stream>>>(ei, E, deg);
    scan_phaseA<<<NB, 256, 0, stream>>>(deg, N, bsum);
    scan_phaseB<<<1, 256, 0, stream>>>(bsum, NB, bpre, rowptr, N);
    scan_phaseC<<<NB, 256, 0, stream>>>(deg, N, bpre, rowptr, cursor, dinv);
    bin_kernel<<<(E + 255) / 256, 256, 0, stream>>>(ei, E, cursor, csr_src);
    graph_ptr_kernel<<<(N + 255) / 256, 256, 0, stream>>>(batch, N, G, gp);
    prep_wfrag<<<(4 * 16384 + 255) / 256, 256, 0, stream>>>(W_in, Wc, Wfrag);

    // ---- input projection (MFMA split-bf16) ----
    int mblocks = (N + 63) / 64;
    gemm_mfma<<<mblocks, 256, 0, stream>>>(x, Wfrag, b_in, nullptr, h, N, 1, 0);

    // ---- 3 GCN layers ----
    for (int l = 0; l < 3; ++l) {
        // hws = (h @ Wc[l]^T) * dinv[row]  (pre-scaled for the gather)
        gemm_mfma<<<mblocks, 256, 0, stream>>>(h, Wfrag + (1 + l) * 32768, nullptr, dinv,
                                               hws, N, 0, 1);
        gather_ln<<<(N + 3) / 4, 256, 0, stream>>>(hws, h, rowptr, csr_src, dinv,
                                                   bc + l * 128, gamma + l * 128,
                                                   beta + l * 128, N);
    }

    // ---- fused pooling + MLP head ----
    pool_mlp_kernel<<<G, 128, 0, stream>>>(h, gp, W1, b1, W2, b2, out, G);
}

// Round 6
// 395.922 us; speedup vs baseline: 2.1874x; 1.1943x over previous
//
#include <hip/hip_runtime.h>
#include <hip/hip_bf16.h>

#define HIDDIM 128

typedef short bf16x8 __attribute__((ext_vector_type(8)));
typedef float f32x4 __attribute__((ext_vector_type(4)));

__device__ inline unsigned short f2bf(float f) {
    unsigned u = __float_as_uint(f);
    unsigned r = (u + 0x7fffu + ((u >> 16) & 1u)) >> 16;  // RNE
    return (unsigned short)r;
}
__device__ inline float bf2f(unsigned short s) {
    return __uint_as_float(((unsigned)s) << 16);
}

// ---------------- degree count (int atomics over dst) ----------------
__global__ __launch_bounds__(256) void deg_kernel(const int* __restrict__ ei, int E,
                                                  int* __restrict__ deg) {
    int gid = blockIdx.x * 256 + threadIdx.x;
    if (gid < E) atomicAdd(&deg[ei[E + gid]], 1);
}

// ---------------- hierarchical scan: phase A — per-block sums (1024 elems/block) ----------------
__global__ __launch_bounds__(256) void scan_phaseA(const int* __restrict__ deg, int n,
                                                   int* __restrict__ bsum) {
    int t = threadIdx.x;
    int base = blockIdx.x * 1024 + t * 4;
    int s = 0;
#pragma unroll
    for (int j = 0; j < 4; ++j) {
        int i = base + j;
        if (i < n) s += deg[i];
    }
#pragma unroll
    for (int off = 32; off; off >>= 1) s += __shfl_xor(s, off);
    __shared__ int wsum[4];
    if ((t & 63) == 0) wsum[t >> 6] = s;
    __syncthreads();
    if (t == 0) bsum[blockIdx.x] = wsum[0] + wsum[1] + wsum[2] + wsum[3];
}

// ---------------- phase B — scan the (<=256) block sums; writes rowptr[n] = total ----------------
__global__ __launch_bounds__(256) void scan_phaseB(const int* __restrict__ bsum, int nb,
                                                   int* __restrict__ bpre,
                                                   int* __restrict__ rowptr, int n) {
    int t = threadIdx.x;
    int lane = t & 63, wave = t >> 6;
    int v = (t < nb) ? bsum[t] : 0;
    int inc = v;
#pragma unroll
    for (int off = 1; off < 64; off <<= 1) {
        int u = __shfl_up(inc, off);
        if (lane >= off) inc += u;
    }
    __shared__ int wtot[4];
    if (lane == 63) wtot[wave] = inc;
    __syncthreads();
    int wbase = 0;
    for (int w = 0; w < wave; ++w) wbase += wtot[w];
    inc += wbase;
    if (t < nb) bpre[t] = inc - v;
    if (t == 255) rowptr[n] = inc;
}

// ---------------- phase C — final exclusive scan; fuses dinv = 1/sqrt(deg+1) ----------------
__global__ __launch_bounds__(256) void scan_phaseC(const int* __restrict__ deg, int n,
                                                   const int* __restrict__ bpre,
                                                   int* __restrict__ rowptr,
                                                   int* __restrict__ cursor,
                                                   float* __restrict__ dinv) {
    int t = threadIdx.x;
    int lane = t & 63, wave = t >> 6;
    int base = blockIdx.x * 1024 + t * 4;
    int d[4];
    int s = 0;
#pragma unroll
    for (int j = 0; j < 4; ++j) {
        int i = base + j;
        d[j] = (i < n) ? deg[i] : 0;
        s += d[j];
    }
    int inc = s;
#pragma unroll
    for (int off = 1; off < 64; off <<= 1) {
        int u = __shfl_up(inc, off);
        if (lane >= off) inc += u;
    }
    __shared__ int wtot[4];
    if (lane == 63) wtot[wave] = inc;
    __syncthreads();
    int wbase = 0;
    for (int w = 0; w < wave; ++w) wbase += wtot[w];
    int run = bpre[blockIdx.x] + wbase + (inc - s);  // exclusive base for this thread
#pragma unroll
    for (int j = 0; j < 4; ++j) {
        int i = base + j;
        if (i < n) {
            rowptr[i] = run;
            cursor[i] = run;
            dinv[i] = 1.0f / sqrtf((float)d[j] + 1.0f);
            run += d[j];
        }
    }
}

// ---------------- bin edges into CSR slots ----------------
__global__ __launch_bounds__(256) void bin_kernel(const int* __restrict__ ei, int E,
                                                  int* __restrict__ cursor,
                                                  int* __restrict__ csr_src) {
    int gid = blockIdx.x * 256 + threadIdx.x;
    if (gid < E) {
        int src = ei[gid];
        int dst = ei[E + gid];
        int pos = atomicAdd(&cursor[dst], 1);
        csr_src[pos] = src;
    }
}

// ---------------- graph_ptr from sorted batch: gp[g] = first node with batch >= g ----------------
__global__ __launch_bounds__(256) void graph_ptr_kernel(const int* __restrict__ batch, int n,
                                                        int G, int* __restrict__ gp) {
    int i = blockIdx.x * 256 + threadIdx.x;
    if (i >= n) return;
    int bi = batch[i];
    if (i == 0) {
        for (int g = 0; g <= bi; ++g) gp[g] = 0;
    } else {
        int bp = batch[i - 1];
        for (int g = bp + 1; g <= bi; ++g) gp[g] = i;
    }
    if (i == n - 1) {
        for (int g = bi + 1; g <= G; ++g) gp[g] = n;
    }
}

// ---------------- prep: W -> hi/lo bf16 fragments in MFMA-ready layout ----------------
// For matrix m (0=W_in, 1..3=Wc[l]): B[k][o] = W[o][k]. Fragment layout for 16x16x32:
// lane = kg*16 + oc (kg=lane>>4, oc=lane&15) holds B[kk*32+kg*8+j][t*16+oc], j=0..7.
// Storage: Wfrag[m*32768 + r] (hi) and [m*32768 + 16384 + r] (lo),
// r = t*2048 + kk*512 + lane*8 + j  -> (t,kk,lane) groups are 16B-contiguous.
__global__ __launch_bounds__(256) void prep_wfrag(const float* __restrict__ Win,
                                                  const float* __restrict__ Wc,
                                                  unsigned short* __restrict__ Wfrag) {
    int gid = blockIdx.x * 256 + threadIdx.x;
    if (gid >= 4 * 16384) return;
    int m = gid >> 14;
    int r = gid & 16383;
    int t = r >> 11;
    int kk = (r >> 9) & 3;
    int lane = (r >> 3) & 63;
    int j = r & 7;
    int kg = lane >> 4, oc = lane & 15;
    int o = t * 16 + oc;
    int k = kk * 32 + kg * 8 + j;
    const float* src = (m == 0) ? Win : (Wc + (m - 1) * 16384);
    float w = src[o * 128 + k];
    unsigned short hi = f2bf(w);
    unsigned short lo = f2bf(w - bf2f(hi));
    Wfrag[m * 32768 + r] = hi;
    Wfrag[m * 32768 + 16384 + r] = lo;
}

// ---------------- MFMA GEMM: C[n][128] = A[n][128] @ W^T via split-bf16 (hi/lo) ----------------
// 3-term product: a_hi*w_hi + a_hi*w_lo + a_lo*w_hi (error ~2^-16 rel; lo*lo dropped).
// Block = 256 thr = 4 waves; wave w owns rows blk*64+w*16 .. +15, all 128 cols.
// B (hi+lo, 64 KB) staged once in LDS; A fragments loaded global->reg (wave reads
// 16 rows x 32 consecutive k -> maps directly to the fragment layout).
// C/D layout (verified m89): col=lane&15, row=(lane>>4)*4+reg.
// out_bf16: store C rows as bf16 (for the gather's halved traffic).
__global__ __launch_bounds__(256) void gemm_mfma(const float* __restrict__ A,
                                                 const unsigned short* __restrict__ Wfrag,
                                                 const float* __restrict__ bias,
                                                 const float* __restrict__ scale,
                                                 void* __restrict__ Cout, int n, int use_bias,
                                                 int use_scale, int out_bf16) {
    __shared__ unsigned short sB[32768];  // 64 KB: hi [0..16383], lo [16384..32767]
    int tid = threadIdx.x;
    int wave = tid >> 6;
    int lane = tid & 63;
    int wbase = blockIdx.x * 64 + wave * 16;

    // stage B fragments (hi+lo) into LDS: 4096 float4 / 256 threads = 16 iters
    {
        const float4* src = (const float4*)Wfrag;
        float4* dst = (float4*)sB;
#pragma unroll
        for (int i = 0; i < 16; ++i) dst[tid + i * 256] = src[tid + i * 256];
    }
    __syncthreads();

    f32x4 acc[8];
#pragma unroll
    for (int t = 0; t < 8; ++t) acc[t] = (f32x4){0.f, 0.f, 0.f, 0.f};

    int arow = wbase + (lane & 15);
    int kg8 = (lane >> 4) * 8;

#pragma unroll
    for (int kk = 0; kk < 4; ++kk) {
        // A fragment: 8 consecutive k at [arow][kk*32 + kg8]
        float4 v0 = {0.f, 0.f, 0.f, 0.f}, v1 = {0.f, 0.f, 0.f, 0.f};
        if (arow < n) {
            const float* ap = A + (size_t)arow * 128 + kk * 32 + kg8;
            v0 = *(const float4*)(ap);
            v1 = *(const float4*)(ap + 4);
        }
        float fs[8] = {v0.x, v0.y, v0.z, v0.w, v1.x, v1.y, v1.z, v1.w};
        bf16x8 ahi, alo;
#pragma unroll
        for (int j = 0; j < 8; ++j) {
            unsigned short h = f2bf(fs[j]);
            ahi[j] = (short)h;
            alo[j] = (short)f2bf(fs[j] - bf2f(h));
        }
#pragma unroll
        for (int t = 0; t < 8; ++t) {
            int boff = ((t * 4 + kk) * 64 + lane) * 8;  // in shorts
            bf16x8 bhi = *(const bf16x8*)(sB + boff);
            bf16x8 blo = *(const bf16x8*)(sB + 16384 + boff);
            acc[t] = __builtin_amdgcn_mfma_f32_16x16x32_bf16(ahi, bhi, acc[t], 0, 0, 0);
            acc[t] = __builtin_amdgcn_mfma_f32_16x16x32_bf16(ahi, blo, acc[t], 0, 0, 0);
            acc[t] = __builtin_amdgcn_mfma_f32_16x16x32_bf16(alo, bhi, acc[t], 0, 0, 0);
        }
    }

    // epilogue: optional bias[col] add, optional scale[row] mul, scalar stores
    int colbase = lane & 15;
    int rquad = (lane >> 4) * 4;
    float bvs[8];
#pragma unroll
    for (int t = 0; t < 8; ++t) bvs[t] = use_bias ? bias[t * 16 + colbase] : 0.0f;
#pragma unroll
    for (int r = 0; r < 4; ++r) {
        int gr = wbase + rquad + r;
        if (gr >= n) continue;
        float s = use_scale ? scale[gr] : 1.0f;
        if (out_bf16) {
            unsigned short* crow = (unsigned short*)Cout + (size_t)gr * 128;
#pragma unroll
            for (int t = 0; t < 8; ++t) crow[t * 16 + colbase] = f2bf((acc[t][r] + bvs[t]) * s);
        } else {
            float* crow = (float*)Cout + (size_t)gr * 128;
#pragma unroll
            for (int t = 0; t < 8; ++t) crow[t * 16 + colbase] = (acc[t][r] + bvs[t]) * s;
        }
    }
}

// ---------------- fused CSR gather + self-loop + bias + LayerNorm + ReLU + residual ----------------
// hws rows are bf16, PRE-SCALED by dinv[row] (gemm epilogue) -> 256B/row, half the request
// volume and working set (12.8MB, better per-XCD L2 hit). Accumulation in fp32.
// One wave per node; lane holds cols {2*lane, 2*lane+1}. 8-deep MLP edge loop.
__global__ __launch_bounds__(256) void gather_ln(const unsigned short* __restrict__ hws,
                                                 float* __restrict__ h,
                                                 const int* __restrict__ rowptr,
                                                 const int* __restrict__ csr_src,
                                                 const float* __restrict__ dinv,
                                                 const float* __restrict__ bc,
                                                 const float* __restrict__ gamma,
                                                 const float* __restrict__ beta, int n) {
    int wid = (blockIdx.x * 256 + threadIdx.x) >> 6;
    int lane = threadIdx.x & 63;
    if (wid >= n) return;
    int i = wid;
    float di = dinv[i];
    int e0 = rowptr[i], e1 = rowptr[i + 1];
    int c0 = lane * 2;
    const unsigned short* hb = hws + c0;

    ushort2 r0 = *(const ushort2*)(hb + (size_t)i * HIDDIM);
    float sx = bf2f(r0.x), sy = bf2f(r0.y);
    int e = e0;
    for (; e + 8 <= e1; e += 8) {
        int i0 = csr_src[e + 0], i1 = csr_src[e + 1], i2 = csr_src[e + 2], i3 = csr_src[e + 3];
        int i4 = csr_src[e + 4], i5 = csr_src[e + 5], i6 = csr_src[e + 6], i7 = csr_src[e + 7];
        ushort2 v0 = *(const ushort2*)(hb + (size_t)i0 * HIDDIM);
        ushort2 v1 = *(const ushort2*)(hb + (size_t)i1 * HIDDIM);
        ushort2 v2 = *(const ushort2*)(hb + (size_t)i2 * HIDDIM);
        ushort2 v3 = *(const ushort2*)(hb + (size_t)i3 * HIDDIM);
        ushort2 v4 = *(const ushort2*)(hb + (size_t)i4 * HIDDIM);
        ushort2 v5 = *(const ushort2*)(hb + (size_t)i5 * HIDDIM);
        ushort2 v6 = *(const ushort2*)(hb + (size_t)i6 * HIDDIM);
        ushort2 v7 = *(const ushort2*)(hb + (size_t)i7 * HIDDIM);
        sx += bf2f(v0.x); sy += bf2f(v0.y);  sx += bf2f(v1.x); sy += bf2f(v1.y);
        sx += bf2f(v2.x); sy += bf2f(v2.y);  sx += bf2f(v3.x); sy += bf2f(v3.y);
        sx += bf2f(v4.x); sy += bf2f(v4.y);  sx += bf2f(v5.x); sy += bf2f(v5.y);
        sx += bf2f(v6.x); sy += bf2f(v6.y);  sx += bf2f(v7.x); sy += bf2f(v7.y);
    }
    if (e + 4 <= e1) {
        int i0 = csr_src[e + 0], i1 = csr_src[e + 1], i2 = csr_src[e + 2], i3 = csr_src[e + 3];
        ushort2 v0 = *(const ushort2*)(hb + (size_t)i0 * HIDDIM);
        ushort2 v1 = *(const ushort2*)(hb + (size_t)i1 * HIDDIM);
        ushort2 v2 = *(const ushort2*)(hb + (size_t)i2 * HIDDIM);
        ushort2 v3 = *(const ushort2*)(hb + (size_t)i3 * HIDDIM);
        sx += bf2f(v0.x); sy += bf2f(v0.y);  sx += bf2f(v1.x); sy += bf2f(v1.y);
        sx += bf2f(v2.x); sy += bf2f(v2.y);  sx += bf2f(v3.x); sy += bf2f(v3.y);
        e += 4;
    }
    for (; e < e1; ++e) {
        int sc = csr_src[e];
        ushort2 v = *(const ushort2*)(hb + (size_t)sc * HIDDIM);
        sx += bf2f(v.x); sy += bf2f(v.y);
    }
    float2 bcv = *(const float2*)(bc + c0);
    float vx = di * sx + bcv.x;
    float vy = di * sy + bcv.y;

    float s1 = vx + vy, s2 = vx * vx + vy * vy;
#pragma unroll
    for (int off = 32; off; off >>= 1) {
        s1 += __shfl_xor(s1, off);
        s2 += __shfl_xor(s2, off);
    }
    float mu = s1 * (1.0f / 128.0f);
    float var = s2 * (1.0f / 128.0f) - mu * mu;
    float rs = 1.0f / sqrtf(var + 1e-5f);

    float2 gm = *(const float2*)(gamma + c0);
    float2 bt = *(const float2*)(beta + c0);
    float yx = fmaxf((vx - mu) * rs * gm.x + bt.x, 0.0f);
    float yy = fmaxf((vy - mu) * rs * gm.y + bt.y, 0.0f);

    float2 hv = *(float2*)(h + (size_t)i * HIDDIM + c0);
    hv.x += yx; hv.y += yy;
    *(float2*)(h + (size_t)i * HIDDIM + c0) = hv;
}

// ---------------- fused segmented mean-pool + MLP head (batch is SORTED) ----------------
__global__ __launch_bounds__(128) void pool_mlp_kernel(const float* __restrict__ h,
                                                       const int* __restrict__ gp,
                                                       const float* __restrict__ W1,
                                                       const float* __restrict__ b1,
                                                       const float* __restrict__ W2,
                                                       const float* __restrict__ b2,
                                                       float* __restrict__ out, int G) {
    __shared__ float sp[128];
    int g = blockIdx.x;
    if (g >= G) return;
    int t = threadIdx.x;
    int s = gp[g], e = gp[g + 1];
    float acc = 0.0f;
    for (int i = s; i < e; ++i) acc += h[(size_t)i * HIDDIM + t];
    float cnt = fmaxf((float)(e - s), 1.0f);
    sp[t] = acc / cnt;
    __syncthreads();
    if (t < 64) {
        const float* wr = W1 + t * HIDDIM;
        float a = 0.0f;
#pragma unroll 8
        for (int k = 0; k < HIDDIM; k += 4) {
            float4 p = *(const float4*)(sp + k);  // same addr all lanes -> LDS broadcast
            float4 w = *(const float4*)(wr + k);
            a += p.x * w.x + p.y * w.y + p.z * w.z + p.w * w.w;
        }
        float h1 = fmaxf(a + b1[t], 0.0f);
        float c = h1 * W2[t];
#pragma unroll
        for (int off = 32; off; off >>= 1) c += __shfl_xor(c, off);
        if (t == 0) out[g] = c + b2[0];
    }
}

extern "C" void kernel_launch(void* const* d_in, const int* in_sizes, int n_in,
                              void* d_out, int out_size, void* d_ws, size_t ws_size,
                              hipStream_t stream) {
    const float* x      = (const float*)d_in[0];
    const int*   ei     = (const int*)d_in[1];
    const int*   batch  = (const int*)d_in[2];
    const float* W_in   = (const float*)d_in[3];
    const float* b_in   = (const float*)d_in[4];
    const float* Wc     = (const float*)d_in[5];
    const float* bc     = (const float*)d_in[6];
    const float* gamma  = (const float*)d_in[7];
    const float* beta   = (const float*)d_in[8];
    const float* W1     = (const float*)d_in[9];
    const float* b1     = (const float*)d_in[10];
    const float* W2     = (const float*)d_in[11];
    const float* b2     = (const float*)d_in[12];
    float* out = (float*)d_out;

    const int N = in_sizes[2];
    const int E = in_sizes[1] / 2;
    const int G = out_size;  // OUT_DIM == 1
    const int NB = (N + 1023) / 1024;

    // workspace carve-up (256B aligned)
    char* ws = (char*)d_ws;
    size_t off = 0;
    auto alloc = [&](size_t bytes) {
        size_t o = off;
        off = (off + bytes + 255) & ~(size_t)255;
        return o;
    };
    int*   deg     = (int*)(ws + alloc((size_t)N * 4));
    int*   rowptr  = (int*)(ws + alloc((size_t)(N + 1) * 4));
    int*   cursor  = (int*)(ws + alloc((size_t)N * 4));
    int*   csr_src = (int*)(ws + alloc((size_t)E * 4));
    float* dinv    = (float*)(ws + alloc((size_t)N * 4));
    unsigned short* Wfrag = (unsigned short*)(ws + alloc((size_t)4 * 32768 * 2));
    float* h       = (float*)(ws + alloc((size_t)N * 128 * 4));
    unsigned short* hws = (unsigned short*)(ws + alloc((size_t)N * 128 * 2));
    int*   gp      = (int*)(ws + alloc((size_t)(G + 1) * 4));
    int*   bsum    = (int*)(ws + alloc((size_t)NB * 4));
    int*   bpre    = (int*)(ws + alloc((size_t)NB * 4));
    (void)ws_size; (void)n_in;

    // ---- graph preprocessing (per-call: ws is re-poisoned each launch) ----
    hipMemsetAsync(deg, 0, (size_t)N * 4, stream);
    deg_kernel<<<(E + 255) / 256, 256, 0, stream>>>(ei, E, deg);
    scan_phaseA<<<NB, 256, 0, stream>>>(deg, N, bsum);
    scan_phaseB<<<1, 256, 0, stream>>>(bsum, NB, bpre, rowptr, N);
    scan_phaseC<<<NB, 256, 0, stream>>>(deg, N, bpre, rowptr, cursor, dinv);
    bin_kernel<<<(E + 255) / 256, 256, 0, stream>>>(ei, E, cursor, csr_src);
    graph_ptr_kernel<<<(N + 255) / 256, 256, 0, stream>>>(batch, N, G, gp);
    prep_wfrag<<<(4 * 16384 + 255) / 256, 256, 0, stream>>>(W_in, Wc, Wfrag);

    // ---- input projection (MFMA split-bf16), fp32 out ----
    int mblocks = (N + 63) / 64;
    gemm_mfma<<<mblocks, 256, 0, stream>>>(x, Wfrag, b_in, nullptr, h, N, 1, 0, 0);

    // ---- 3 GCN layers ----
    for (int l = 0; l < 3; ++l) {
        // hws = bf16( (h @ Wc[l]^T) * dinv[row] )  (pre-scaled for the gather)
        gemm_mfma<<<mblocks, 256, 0, stream>>>(h, Wfrag + (1 + l) * 32768, nullptr, dinv,
                                               hws, N, 0, 1, 1);
        gather_ln<<<(N + 3) / 4, 256, 0, stream>>>(hws, h, rowptr, csr_src, dinv,
                                                   bc + l * 128, gamma + l * 128,
                                                   beta + l * 128, N);
    }

    // ---- fused pooling + MLP head ----
    pool_mlp_kernel<<<G, 128, 0, stream>>>(h, gp, W1, b1, W2, b2, out, G);
}

// Round 7
// 331.984 us; speedup vs baseline: 2.6087x; 1.1926x over previous
//
#include <hip/hip_runtime.h>
#include <hip/hip_bf16.h>

#define HIDDIM 128
#define CAP 4096           // slab capacity per bucket (mean fill ~2046, 45 sigma headroom)

typedef short bf16x8 __attribute__((ext_vector_type(8)));
typedef float f32x4 __attribute__((ext_vector_type(4)));

__device__ inline unsigned short f2bf(float f) {
    unsigned u = __float_as_uint(f);
    unsigned r = (u + 0x7fffu + ((u >> 16) & 1u)) >> 16;  // RNE
    return (unsigned short)r;
}
__device__ inline float bf2f(unsigned short s) {
    return __uint_as_float(((unsigned)s) << 16);
}

// ---------------- init bucket cursors: gcursor[b] = b*CAP ----------------
__global__ __launch_bounds__(256) void init_gcursor(int* __restrict__ gcursor, int nbuck) {
    int b = blockIdx.x * 256 + threadIdx.x;
    if (b < nbuck) gcursor[b] = b * CAP;
}

// ---------------- pass 1: bucket-scatter edges into per-bucket slabs ----------------
// bucket = dst>>7 (128 nodes/bucket). Per 2048-edge chunk: LDS-count per bucket, ONE global
// atomicAdd per nonempty bucket reserves a contiguous slab run, then packed records
// (src<<7 | dst&127) are written into the run. Writes from one block = one XCD = good
// write-combining (vs. old bin_kernel's 16x partial-line amplification).
__global__ __launch_bounds__(256) void bucket_scatter(const int* __restrict__ ei, int E,
                                                      int* __restrict__ gcursor,
                                                      unsigned* __restrict__ ebuf, int nbuck) {
    __shared__ int lcount[512];
    __shared__ int lbase[512];
    int t = threadIdx.x;
    int cb = blockIdx.x * 2048;
    lcount[t] = 0;
    lcount[t + 256] = 0;
    __syncthreads();

    int bkt[8];
    int lpos[8];
    unsigned pk[8];
#pragma unroll
    for (int j = 0; j < 8; ++j) {
        int e = cb + j * 256 + t;
        if (e < E) {
            int s_ = ei[e];
            int d_ = ei[E + e];
            bkt[j] = d_ >> 7;
            pk[j] = ((unsigned)s_ << 7) | (unsigned)(d_ & 127);
            lpos[j] = atomicAdd(&lcount[bkt[j]], 1);
        } else {
            bkt[j] = -1;
            lpos[j] = 0;
            pk[j] = 0;
        }
    }
    __syncthreads();
    for (int bb = t; bb < nbuck; bb += 256) {
        int c = lcount[bb];
        lbase[bb] = c ? atomicAdd(&gcursor[bb], c) : 0;
    }
    __syncthreads();
#pragma unroll
    for (int j = 0; j < 8; ++j) {
        if (bkt[j] >= 0) {
            unsigned idx = (unsigned)lbase[bkt[j]] + (unsigned)lpos[j];
            if (idx < (unsigned)(bkt[j] + 1) * CAP)  // slab overflow guard (never fires)
                ebuf[idx] = pk[j];
        }
    }
}

// ---------------- pass 2: scan bucket counts -> bptr; rowptr[N] = total ----------------
__global__ __launch_bounds__(256) void bucket_scan(const int* __restrict__ gcursor, int nbuck,
                                                   int* __restrict__ bptr,
                                                   int* __restrict__ rowptr, int N) {
    int t = threadIdx.x;
    int lane = t & 63, wave = t >> 6;
    int i0 = 2 * t, i1 = 2 * t + 1;
    int c0 = (i0 < nbuck) ? gcursor[i0] - i0 * CAP : 0;
    int c1 = (i1 < nbuck) ? gcursor[i1] - i1 * CAP : 0;
    int s = c0 + c1;
    int inc = s;
#pragma unroll
    for (int off = 1; off < 64; off <<= 1) {
        int u = __shfl_up(inc, off);
        if (lane >= off) inc += u;
    }
    __shared__ int wtot[4];
    if (lane == 63) wtot[wave] = inc;
    __syncthreads();
    int wbase = 0;
    for (int w = 0; w < wave; ++w) wbase += wtot[w];
    inc += wbase;
    int excl = inc - s;
    if (i0 < nbuck) bptr[i0] = excl;
    if (i1 < nbuck) bptr[i1] = excl + c0;
    if (t == 255) {
        int total = wtot[0] + wtot[1] + wtot[2] + wtot[3];
        bptr[nbuck] = total;
        rowptr[N] = total;
    }
}

// ---------------- pass 3: per-bucket CSR build; fuses deg + dinv ----------------
// One block per bucket; its csr_src region [bptr[b], bptr[b+1]) is contiguous and
// written only by this block -> full-line writebacks.
__global__ __launch_bounds__(256) void csr_build(const unsigned* __restrict__ ebuf,
                                                 const int* __restrict__ bptr, int N,
                                                 int* __restrict__ rowptr,
                                                 int* __restrict__ csr_src,
                                                 float* __restrict__ dinv) {
    __shared__ int hist[128];
    __shared__ int excl[128];
    __shared__ int cur[128];
    int b = blockIdx.x;
    int t = threadIdx.x;
    int node0 = b << 7;
    int e0 = bptr[b], e1 = bptr[b + 1];
    int cnt = e1 - e0;
    if (t < 128) hist[t] = 0;
    __syncthreads();
    const unsigned* slab = ebuf + (size_t)b * CAP;
    for (int k = t; k < cnt; k += 256) atomicAdd(&hist[slab[k] & 127], 1);
    __syncthreads();
    if (t < 128) excl[t] = hist[t];
    __syncthreads();
    for (int off = 1; off < 128; off <<= 1) {
        int v = (t < 128 && t >= off) ? excl[t - off] : 0;
        __syncthreads();
        if (t < 128) excl[t] += v;
        __syncthreads();
    }
    if (t < 128) {
        int ex = excl[t] - hist[t];  // inclusive -> exclusive
        excl[t] = ex;
        cur[t] = ex;
    }
    __syncthreads();
    int nn = N - node0;
    if (nn > 128) nn = 128;
    if (t < nn) {
        rowptr[node0 + t] = e0 + excl[t];
        dinv[node0 + t] = 1.0f / sqrtf((float)hist[t] + 1.0f);
    }
    for (int k = t; k < cnt; k += 256) {
        unsigned p = slab[k];
        int dl = p & 127;
        int pos = atomicAdd(&cur[dl], 1);
        csr_src[e0 + pos] = (int)(p >> 7);
    }
}

// ---------------- graph_ptr from sorted batch: gp[g] = first node with batch >= g ----------------
__global__ __launch_bounds__(256) void graph_ptr_kernel(const int* __restrict__ batch, int n,
                                                        int G, int* __restrict__ gp) {
    int i = blockIdx.x * 256 + threadIdx.x;
    if (i >= n) return;
    int bi = batch[i];
    if (i == 0) {
        for (int g = 0; g <= bi; ++g) gp[g] = 0;
    } else {
        int bp = batch[i - 1];
        for (int g = bp + 1; g <= bi; ++g) gp[g] = i;
    }
    if (i == n - 1) {
        for (int g = bi + 1; g <= G; ++g) gp[g] = n;
    }
}

// ---------------- prep: W -> hi/lo bf16 fragments in MFMA-ready layout ----------------
// For matrix m (0=W_in, 1..3=Wc[l]): B[k][o] = W[o][k]. Fragment layout for 16x16x32:
// lane = kg*16 + oc (kg=lane>>4, oc=lane&15) holds B[kk*32+kg*8+j][t*16+oc], j=0..7.
__global__ __launch_bounds__(256) void prep_wfrag(const float* __restrict__ Win,
                                                  const float* __restrict__ Wc,
                                                  unsigned short* __restrict__ Wfrag) {
    int gid = blockIdx.x * 256 + threadIdx.x;
    if (gid >= 4 * 16384) return;
    int m = gid >> 14;
    int r = gid & 16383;
    int t = r >> 11;
    int kk = (r >> 9) & 3;
    int lane = (r >> 3) & 63;
    int j = r & 7;
    int kg = lane >> 4, oc = lane & 15;
    int o = t * 16 + oc;
    int k = kk * 32 + kg * 8 + j;
    const float* src = (m == 0) ? Win : (Wc + (m - 1) * 16384);
    float w = src[o * 128 + k];
    unsigned short hi = f2bf(w);
    unsigned short lo = f2bf(w - bf2f(hi));
    Wfrag[m * 32768 + r] = hi;
    Wfrag[m * 32768 + 16384 + r] = lo;
}

// ---------------- MFMA GEMM: C[n][128] = A[n][128] @ W^T via split-bf16 (hi/lo) ----------------
// 3-term product: a_hi*w_hi + a_hi*w_lo + a_lo*w_hi (error ~2^-16 rel; lo*lo dropped).
// C/D layout (verified m89): col=lane&15, row=(lane>>4)*4+reg.
__global__ __launch_bounds__(256) void gemm_mfma(const float* __restrict__ A,
                                                 const unsigned short* __restrict__ Wfrag,
                                                 const float* __restrict__ bias,
                                                 const float* __restrict__ scale,
                                                 void* __restrict__ Cout, int n, int use_bias,
                                                 int use_scale, int out_bf16) {
    __shared__ unsigned short sB[32768];  // 64 KB: hi [0..16383], lo [16384..32767]
    int tid = threadIdx.x;
    int wave = tid >> 6;
    int lane = tid & 63;
    int wbase = blockIdx.x * 64 + wave * 16;

    {
        const float4* src = (const float4*)Wfrag;
        float4* dst = (float4*)sB;
#pragma unroll
        for (int i = 0; i < 16; ++i) dst[tid + i * 256] = src[tid + i * 256];
    }
    __syncthreads();

    f32x4 acc[8];
#pragma unroll
    for (int t = 0; t < 8; ++t) acc[t] = (f32x4){0.f, 0.f, 0.f, 0.f};

    int arow = wbase + (lane & 15);
    int kg8 = (lane >> 4) * 8;

#pragma unroll
    for (int kk = 0; kk < 4; ++kk) {
        float4 v0 = {0.f, 0.f, 0.f, 0.f}, v1 = {0.f, 0.f, 0.f, 0.f};
        if (arow < n) {
            const float* ap = A + (size_t)arow * 128 + kk * 32 + kg8;
            v0 = *(const float4*)(ap);
            v1 = *(const float4*)(ap + 4);
        }
        float fs[8] = {v0.x, v0.y, v0.z, v0.w, v1.x, v1.y, v1.z, v1.w};
        bf16x8 ahi, alo;
#pragma unroll
        for (int j = 0; j < 8; ++j) {
            unsigned short h = f2bf(fs[j]);
            ahi[j] = (short)h;
            alo[j] = (short)f2bf(fs[j] - bf2f(h));
        }
#pragma unroll
        for (int t = 0; t < 8; ++t) {
            int boff = ((t * 4 + kk) * 64 + lane) * 8;  // in shorts
            bf16x8 bhi = *(const bf16x8*)(sB + boff);
            bf16x8 blo = *(const bf16x8*)(sB + 16384 + boff);
            acc[t] = __builtin_amdgcn_mfma_f32_16x16x32_bf16(ahi, bhi, acc[t], 0, 0, 0);
            acc[t] = __builtin_amdgcn_mfma_f32_16x16x32_bf16(ahi, blo, acc[t], 0, 0, 0);
            acc[t] = __builtin_amdgcn_mfma_f32_16x16x32_bf16(alo, bhi, acc[t], 0, 0, 0);
        }
    }

    int colbase = lane & 15;
    int rquad = (lane >> 4) * 4;
    float bvs[8];
#pragma unroll
    for (int t = 0; t < 8; ++t) bvs[t] = use_bias ? bias[t * 16 + colbase] : 0.0f;
#pragma unroll
    for (int r = 0; r < 4; ++r) {
        int gr = wbase + rquad + r;
        if (gr >= n) continue;
        float s = use_scale ? scale[gr] : 1.0f;
        if (out_bf16) {
            unsigned short* crow = (unsigned short*)Cout + (size_t)gr * 128;
#pragma unroll
            for (int t = 0; t < 8; ++t) crow[t * 16 + colbase] = f2bf((acc[t][r] + bvs[t]) * s);
        } else {
            float* crow = (float*)Cout + (size_t)gr * 128;
#pragma unroll
            for (int t = 0; t < 8; ++t) crow[t * 16 + colbase] = (acc[t][r] + bvs[t]) * s;
        }
    }
}

// ---------------- fused CSR gather + self-loop + bias + LayerNorm + ReLU + residual ----------------
// hws rows are bf16, PRE-SCALED by dinv[row] (gemm epilogue). 8-deep MLP edge loop.
__global__ __launch_bounds__(256) void gather_ln(const unsigned short* __restrict__ hws,
                                                 float* __restrict__ h,
                                                 const int* __restrict__ rowptr,
                                                 const int* __restrict__ csr_src,
                                                 const float* __restrict__ dinv,
                                                 const float* __restrict__ bc,
                                                 const float* __restrict__ gamma,
                                                 const float* __restrict__ beta, int n) {
    int wid = (blockIdx.x * 256 + threadIdx.x) >> 6;
    int lane = threadIdx.x & 63;
    if (wid >= n) return;
    int i = wid;
    float di = dinv[i];
    int e0 = rowptr[i], e1 = rowptr[i + 1];
    int c0 = lane * 2;
    const unsigned short* hb = hws + c0;

    ushort2 r0 = *(const ushort2*)(hb + (size_t)i * HIDDIM);
    float sx = bf2f(r0.x), sy = bf2f(r0.y);
    int e = e0;
    for (; e + 8 <= e1; e += 8) {
        int i0 = csr_src[e + 0], i1 = csr_src[e + 1], i2 = csr_src[e + 2], i3 = csr_src[e + 3];
        int i4 = csr_src[e + 4], i5 = csr_src[e + 5], i6 = csr_src[e + 6], i7 = csr_src[e + 7];
        ushort2 v0 = *(const ushort2*)(hb + (size_t)i0 * HIDDIM);
        ushort2 v1 = *(const ushort2*)(hb + (size_t)i1 * HIDDIM);
        ushort2 v2 = *(const ushort2*)(hb + (size_t)i2 * HIDDIM);
        ushort2 v3 = *(const ushort2*)(hb + (size_t)i3 * HIDDIM);
        ushort2 v4 = *(const ushort2*)(hb + (size_t)i4 * HIDDIM);
        ushort2 v5 = *(const ushort2*)(hb + (size_t)i5 * HIDDIM);
        ushort2 v6 = *(const ushort2*)(hb + (size_t)i6 * HIDDIM);
        ushort2 v7 = *(const ushort2*)(hb + (size_t)i7 * HIDDIM);
        sx += bf2f(v0.x); sy += bf2f(v0.y);  sx += bf2f(v1.x); sy += bf2f(v1.y);
        sx += bf2f(v2.x); sy += bf2f(v2.y);  sx += bf2f(v3.x); sy += bf2f(v3.y);
        sx += bf2f(v4.x); sy += bf2f(v4.y);  sx += bf2f(v5.x); sy += bf2f(v5.y);
        sx += bf2f(v6.x); sy += bf2f(v6.y);  sx += bf2f(v7.x); sy += bf2f(v7.y);
    }
    if (e + 4 <= e1) {
        int i0 = csr_src[e + 0], i1 = csr_src[e + 1], i2 = csr_src[e + 2], i3 = csr_src[e + 3];
        ushort2 v0 = *(const ushort2*)(hb + (size_t)i0 * HIDDIM);
        ushort2 v1 = *(const ushort2*)(hb + (size_t)i1 * HIDDIM);
        ushort2 v2 = *(const ushort2*)(hb + (size_t)i2 * HIDDIM);
        ushort2 v3 = *(const ushort2*)(hb + (size_t)i3 * HIDDIM);
        sx += bf2f(v0.x); sy += bf2f(v0.y);  sx += bf2f(v1.x); sy += bf2f(v1.y);
        sx += bf2f(v2.x); sy += bf2f(v2.y);  sx += bf2f(v3.x); sy += bf2f(v3.y);
        e += 4;
    }
    for (; e < e1; ++e) {
        int sc = csr_src[e];
        ushort2 v = *(const ushort2*)(hb + (size_t)sc * HIDDIM);
        sx += bf2f(v.x); sy += bf2f(v.y);
    }
    float2 bcv = *(const float2*)(bc + c0);
    float vx = di * sx + bcv.x;
    float vy = di * sy + bcv.y;

    float s1 = vx + vy, s2 = vx * vx + vy * vy;
#pragma unroll
    for (int off = 32; off; off >>= 1) {
        s1 += __shfl_xor(s1, off);
        s2 += __shfl_xor(s2, off);
    }
    float mu = s1 * (1.0f / 128.0f);
    float var = s2 * (1.0f / 128.0f) - mu * mu;
    float rs = 1.0f / sqrtf(var + 1e-5f);

    float2 gm = *(const float2*)(gamma + c0);
    float2 bt = *(const float2*)(beta + c0);
    float yx = fmaxf((vx - mu) * rs * gm.x + bt.x, 0.0f);
    float yy = fmaxf((vy - mu) * rs * gm.y + bt.y, 0.0f);

    float2 hv = *(float2*)(h + (size_t)i * HIDDIM + c0);
    hv.x += yx; hv.y += yy;
    *(float2*)(h + (size_t)i * HIDDIM + c0) = hv;
}

// ---------------- fused segmented mean-pool + MLP head (batch is SORTED) ----------------
__global__ __launch_bounds__(128) void pool_mlp_kernel(const float* __restrict__ h,
                                                       const int* __restrict__ gp,
                                                       const float* __restrict__ W1,
                                                       const float* __restrict__ b1,
                                                       const float* __restrict__ W2,
                                                       const float* __restrict__ b2,
                                                       float* __restrict__ out, int G) {
    __shared__ float sp[128];
    int g = blockIdx.x;
    if (g >= G) return;
    int t = threadIdx.x;
    int s = gp[g], e = gp[g + 1];
    float acc = 0.0f;
    for (int i = s; i < e; ++i) acc += h[(size_t)i * HIDDIM + t];
    float cnt = fmaxf((float)(e - s), 1.0f);
    sp[t] = acc / cnt;
    __syncthreads();
    if (t < 64) {
        const float* wr = W1 + t * HIDDIM;
        float a = 0.0f;
#pragma unroll 8
        for (int k = 0; k < HIDDIM; k += 4) {
            float4 p = *(const float4*)(sp + k);  // same addr all lanes -> LDS broadcast
            float4 w = *(const float4*)(wr + k);
            a += p.x * w.x + p.y * w.y + p.z * w.z + p.w * w.w;
        }
        float h1 = fmaxf(a + b1[t], 0.0f);
        float c = h1 * W2[t];
#pragma unroll
        for (int off = 32; off; off >>= 1) c += __shfl_xor(c, off);
        if (t == 0) out[g] = c + b2[0];
    }
}

extern "C" void kernel_launch(void* const* d_in, const int* in_sizes, int n_in,
                              void* d_out, int out_size, void* d_ws, size_t ws_size,
                              hipStream_t stream) {
    const float* x      = (const float*)d_in[0];
    const int*   ei     = (const int*)d_in[1];
    const int*   batch  = (const int*)d_in[2];
    const float* W_in   = (const float*)d_in[3];
    const float* b_in   = (const float*)d_in[4];
    const float* Wc     = (const float*)d_in[5];
    const float* bc     = (const float*)d_in[6];
    const float* gamma  = (const float*)d_in[7];
    const float* beta   = (const float*)d_in[8];
    const float* W1     = (const float*)d_in[9];
    const float* b1     = (const float*)d_in[10];
    const float* W2     = (const float*)d_in[11];
    const float* b2     = (const float*)d_in[12];
    float* out = (float*)d_out;

    const int N = in_sizes[2];
    const int E = in_sizes[1] / 2;
    const int G = out_size;  // OUT_DIM == 1
    const int NBUCK = (N + 127) >> 7;  // 128 nodes per bucket

    // workspace carve-up (256B aligned)
    char* ws = (char*)d_ws;
    size_t off = 0;
    auto alloc = [&](size_t bytes) {
        size_t o = off;
        off = (off + bytes + 255) & ~(size_t)255;
        return o;
    };
    int*      rowptr  = (int*)(ws + alloc((size_t)(N + 1) * 4));
    int*      csr_src = (int*)(ws + alloc((size_t)E * 4));
    float*    dinv    = (float*)(ws + alloc((size_t)N * 4));
    unsigned* ebuf    = (unsigned*)(ws + alloc((size_t)NBUCK * CAP * 4));
    int*      gcursor = (int*)(ws + alloc((size_t)NBUCK * 4));
    int*      bptr    = (int*)(ws + alloc((size_t)(NBUCK + 1) * 4));
    unsigned short* Wfrag = (unsigned short*)(ws + alloc((size_t)4 * 32768 * 2));
    float*    h       = (float*)(ws + alloc((size_t)N * 128 * 4));
    unsigned short* hws = (unsigned short*)(ws + alloc((size_t)N * 128 * 2));
    int*      gp      = (int*)(ws + alloc((size_t)(G + 1) * 4));
    (void)ws_size; (void)n_in;

    // ---- graph preprocessing: two-level bucket counting sort ----
    init_gcursor<<<(NBUCK + 255) / 256, 256, 0, stream>>>(gcursor, NBUCK);
    bucket_scatter<<<(E + 2047) / 2048, 256, 0, stream>>>(ei, E, gcursor, ebuf, NBUCK);
    bucket_scan<<<1, 256, 0, stream>>>(gcursor, NBUCK, bptr, rowptr, N);
    csr_build<<<NBUCK, 256, 0, stream>>>(ebuf, bptr, N, rowptr, csr_src, dinv);
    graph_ptr_kernel<<<(N + 255) / 256, 256, 0, stream>>>(batch, N, G, gp);
    prep_wfrag<<<(4 * 16384 + 255) / 256, 256, 0, stream>>>(W_in, Wc, Wfrag);

    // ---- input projection (MFMA split-bf16), fp32 out ----
    int mblocks = (N + 63) / 64;
    gemm_mfma<<<mblocks, 256, 0, stream>>>(x, Wfrag, b_in, nullptr, h, N, 1, 0, 0);

    // ---- 3 GCN layers ----
    for (int l = 0; l < 3; ++l) {
        // hws = bf16( (h @ Wc[l]^T) * dinv[row] )  (pre-scaled for the gather)
        gemm_mfma<<<mblocks, 256, 0, stream>>>(h, Wfrag + (1 + l) * 32768, nullptr, dinv,
                                               hws, N, 0, 1, 1);
        gather_ln<<<(N + 3) / 4, 256, 0, stream>>>(hws, h, rowptr, csr_src, dinv,
                                                   bc + l * 128, gamma + l * 128,
                                                   beta + l * 128, N);
    }

    // ---- fused pooling + MLP head ----
    pool_mlp_kernel<<<G, 128, 0, stream>>>(h, gp, W1, b1, W2, b2, out, G);
}

// Round 8
// 298.142 us; speedup vs baseline: 2.9048x; 1.1135x over previous
//
#include <hip/hip_runtime.h>
#include <hip/hip_bf16.h>

#define HIDDIM 128
#define CAP 4096           // slab capacity per bucket (mean fill ~2046, 45 sigma headroom)

typedef short bf16x8 __attribute__((ext_vector_type(8)));
typedef float f32x4 __attribute__((ext_vector_type(4)));

__device__ inline unsigned short f2bf(float f) {
    unsigned u = __float_as_uint(f);
    unsigned r = (u + 0x7fffu + ((u >> 16) & 1u)) >> 16;  // RNE
    return (unsigned short)r;
}
__device__ inline float bf2f(unsigned short s) {
    return __uint_as_float(((unsigned)s) << 16);
}

// ---------------- fused misc preprocessing (block-partitioned) ----------------
// blocks [0,2): init gcursor; [2, 2+NBGP): graph_ptr; [2+NBGP, ...): prep_wfrag.
__global__ __launch_bounds__(256) void preproc_misc(int* __restrict__ gcursor, int nbuck,
                                                    const int* __restrict__ batch, int n, int G,
                                                    int* __restrict__ gp,
                                                    const float* __restrict__ Win,
                                                    const float* __restrict__ Wc,
                                                    unsigned short* __restrict__ Wfrag,
                                                    int nbgp) {
    int bx = blockIdx.x;
    if (bx < 2) {
        int b = bx * 256 + threadIdx.x;
        if (b < nbuck) gcursor[b] = b * CAP;
        return;
    }
    bx -= 2;
    if (bx < nbgp) {
        // graph_ptr from sorted batch: gp[g] = first node with batch >= g
        int i = bx * 256 + threadIdx.x;
        if (i >= n) return;
        int bi = batch[i];
        if (i == 0) {
            for (int g = 0; g <= bi; ++g) gp[g] = 0;
        } else {
            int bp = batch[i - 1];
            for (int g = bp + 1; g <= bi; ++g) gp[g] = i;
        }
        if (i == n - 1) {
            for (int g = bi + 1; g <= G; ++g) gp[g] = n;
        }
        return;
    }
    bx -= nbgp;
    // prep_wfrag: W -> hi/lo bf16 fragments in MFMA-ready layout.
    // lane = kg*16 + oc holds B[kk*32+kg*8+j][t*16+oc] where B[k][o] = W[o][k].
    int gid = bx * 256 + threadIdx.x;
    if (gid >= 4 * 16384) return;
    int m = gid >> 14;
    int r = gid & 16383;
    int t = r >> 11;
    int kk = (r >> 9) & 3;
    int lane = (r >> 3) & 63;
    int j = r & 7;
    int kg = lane >> 4, oc = lane & 15;
    int o = t * 16 + oc;
    int k = kk * 32 + kg * 8 + j;
    const float* src = (m == 0) ? Win : (Wc + (m - 1) * 16384);
    float w = src[o * 128 + k];
    unsigned short hi = f2bf(w);
    unsigned short lo = f2bf(w - bf2f(hi));
    Wfrag[m * 32768 + r] = hi;
    Wfrag[m * 32768 + 16384 + r] = lo;
}

// ---------------- pass 1: bucket-scatter edges into per-bucket slabs ----------------
__global__ __launch_bounds__(256) void bucket_scatter(const int* __restrict__ ei, int E,
                                                      int* __restrict__ gcursor,
                                                      unsigned* __restrict__ ebuf, int nbuck) {
    __shared__ int lcount[512];
    __shared__ int lbase[512];
    int t = threadIdx.x;
    int cb = blockIdx.x * 2048;
    lcount[t] = 0;
    lcount[t + 256] = 0;
    __syncthreads();

    int bkt[8];
    int lpos[8];
    unsigned pk[8];
#pragma unroll
    for (int j = 0; j < 8; ++j) {
        int e = cb + j * 256 + t;
        if (e < E) {
            int s_ = ei[e];
            int d_ = ei[E + e];
            bkt[j] = d_ >> 7;
            pk[j] = ((unsigned)s_ << 7) | (unsigned)(d_ & 127);
            lpos[j] = atomicAdd(&lcount[bkt[j]], 1);
        } else {
            bkt[j] = -1;
            lpos[j] = 0;
            pk[j] = 0;
        }
    }
    __syncthreads();
    for (int bb = t; bb < nbuck; bb += 256) {
        int c = lcount[bb];
        lbase[bb] = c ? atomicAdd(&gcursor[bb], c) : 0;
    }
    __syncthreads();
#pragma unroll
    for (int j = 0; j < 8; ++j) {
        if (bkt[j] >= 0) {
            unsigned idx = (unsigned)lbase[bkt[j]] + (unsigned)lpos[j];
            if (idx < (unsigned)(bkt[j] + 1) * CAP)  // slab overflow guard (never fires)
                ebuf[idx] = pk[j];
        }
    }
}

// ---------------- pass 2: scan bucket counts -> bptr; rowptr[N] = total ----------------
__global__ __launch_bounds__(256) void bucket_scan(const int* __restrict__ gcursor, int nbuck,
                                                   int* __restrict__ bptr,
                                                   int* __restrict__ rowptr, int N) {
    int t = threadIdx.x;
    int lane = t & 63, wave = t >> 6;
    int i0 = 2 * t, i1 = 2 * t + 1;
    int c0 = (i0 < nbuck) ? gcursor[i0] - i0 * CAP : 0;
    int c1 = (i1 < nbuck) ? gcursor[i1] - i1 * CAP : 0;
    int s = c0 + c1;
    int inc = s;
#pragma unroll
    for (int off = 1; off < 64; off <<= 1) {
        int u = __shfl_up(inc, off);
        if (lane >= off) inc += u;
    }
    __shared__ int wtot[4];
    if (lane == 63) wtot[wave] = inc;
    __syncthreads();
    int wbase = 0;
    for (int w = 0; w < wave; ++w) wbase += wtot[w];
    inc += wbase;
    int excl = inc - s;
    if (i0 < nbuck) bptr[i0] = excl;
    if (i1 < nbuck) bptr[i1] = excl + c0;
    if (t == 255) {
        int total = wtot[0] + wtot[1] + wtot[2] + wtot[3];
        bptr[nbuck] = total;
        rowptr[N] = total;
    }
}

// ---------------- pass 3: per-bucket CSR build; fuses deg + dinv ----------------
__global__ __launch_bounds__(256) void csr_build(const unsigned* __restrict__ ebuf,
                                                 const int* __restrict__ bptr, int N,
                                                 int* __restrict__ rowptr,
                                                 int* __restrict__ csr_src,
                                                 float* __restrict__ dinv) {
    __shared__ int hist[128];
    __shared__ int excl[128];
    __shared__ int cur[128];
    int b = blockIdx.x;
    int t = threadIdx.x;
    int node0 = b << 7;
    int e0 = bptr[b], e1 = bptr[b + 1];
    int cnt = e1 - e0;
    if (t < 128) hist[t] = 0;
    __syncthreads();
    const unsigned* slab = ebuf + (size_t)b * CAP;
    for (int k = t; k < cnt; k += 256) atomicAdd(&hist[slab[k] & 127], 1);
    __syncthreads();
    if (t < 128) excl[t] = hist[t];
    __syncthreads();
    for (int off = 1; off < 128; off <<= 1) {
        int v = (t < 128 && t >= off) ? excl[t - off] : 0;
        __syncthreads();
        if (t < 128) excl[t] += v;
        __syncthreads();
    }
    if (t < 128) {
        int ex = excl[t] - hist[t];  // inclusive -> exclusive
        excl[t] = ex;
        cur[t] = ex;
    }
    __syncthreads();
    int nn = N - node0;
    if (nn > 128) nn = 128;
    if (t < nn) {
        rowptr[node0 + t] = e0 + excl[t];
        dinv[node0 + t] = 1.0f / sqrtf((float)hist[t] + 1.0f);
    }
    for (int k = t; k < cnt; k += 256) {
        unsigned p = slab[k];
        int dl = p & 127;
        int pos = atomicAdd(&cur[dl], 1);
        csr_src[e0 + pos] = (int)(p >> 7);
    }
}

// ---------------- MFMA GEMM: C[n][128] = A[n][128] @ W^T via split-bf16 (hi/lo) ----------------
// 512 thr = 8 waves, 128 rows/block -> 64KB LDS, 2 blocks/CU = 16 waves/CU (was 8).
// 3-term product: a_hi*w_hi + a_hi*w_lo + a_lo*w_hi. C/D: col=lane&15, row=(lane>>4)*4+reg.
__global__ __launch_bounds__(512) void gemm_mfma(const float* __restrict__ A,
                                                 const unsigned short* __restrict__ Wfrag,
                                                 const float* __restrict__ bias,
                                                 const float* __restrict__ scale,
                                                 void* __restrict__ Cout, int n, int use_bias,
                                                 int use_scale, int out_bf16) {
    __shared__ unsigned short sB[32768];  // 64 KB: hi [0..16383], lo [16384..32767]
    int tid = threadIdx.x;
    int wave = tid >> 6;
    int lane = tid & 63;
    int wbase = blockIdx.x * 128 + wave * 16;

    {
        const float4* src = (const float4*)Wfrag;
        float4* dst = (float4*)sB;
#pragma unroll
        for (int i = 0; i < 8; ++i) dst[tid + i * 512] = src[tid + i * 512];
    }
    __syncthreads();

    f32x4 acc[8];
#pragma unroll
    for (int t = 0; t < 8; ++t) acc[t] = (f32x4){0.f, 0.f, 0.f, 0.f};

    int arow = wbase + (lane & 15);
    int kg8 = (lane >> 4) * 8;

#pragma unroll
    for (int kk = 0; kk < 4; ++kk) {
        float4 v0 = {0.f, 0.f, 0.f, 0.f}, v1 = {0.f, 0.f, 0.f, 0.f};
        if (arow < n) {
            const float* ap = A + (size_t)arow * 128 + kk * 32 + kg8;
            v0 = *(const float4*)(ap);
            v1 = *(const float4*)(ap + 4);
        }
        float fs[8] = {v0.x, v0.y, v0.z, v0.w, v1.x, v1.y, v1.z, v1.w};
        bf16x8 ahi, alo;
#pragma unroll
        for (int j = 0; j < 8; ++j) {
            unsigned short h = f2bf(fs[j]);
            ahi[j] = (short)h;
            alo[j] = (short)f2bf(fs[j] - bf2f(h));
        }
#pragma unroll
        for (int t = 0; t < 8; ++t) {
            int boff = ((t * 4 + kk) * 64 + lane) * 8;  // in shorts
            bf16x8 bhi = *(const bf16x8*)(sB + boff);
            bf16x8 blo = *(const bf16x8*)(sB + 16384 + boff);
            acc[t] = __builtin_amdgcn_mfma_f32_16x16x32_bf16(ahi, bhi, acc[t], 0, 0, 0);
            acc[t] = __builtin_amdgcn_mfma_f32_16x16x32_bf16(ahi, blo, acc[t], 0, 0, 0);
            acc[t] = __builtin_amdgcn_mfma_f32_16x16x32_bf16(alo, bhi, acc[t], 0, 0, 0);
        }
    }

    int colbase = lane & 15;
    int rquad = (lane >> 4) * 4;
    float bvs[8];
#pragma unroll
    for (int t = 0; t < 8; ++t) bvs[t] = use_bias ? bias[t * 16 + colbase] : 0.0f;
#pragma unroll
    for (int r = 0; r < 4; ++r) {
        int gr = wbase + rquad + r;
        if (gr >= n) continue;
        float s = use_scale ? scale[gr] : 1.0f;
        if (out_bf16) {
            unsigned short* crow = (unsigned short*)Cout + (size_t)gr * 128;
#pragma unroll
            for (int t = 0; t < 8; ++t) crow[t * 16 + colbase] = f2bf((acc[t][r] + bvs[t]) * s);
        } else {
            float* crow = (float*)Cout + (size_t)gr * 128;
#pragma unroll
            for (int t = 0; t < 8; ++t) crow[t * 16 + colbase] = (acc[t][r] + bvs[t]) * s;
        }
    }
}

// ---------------- fused CSR gather + self-loop + bias + LayerNorm + ReLU + residual ----------------
// hws rows are bf16, PRE-SCALED by dinv[row] (gemm epilogue). 8-deep MLP edge loop.
__global__ __launch_bounds__(256) void gather_ln(const unsigned short* __restrict__ hws,
                                                 float* __restrict__ h,
                                                 const int* __restrict__ rowptr,
                                                 const int* __restrict__ csr_src,
                                                 const float* __restrict__ dinv,
                                                 const float* __restrict__ bc,
                                                 const float* __restrict__ gamma,
                                                 const float* __restrict__ beta, int n) {
    int wid = (blockIdx.x * 256 + threadIdx.x) >> 6;
    int lane = threadIdx.x & 63;
    if (wid >= n) return;
    int i = wid;
    float di = dinv[i];
    int e0 = rowptr[i], e1 = rowptr[i + 1];
    int c0 = lane * 2;
    const unsigned short* hb = hws + c0;

    ushort2 r0 = *(const ushort2*)(hb + (size_t)i * HIDDIM);
    float sx = bf2f(r0.x), sy = bf2f(r0.y);
    int e = e0;
    for (; e + 8 <= e1; e += 8) {
        int i0 = csr_src[e + 0], i1 = csr_src[e + 1], i2 = csr_src[e + 2], i3 = csr_src[e + 3];
        int i4 = csr_src[e + 4], i5 = csr_src[e + 5], i6 = csr_src[e + 6], i7 = csr_src[e + 7];
        ushort2 v0 = *(const ushort2*)(hb + (size_t)i0 * HIDDIM);
        ushort2 v1 = *(const ushort2*)(hb + (size_t)i1 * HIDDIM);
        ushort2 v2 = *(const ushort2*)(hb + (size_t)i2 * HIDDIM);
        ushort2 v3 = *(const ushort2*)(hb + (size_t)i3 * HIDDIM);
        ushort2 v4 = *(const ushort2*)(hb + (size_t)i4 * HIDDIM);
        ushort2 v5 = *(const ushort2*)(hb + (size_t)i5 * HIDDIM);
        ushort2 v6 = *(const ushort2*)(hb + (size_t)i6 * HIDDIM);
        ushort2 v7 = *(const ushort2*)(hb + (size_t)i7 * HIDDIM);
        sx += bf2f(v0.x); sy += bf2f(v0.y);  sx += bf2f(v1.x); sy += bf2f(v1.y);
        sx += bf2f(v2.x); sy += bf2f(v2.y);  sx += bf2f(v3.x); sy += bf2f(v3.y);
        sx += bf2f(v4.x); sy += bf2f(v4.y);  sx += bf2f(v5.x); sy += bf2f(v5.y);
        sx += bf2f(v6.x); sy += bf2f(v6.y);  sx += bf2f(v7.x); sy += bf2f(v7.y);
    }
    if (e + 4 <= e1) {
        int i0 = csr_src[e + 0], i1 = csr_src[e + 1], i2 = csr_src[e + 2], i3 = csr_src[e + 3];
        ushort2 v0 = *(const ushort2*)(hb + (size_t)i0 * HIDDIM);
        ushort2 v1 = *(const ushort2*)(hb + (size_t)i1 * HIDDIM);
        ushort2 v2 = *(const ushort2*)(hb + (size_t)i2 * HIDDIM);
        ushort2 v3 = *(const ushort2*)(hb + (size_t)i3 * HIDDIM);
        sx += bf2f(v0.x); sy += bf2f(v0.y);  sx += bf2f(v1.x); sy += bf2f(v1.y);
        sx += bf2f(v2.x); sy += bf2f(v2.y);  sx += bf2f(v3.x); sy += bf2f(v3.y);
        e += 4;
    }
    for (; e < e1; ++e) {
        int sc = csr_src[e];
        ushort2 v = *(const ushort2*)(hb + (size_t)sc * HIDDIM);
        sx += bf2f(v.x); sy += bf2f(v.y);
    }
    float2 bcv = *(const float2*)(bc + c0);
    float vx = di * sx + bcv.x;
    float vy = di * sy + bcv.y;

    float s1 = vx + vy, s2 = vx * vx + vy * vy;
#pragma unroll
    for (int off = 32; off; off >>= 1) {
        s1 += __shfl_xor(s1, off);
        s2 += __shfl_xor(s2, off);
    }
    float mu = s1 * (1.0f / 128.0f);
    float var = s2 * (1.0f / 128.0f) - mu * mu;
    float rs = 1.0f / sqrtf(var + 1e-5f);

    float2 gm = *(const float2*)(gamma + c0);
    float2 bt = *(const float2*)(beta + c0);
    float yx = fmaxf((vx - mu) * rs * gm.x + bt.x, 0.0f);
    float yy = fmaxf((vy - mu) * rs * gm.y + bt.y, 0.0f);

    float2 hv = *(float2*)(h + (size_t)i * HIDDIM + c0);
    hv.x += yx; hv.y += yy;
    *(float2*)(h + (size_t)i * HIDDIM + c0) = hv;
}

// ---------------- fused segmented mean-pool + MLP head (batch is SORTED) ----------------
// 2-accumulator unroll to break the serial add chain (latency-bound at 500 blocks).
__global__ __launch_bounds__(128) void pool_mlp_kernel(const float* __restrict__ h,
                                                       const int* __restrict__ gp,
                                                       const float* __restrict__ W1,
                                                       const float* __restrict__ b1,
                                                       const float* __restrict__ W2,
                                                       const float* __restrict__ b2,
                                                       float* __restrict__ out, int G) {
    __shared__ float sp[128];
    int g = blockIdx.x;
    if (g >= G) return;
    int t = threadIdx.x;
    int s = gp[g], e = gp[g + 1];
    float a0 = 0.0f, a1 = 0.0f;
    int i = s;
    for (; i + 2 <= e; i += 2) {
        a0 += h[(size_t)i * HIDDIM + t];
        a1 += h[(size_t)(i + 1) * HIDDIM + t];
    }
    if (i < e) a0 += h[(size_t)i * HIDDIM + t];
    float cnt = fmaxf((float)(e - s), 1.0f);
    sp[t] = (a0 + a1) / cnt;
    __syncthreads();
    if (t < 64) {
        const float* wr = W1 + t * HIDDIM;
        float a = 0.0f;
#pragma unroll 8
        for (int k = 0; k < HIDDIM; k += 4) {
            float4 p = *(const float4*)(sp + k);  // same addr all lanes -> LDS broadcast
            float4 w = *(const float4*)(wr + k);
            a += p.x * w.x + p.y * w.y + p.z * w.z + p.w * w.w;
        }
        float h1 = fmaxf(a + b1[t], 0.0f);
        float c = h1 * W2[t];
#pragma unroll
        for (int off = 32; off; off >>= 1) c += __shfl_xor(c, off);
        if (t == 0) out[g] = c + b2[0];
    }
}

extern "C" void kernel_launch(void* const* d_in, const int* in_sizes, int n_in,
                              void* d_out, int out_size, void* d_ws, size_t ws_size,
                              hipStream_t stream) {
    const float* x      = (const float*)d_in[0];
    const int*   ei     = (const int*)d_in[1];
    const int*   batch  = (const int*)d_in[2];
    const float* W_in   = (const float*)d_in[3];
    const float* b_in   = (const float*)d_in[4];
    const float* Wc     = (const float*)d_in[5];
    const float* bc     = (const float*)d_in[6];
    const float* gamma  = (const float*)d_in[7];
    const float* beta   = (const float*)d_in[8];
    const float* W1     = (const float*)d_in[9];
    const float* b1     = (const float*)d_in[10];
    const float* W2     = (const float*)d_in[11];
    const float* b2     = (const float*)d_in[12];
    float* out = (float*)d_out;

    const int N = in_sizes[2];
    const int E = in_sizes[1] / 2;
    const int G = out_size;  // OUT_DIM == 1
    const int NBUCK = (N + 127) >> 7;  // 128 nodes per bucket

    // workspace carve-up (256B aligned)
    char* ws = (char*)d_ws;
    size_t off = 0;
    auto alloc = [&](size_t bytes) {
        size_t o = off;
        off = (off + bytes + 255) & ~(size_t)255;
        return o;
    };
    int*      rowptr  = (int*)(ws + alloc((size_t)(N + 1) * 4));
    int*      csr_src = (int*)(ws + alloc((size_t)E * 4));
    float*    dinv    = (float*)(ws + alloc((size_t)N * 4));
    unsigned* ebuf    = (unsigned*)(ws + alloc((size_t)NBUCK * CAP * 4));
    int*      gcursor = (int*)(ws + alloc((size_t)NBUCK * 4));
    int*      bptr    = (int*)(ws + alloc((size_t)(NBUCK + 1) * 4));
    unsigned short* Wfrag = (unsigned short*)(ws + alloc((size_t)4 * 32768 * 2));
    float*    h       = (float*)(ws + alloc((size_t)N * 128 * 4));
    unsigned short* hws = (unsigned short*)(ws + alloc((size_t)N * 128 * 2));
    int*      gp      = (int*)(ws + alloc((size_t)(G + 1) * 4));
    (void)ws_size; (void)n_in;

    // ---- fused misc preprocessing + two-level bucket counting sort ----
    const int NBGP = (N + 255) / 256;
    const int NBPW = (4 * 16384 + 255) / 256;
    preproc_misc<<<2 + NBGP + NBPW, 256, 0, stream>>>(gcursor, NBUCK, batch, N, G, gp,
                                                      W_in, Wc, Wfrag, NBGP);
    bucket_scatter<<<(E + 2047) / 2048, 256, 0, stream>>>(ei, E, gcursor, ebuf, NBUCK);
    bucket_scan<<<1, 256, 0, stream>>>(gcursor, NBUCK, bptr, rowptr, N);
    csr_build<<<NBUCK, 256, 0, stream>>>(ebuf, bptr, N, rowptr, csr_src, dinv);

    // ---- input projection (MFMA split-bf16), fp32 out ----
    int mblocks = (N + 127) / 128;
    gemm_mfma<<<mblocks, 512, 0, stream>>>(x, Wfrag, b_in, nullptr, h, N, 1, 0, 0);

    // ---- 3 GCN layers ----
    for (int l = 0; l < 3; ++l) {
        // hws = bf16( (h @ Wc[l]^T) * dinv[row] )  (pre-scaled for the gather)
        gemm_mfma<<<mblocks, 512, 0, stream>>>(h, Wfrag + (1 + l) * 32768, nullptr, dinv,
                                               hws, N, 0, 1, 1);
        gather_ln<<<(N + 3) / 4, 256, 0, stream>>>(hws, h, rowptr, csr_src, dinv,
                                                   bc + l * 128, gamma + l * 128,
                                                   beta + l * 128, N);
    }

    // ---- fused pooling + MLP head ----
    pool_mlp_kernel<<<G, 128, 0, stream>>>(h, gp, W1, b1, W2, b2, out, G);
}

// Round 10
// 298.051 us; speedup vs baseline: 2.9057x; 1.0003x over previous
//
#include <hip/hip_runtime.h>
#include <hip/hip_bf16.h>

#define HIDDIM 128
#define CAP 4096           // slab capacity per bucket (mean fill ~2046, huge headroom)

typedef short bf16x8 __attribute__((ext_vector_type(8)));
typedef float f32x4 __attribute__((ext_vector_type(4)));
typedef unsigned short u16x8 __attribute__((ext_vector_type(8)));

__device__ inline unsigned short f2bf(float f) {
    unsigned u = __float_as_uint(f);
    unsigned r = (u + 0x7fffu + ((u >> 16) & 1u)) >> 16;  // RNE
    return (unsigned short)r;
}
__device__ inline float bf2f(unsigned short s) {
    return __uint_as_float(((unsigned)s) << 16);
}

// ---------------- fused misc preprocessing (block-partitioned) ----------------
// blocks [0,2): init gcursor; [2, 2+NBGP): graph_ptr; [2+NBGP, ...): prep_wfrag.
__global__ __launch_bounds__(256) void preproc_misc(int* __restrict__ gcursor, int nbuck,
                                                    const int* __restrict__ batch, int n, int G,
                                                    int* __restrict__ gp,
                                                    const float* __restrict__ Win,
                                                    const float* __restrict__ Wc,
                                                    unsigned short* __restrict__ Wfrag,
                                                    int nbgp) {
    int bx = blockIdx.x;
    if (bx < 2) {
        int b = bx * 256 + threadIdx.x;
        if (b < nbuck) gcursor[b] = b * CAP;
        return;
    }
    bx -= 2;
    if (bx < nbgp) {
        // graph_ptr from sorted batch: gp[g] = first node with batch >= g
        int i = bx * 256 + threadIdx.x;
        if (i >= n) return;
        int bi = batch[i];
        if (i == 0) {
            for (int g = 0; g <= bi; ++g) gp[g] = 0;
        } else {
            int bp = batch[i - 1];
            for (int g = bp + 1; g <= bi; ++g) gp[g] = i;
        }
        if (i == n - 1) {
            for (int g = bi + 1; g <= G; ++g) gp[g] = n;
        }
        return;
    }
    bx -= nbgp;
    // prep_wfrag: W -> hi/lo bf16 fragments in MFMA-ready layout.
    int gid = bx * 256 + threadIdx.x;
    if (gid >= 4 * 16384) return;
    int m = gid >> 14;
    int r = gid & 16383;
    int t = r >> 11;
    int kk = (r >> 9) & 3;
    int lane = (r >> 3) & 63;
    int j = r & 7;
    int kg = lane >> 4, oc = lane & 15;
    int o = t * 16 + oc;
    int k = kk * 32 + kg * 8 + j;
    const float* src = (m == 0) ? Win : (Wc + (m - 1) * 16384);
    float w = src[o * 128 + k];
    unsigned short hi = f2bf(w);
    unsigned short lo = f2bf(w - bf2f(hi));
    Wfrag[m * 32768 + r] = hi;
    Wfrag[m * 32768 + 16384 + r] = lo;
}

// ---------------- pass 1: bucket-scatter edges into per-bucket slabs ----------------
__global__ __launch_bounds__(256) void bucket_scatter(const int* __restrict__ ei, int E,
                                                      int* __restrict__ gcursor,
                                                      unsigned* __restrict__ ebuf, int nbuck) {
    __shared__ int lcount[512];
    __shared__ int lbase[512];
    int t = threadIdx.x;
    int cb = blockIdx.x * 2048;
    lcount[t] = 0;
    lcount[t + 256] = 0;
    __syncthreads();

    int bkt[8];
    int lpos[8];
    unsigned pk[8];
#pragma unroll
    for (int j = 0; j < 8; ++j) {
        int e = cb + j * 256 + t;
        if (e < E) {
            int s_ = ei[e];
            int d_ = ei[E + e];
            bkt[j] = d_ >> 7;
            pk[j] = ((unsigned)s_ << 7) | (unsigned)(d_ & 127);
            lpos[j] = atomicAdd(&lcount[bkt[j]], 1);
        } else {
            bkt[j] = -1;
            lpos[j] = 0;
            pk[j] = 0;
        }
    }
    __syncthreads();
    for (int bb = t; bb < nbuck; bb += 256) {
        int c = lcount[bb];
        lbase[bb] = c ? atomicAdd(&gcursor[bb], c) : 0;
    }
    __syncthreads();
#pragma unroll
    for (int j = 0; j < 8; ++j) {
        if (bkt[j] >= 0) {
            unsigned idx = (unsigned)lbase[bkt[j]] + (unsigned)lpos[j];
            if (idx < (unsigned)(bkt[j] + 1) * CAP)  // slab overflow guard (never fires)
                ebuf[idx] = pk[j];
        }
    }
}

// ---------------- pass 2: per-bucket CSR build with INLINE bucket prefix scan ----------------
// Each block computes its own prefix over the (<=512) bucket counts -- replaces the serial
// 1-block bucket_scan kernel (and its launch gap). Fuses deg + dinv as before.
__global__ __launch_bounds__(256) void csr_build(const unsigned* __restrict__ ebuf,
                                                 const int* __restrict__ gcursor,
                                                 int N, int nbuck,
                                                 int* __restrict__ rowptr,
                                                 int* __restrict__ csr_src,
                                                 float* __restrict__ dinv) {
    __shared__ int hist[128];
    __shared__ int excl[128];
    __shared__ int cur[128];
    __shared__ int wsum[4];
    __shared__ int sh_e0;
    int b = blockIdx.x;
    int t = threadIdx.x;
    // prefix of counts over buckets < b
    int partial = 0;
    for (int j = t; j < b; j += 256) {
        int c = gcursor[j] - j * CAP;
        partial += (c > CAP) ? CAP : c;
    }
#pragma unroll
    for (int off = 32; off; off >>= 1) partial += __shfl_xor(partial, off);
    if ((t & 63) == 0) wsum[t >> 6] = partial;
    if (t < 128) hist[t] = 0;
    __syncthreads();
    if (t == 0) sh_e0 = wsum[0] + wsum[1] + wsum[2] + wsum[3];
    __syncthreads();
    int e0 = sh_e0;
    int cnt = gcursor[b] - b * CAP;
    if (cnt > CAP) cnt = CAP;
    if (b == nbuck - 1 && t == 0) rowptr[N] = e0 + cnt;

    int node0 = b << 7;
    const unsigned* slab = ebuf + (size_t)b * CAP;
    for (int k = t; k < cnt; k += 256) atomicAdd(&hist[slab[k] & 127], 1);
    __syncthreads();
    if (t < 128) excl[t] = hist[t];
    __syncthreads();
    for (int off = 1; off < 128; off <<= 1) {
        int v = (t < 128 && t >= off) ? excl[t - off] : 0;
        __syncthreads();
        if (t < 128) excl[t] += v;
        __syncthreads();
    }
    if (t < 128) {
        int ex = excl[t] - hist[t];  // inclusive -> exclusive
        excl[t] = ex;
        cur[t] = ex;
    }
    __syncthreads();
    int nn = N - node0;
    if (nn > 128) nn = 128;
    if (t < nn) {
        rowptr[node0 + t] = e0 + excl[t];
        dinv[node0 + t] = 1.0f / sqrtf((float)hist[t] + 1.0f);
    }
    for (int k = t; k < cnt; k += 256) {
        unsigned p = slab[k];
        int dl = p & 127;
        int pos = atomicAdd(&cur[dl], 1);
        csr_src[e0 + pos] = (int)(p >> 7);
    }
}

// ---------------- MFMA GEMM: C[n][128] = A[n][128] @ W^T via split-bf16 (hi/lo) ----------------
// 512 thr = 8 waves, 128 rows/block -> 64KB LDS, 2 blocks/CU = 16 waves/CU.
__global__ __launch_bounds__(512) void gemm_mfma(const float* __restrict__ A,
                                                 const unsigned short* __restrict__ Wfrag,
                                                 const float* __restrict__ bias,
                                                 const float* __restrict__ scale,
                                                 void* __restrict__ Cout, int n, int use_bias,
                                                 int use_scale, int out_bf16) {
    __shared__ unsigned short sB[32768];  // 64 KB: hi [0..16383], lo [16384..32767]
    int tid = threadIdx.x;
    int wave = tid >> 6;
    int lane = tid & 63;
    int wbase = blockIdx.x * 128 + wave * 16;

    {
        const float4* src = (const float4*)Wfrag;
        float4* dst = (float4*)sB;
#pragma unroll
        for (int i = 0; i < 8; ++i) dst[tid + i * 512] = src[tid + i * 512];
    }
    __syncthreads();

    f32x4 acc[8];
#pragma unroll
    for (int t = 0; t < 8; ++t) acc[t] = (f32x4){0.f, 0.f, 0.f, 0.f};

    int arow = wbase + (lane & 15);
    int kg8 = (lane >> 4) * 8;

#pragma unroll
    for (int kk = 0; kk < 4; ++kk) {
        float4 v0 = {0.f, 0.f, 0.f, 0.f}, v1 = {0.f, 0.f, 0.f, 0.f};
        if (arow < n) {
            const float* ap = A + (size_t)arow * 128 + kk * 32 + kg8;
            v0 = *(const float4*)(ap);
            v1 = *(const float4*)(ap + 4);
        }
        float fs[8] = {v0.x, v0.y, v0.z, v0.w, v1.x, v1.y, v1.z, v1.w};
        bf16x8 ahi, alo;
#pragma unroll
        for (int j = 0; j < 8; ++j) {
            unsigned short h = f2bf(fs[j]);
            ahi[j] = (short)h;
            alo[j] = (short)f2bf(fs[j] - bf2f(h));
        }
#pragma unroll
        for (int t = 0; t < 8; ++t) {
            int boff = ((t * 4 + kk) * 64 + lane) * 8;  // in shorts
            bf16x8 bhi = *(const bf16x8*)(sB + boff);
            bf16x8 blo = *(const bf16x8*)(sB + 16384 + boff);
            acc[t] = __builtin_amdgcn_mfma_f32_16x16x32_bf16(ahi, bhi, acc[t], 0, 0, 0);
            acc[t] = __builtin_amdgcn_mfma_f32_16x16x32_bf16(ahi, blo, acc[t], 0, 0, 0);
            acc[t] = __builtin_amdgcn_mfma_f32_16x16x32_bf16(alo, bhi, acc[t], 0, 0, 0);
        }
    }

    int colbase = lane & 15;
    int rquad = (lane >> 4) * 4;
    float bvs[8];
#pragma unroll
    for (int t = 0; t < 8; ++t) bvs[t] = use_bias ? bias[t * 16 + colbase] : 0.0f;
#pragma unroll
    for (int r = 0; r < 4; ++r) {
        int gr = wbase + rquad + r;
        if (gr >= n) continue;
        float s = use_scale ? scale[gr] : 1.0f;
        if (out_bf16) {
            unsigned short* crow = (unsigned short*)Cout + (size_t)gr * 128;
#pragma unroll
            for (int t = 0; t < 8; ++t) crow[t * 16 + colbase] = f2bf((acc[t][r] + bvs[t]) * s);
        } else {
            float* crow = (float*)Cout + (size_t)gr * 128;
#pragma unroll
            for (int t = 0; t < 8; ++t) crow[t * 16 + colbase] = (acc[t][r] + bvs[t]) * s;
        }
    }
}

// ---------------- fused CSR gather + self-loop + bias + LayerNorm + ReLU + residual ----------------
// One wave per node; lanes = (row-slot r = lane>>4, col-group c = lane&15). Each lane loads
// ushort8 (16B) -> ONE VMEM instruction fetches 4 neighbor rows (1KB), 4x fewer instrs than
// the 256B-per-instr layout. Cross-slot shfl_xor(16,32) reduce, then c-group LN reduce.
__global__ __launch_bounds__(256) void gather_ln(const unsigned short* __restrict__ hws,
                                                 float* __restrict__ h,
                                                 const int* __restrict__ rowptr,
                                                 const int* __restrict__ csr_src,
                                                 const float* __restrict__ dinv,
                                                 const float* __restrict__ bc,
                                                 const float* __restrict__ gamma,
                                                 const float* __restrict__ beta, int n) {
    int wid = (blockIdx.x * 256 + threadIdx.x) >> 6;
    int lane = threadIdx.x & 63;
    if (wid >= n) return;
    int i = wid;
    int r = lane >> 4;   // row-slot 0..3
    int c = lane & 15;   // col-group: cols 8c..8c+7
    float di = dinv[i];
    int e0 = rowptr[i], e1 = rowptr[i + 1];

    float acc[8];
#pragma unroll
    for (int j = 0; j < 8; ++j) acc[j] = 0.0f;

    int e = e0;
    for (; e + 8 <= e1; e += 8) {
        int s0 = csr_src[e + r];
        int s1 = csr_src[e + 4 + r];
        u16x8 v0 = *(const u16x8*)(hws + (size_t)s0 * HIDDIM + c * 8);
        u16x8 v1 = *(const u16x8*)(hws + (size_t)s1 * HIDDIM + c * 8);
#pragma unroll
        for (int j = 0; j < 8; ++j) acc[j] += bf2f(v0[j]);
#pragma unroll
        for (int j = 0; j < 8; ++j) acc[j] += bf2f(v1[j]);
    }
    if (e + 4 <= e1) {
        int s0 = csr_src[e + r];
        u16x8 v0 = *(const u16x8*)(hws + (size_t)s0 * HIDDIM + c * 8);
#pragma unroll
        for (int j = 0; j < 8; ++j) acc[j] += bf2f(v0[j]);
        e += 4;
    }
    int rem = e1 - e;
    if (r < rem) {
        int s0 = csr_src[e + r];
        u16x8 v0 = *(const u16x8*)(hws + (size_t)s0 * HIDDIM + c * 8);
#pragma unroll
        for (int j = 0; j < 8; ++j) acc[j] += bf2f(v0[j]);
    }
    // reduce across the 4 row-slots (lanes differ only in bits 4..5)
#pragma unroll
    for (int j = 0; j < 8; ++j) {
        acc[j] += __shfl_xor(acc[j], 16);
        acc[j] += __shfl_xor(acc[j], 32);
    }
    // self-loop term (hws[i] is pre-scaled by dinv[i]); all r-slots identical from here on
    {
        u16x8 sv = *(const u16x8*)(hws + (size_t)i * HIDDIM + c * 8);
#pragma unroll
        for (int j = 0; j < 8; ++j) acc[j] += bf2f(sv[j]);
    }
    float4 bc0 = *(const float4*)(bc + c * 8);
    float4 bc1 = *(const float4*)(bc + c * 8 + 4);
    float v[8];
    v[0] = di * acc[0] + bc0.x; v[1] = di * acc[1] + bc0.y;
    v[2] = di * acc[2] + bc0.z; v[3] = di * acc[3] + bc0.w;
    v[4] = di * acc[4] + bc1.x; v[5] = di * acc[5] + bc1.y;
    v[6] = di * acc[6] + bc1.z; v[7] = di * acc[7] + bc1.w;

    float s1 = 0.0f, s2 = 0.0f;
#pragma unroll
    for (int j = 0; j < 8; ++j) { s1 += v[j]; s2 += v[j] * v[j]; }
#pragma unroll
    for (int off = 1; off <= 8; off <<= 1) {
        s1 += __shfl_xor(s1, off);
        s2 += __shfl_xor(s2, off);
    }
    float mu = s1 * (1.0f / 128.0f);
    float var = s2 * (1.0f / 128.0f) - mu * mu;
    float rs = 1.0f / sqrtf(var + 1e-5f);

    if (r == 0) {
        float4 gm0 = *(const float4*)(gamma + c * 8);
        float4 gm1 = *(const float4*)(gamma + c * 8 + 4);
        float4 bt0 = *(const float4*)(beta + c * 8);
        float4 bt1 = *(const float4*)(beta + c * 8 + 4);
        float gmv[8] = {gm0.x, gm0.y, gm0.z, gm0.w, gm1.x, gm1.y, gm1.z, gm1.w};
        float btv[8] = {bt0.x, bt0.y, bt0.z, bt0.w, bt1.x, bt1.y, bt1.z, bt1.w};
        float* hp = h + (size_t)i * HIDDIM + c * 8;
        float4 h0 = *(float4*)(hp);
        float4 h1 = *(float4*)(hp + 4);
        float hv[8] = {h0.x, h0.y, h0.z, h0.w, h1.x, h1.y, h1.z, h1.w};
#pragma unroll
        for (int j = 0; j < 8; ++j)
            hv[j] += fmaxf((v[j] - mu) * rs * gmv[j] + btv[j], 0.0f);
        *(float4*)(hp) = make_float4(hv[0], hv[1], hv[2], hv[3]);
        *(float4*)(hp + 4) = make_float4(hv[4], hv[5], hv[6], hv[7]);
    }
}

// ---------------- fused segmented mean-pool + MLP head (batch is SORTED) ----------------
__global__ __launch_bounds__(128) void pool_mlp_kernel(const float* __restrict__ h,
                                                       const int* __restrict__ gp,
                                                       const float* __restrict__ W1,
                                                       const float* __restrict__ b1,
                                                       const float* __restrict__ W2,
                                                       const float* __restrict__ b2,
                                                       float* __restrict__ out, int G) {
    __shared__ float sp[128];
    int g = blockIdx.x;
    if (g >= G) return;
    int t = threadIdx.x;
    int s = gp[g], e = gp[g + 1];
    float a0 = 0.0f, a1 = 0.0f;
    int i = s;
    for (; i + 2 <= e; i += 2) {
        a0 += h[(size_t)i * HIDDIM + t];
        a1 += h[(size_t)(i + 1) * HIDDIM + t];
    }
    if (i < e) a0 += h[(size_t)i * HIDDIM + t];
    float cnt = fmaxf((float)(e - s), 1.0f);
    sp[t] = (a0 + a1) / cnt;
    __syncthreads();
    if (t < 64) {
        const float* wr = W1 + t * HIDDIM;
        float a = 0.0f;
#pragma unroll 8
        for (int k = 0; k < HIDDIM; k += 4) {
            float4 p = *(const float4*)(sp + k);  // same addr all lanes -> LDS broadcast
            float4 w = *(const float4*)(wr + k);
            a += p.x * w.x + p.y * w.y + p.z * w.z + p.w * w.w;
        }
        float h1 = fmaxf(a + b1[t], 0.0f);
        float c = h1 * W2[t];
#pragma unroll
        for (int off = 32; off; off >>= 1) c += __shfl_xor(c, off);
        if (t == 0) out[g] = c + b2[0];
    }
}

extern "C" void kernel_launch(void* const* d_in, const int* in_sizes, int n_in,
                              void* d_out, int out_size, void* d_ws, size_t ws_size,
                              hipStream_t stream) {
    const float* x      = (const float*)d_in[0];
    const int*   ei     = (const int*)d_in[1];
    const int*   batch  = (const int*)d_in[2];
    const float* W_in   = (const float*)d_in[3];
    const float* b_in   = (const float*)d_in[4];
    const float* Wc     = (const float*)d_in[5];
    const float* bc     = (const float*)d_in[6];
    const float* gamma  = (const float*)d_in[7];
    const float* beta   = (const float*)d_in[8];
    const float* W1     = (const float*)d_in[9];
    const float* b1     = (const float*)d_in[10];
    const float* W2     = (const float*)d_in[11];
    const float* b2     = (const float*)d_in[12];
    float* out = (float*)d_out;

    const int N = in_sizes[2];
    const int E = in_sizes[1] / 2;
    const int G = out_size;  // OUT_DIM == 1
    const int NBUCK = (N + 127) >> 7;  // 128 nodes per bucket

    // workspace carve-up (256B aligned)
    char* ws = (char*)d_ws;
    size_t off = 0;
    auto alloc = [&](size_t bytes) {
        size_t o = off;
        off = (off + bytes + 255) & ~(size_t)255;
        return o;
    };
    int*      rowptr  = (int*)(ws + alloc((size_t)(N + 1) * 4));
    int*      csr_src = (int*)(ws + alloc((size_t)E * 4));
    float*    dinv    = (float*)(ws + alloc((size_t)N * 4));
    unsigned* ebuf    = (unsigned*)(ws + alloc((size_t)NBUCK * CAP * 4));
    int*      gcursor = (int*)(ws + alloc((size_t)NBUCK * 4));
    unsigned short* Wfrag = (unsigned short*)(ws + alloc((size_t)4 * 32768 * 2));
    float*    h       = (float*)(ws + alloc((size_t)N * 128 * 4));
    unsigned short* hws = (unsigned short*)(ws + alloc((size_t)N * 128 * 2));
    int*      gp      = (int*)(ws + alloc((size_t)(G + 1) * 4));
    (void)ws_size; (void)n_in;

    // ---- fused misc preprocessing + two-level bucket counting sort ----
    const int NBGP = (N + 255) / 256;
    const int NBPW = (4 * 16384 + 255) / 256;
    preproc_misc<<<2 + NBGP + NBPW, 256, 0, stream>>>(gcursor, NBUCK, batch, N, G, gp,
                                                      W_in, Wc, Wfrag, NBGP);
    bucket_scatter<<<(E + 2047) / 2048, 256, 0, stream>>>(ei, E, gcursor, ebuf, NBUCK);
    csr_build<<<NBUCK, 256, 0, stream>>>(ebuf, gcursor, N, NBUCK, rowptr, csr_src, dinv);

    // ---- input projection (MFMA split-bf16), fp32 out ----
    int mblocks = (N + 127) / 128;
    gemm_mfma<<<mblocks, 512, 0, stream>>>(x, Wfrag, b_in, nullptr, h, N, 1, 0, 0);

    // ---- 3 GCN layers ----
    for (int l = 0; l < 3; ++l) {
        // hws = bf16( (h @ Wc[l]^T) * dinv[row] )  (pre-scaled for the gather)
        gemm_mfma<<<mblocks, 512, 0, stream>>>(h, Wfrag + (1 + l) * 32768, nullptr, dinv,
                                               hws, N, 0, 1, 1);
        gather_ln<<<(N + 3) / 4, 256, 0, stream>>>(hws, h, rowptr, csr_src, dinv,
                                                   bc + l * 128, gamma + l * 128,
                                                   beta + l * 128, N);
    }

    // ---- fused pooling + MLP head ----
    pool_mlp_kernel<<<G, 128, 0, stream>>>(h, gp, W1, b1, W2, b2, out, G);
}

// Round 11
// 295.374 us; speedup vs baseline: 2.9321x; 1.0091x over previous
//
#include <hip/hip_runtime.h>
#include <hip/hip_bf16.h>

#define HIDDIM 128
#define CAP 4096           // slab capacity per bucket (mean fill ~2046, huge headroom)

typedef short bf16x8 __attribute__((ext_vector_type(8)));
typedef float f32x4 __attribute__((ext_vector_type(4)));
typedef unsigned short u16x8 __attribute__((ext_vector_type(8)));

__device__ inline unsigned short f2bf(float f) {
    unsigned u = __float_as_uint(f);
    unsigned r = (u + 0x7fffu + ((u >> 16) & 1u)) >> 16;  // RNE
    return (unsigned short)r;
}
__device__ inline float bf2f(unsigned short s) {
    return __uint_as_float(((unsigned)s) << 16);
}

// ---------------- fused misc preprocessing (block-partitioned) ----------------
// blocks [0,2): init gcursor; [2, 2+NBGP): graph_ptr; [2+NBGP, ...): prep_wfrag.
__global__ __launch_bounds__(256) void preproc_misc(int* __restrict__ gcursor, int nbuck,
                                                    const int* __restrict__ batch, int n, int G,
                                                    int* __restrict__ gp,
                                                    const float* __restrict__ Win,
                                                    const float* __restrict__ Wc,
                                                    unsigned short* __restrict__ Wfrag,
                                                    int nbgp) {
    int bx = blockIdx.x;
    if (bx < 2) {
        int b = bx * 256 + threadIdx.x;
        if (b < nbuck) gcursor[b] = b * CAP;
        return;
    }
    bx -= 2;
    if (bx < nbgp) {
        // graph_ptr from sorted batch: gp[g] = first node with batch >= g
        int i = bx * 256 + threadIdx.x;
        if (i >= n) return;
        int bi = batch[i];
        if (i == 0) {
            for (int g = 0; g <= bi; ++g) gp[g] = 0;
        } else {
            int bp = batch[i - 1];
            for (int g = bp + 1; g <= bi; ++g) gp[g] = i;
        }
        if (i == n - 1) {
            for (int g = bi + 1; g <= G; ++g) gp[g] = n;
        }
        return;
    }
    bx -= nbgp;
    // prep_wfrag: W -> hi/lo bf16 fragments in MFMA-ready layout.
    int gid = bx * 256 + threadIdx.x;
    if (gid >= 4 * 16384) return;
    int m = gid >> 14;
    int r = gid & 16383;
    int t = r >> 11;
    int kk = (r >> 9) & 3;
    int lane = (r >> 3) & 63;
    int j = r & 7;
    int kg = lane >> 4, oc = lane & 15;
    int o = t * 16 + oc;
    int k = kk * 32 + kg * 8 + j;
    const float* src = (m == 0) ? Win : (Wc + (m - 1) * 16384);
    float w = src[o * 128 + k];
    unsigned short hi = f2bf(w);
    unsigned short lo = f2bf(w - bf2f(hi));
    Wfrag[m * 32768 + r] = hi;
    Wfrag[m * 32768 + 16384 + r] = lo;
}

// ---------------- pass 1: bucket-scatter edges into per-bucket slabs ----------------
__global__ __launch_bounds__(256) void bucket_scatter(const int* __restrict__ ei, int E,
                                                      int* __restrict__ gcursor,
                                                      unsigned* __restrict__ ebuf, int nbuck) {
    __shared__ int lcount[512];
    __shared__ int lbase[512];
    int t = threadIdx.x;
    int cb = blockIdx.x * 2048;
    lcount[t] = 0;
    lcount[t + 256] = 0;
    __syncthreads();

    int bkt[8];
    int lpos[8];
    unsigned pk[8];
#pragma unroll
    for (int j = 0; j < 8; ++j) {
        int e = cb + j * 256 + t;
        if (e < E) {
            int s_ = ei[e];
            int d_ = ei[E + e];
            bkt[j] = d_ >> 7;
            pk[j] = ((unsigned)s_ << 7) | (unsigned)(d_ & 127);
            lpos[j] = atomicAdd(&lcount[bkt[j]], 1);
        } else {
            bkt[j] = -1;
            lpos[j] = 0;
            pk[j] = 0;
        }
    }
    __syncthreads();
    for (int bb = t; bb < nbuck; bb += 256) {
        int c = lcount[bb];
        lbase[bb] = c ? atomicAdd(&gcursor[bb], c) : 0;
    }
    __syncthreads();
#pragma unroll
    for (int j = 0; j < 8; ++j) {
        if (bkt[j] >= 0) {
            unsigned idx = (unsigned)lbase[bkt[j]] + (unsigned)lpos[j];
            if (idx < (unsigned)(bkt[j] + 1) * CAP)  // slab overflow guard (never fires)
                ebuf[idx] = pk[j];
        }
    }
}

// ---------------- pass 2: per-bucket CSR build with INLINE bucket prefix scan ----------------
__global__ __launch_bounds__(256) void csr_build(const unsigned* __restrict__ ebuf,
                                                 const int* __restrict__ gcursor,
                                                 int N, int nbuck,
                                                 int* __restrict__ rowptr,
                                                 int* __restrict__ csr_src,
                                                 float* __restrict__ dinv) {
    __shared__ int hist[128];
    __shared__ int excl[128];
    __shared__ int cur[128];
    __shared__ int wsum[4];
    __shared__ int sh_e0;
    int b = blockIdx.x;
    int t = threadIdx.x;
    // prefix of counts over buckets < b
    int partial = 0;
    for (int j = t; j < b; j += 256) {
        int c = gcursor[j] - j * CAP;
        partial += (c > CAP) ? CAP : c;
    }
#pragma unroll
    for (int off = 32; off; off >>= 1) partial += __shfl_xor(partial, off);
    if ((t & 63) == 0) wsum[t >> 6] = partial;
    if (t < 128) hist[t] = 0;
    __syncthreads();
    if (t == 0) sh_e0 = wsum[0] + wsum[1] + wsum[2] + wsum[3];
    __syncthreads();
    int e0 = sh_e0;
    int cnt = gcursor[b] - b * CAP;
    if (cnt > CAP) cnt = CAP;
    if (b == nbuck - 1 && t == 0) rowptr[N] = e0 + cnt;

    int node0 = b << 7;
    const unsigned* slab = ebuf + (size_t)b * CAP;
    for (int k = t; k < cnt; k += 256) atomicAdd(&hist[slab[k] & 127], 1);
    __syncthreads();
    if (t < 128) excl[t] = hist[t];
    __syncthreads();
    for (int off = 1; off < 128; off <<= 1) {
        int v = (t < 128 && t >= off) ? excl[t - off] : 0;
        __syncthreads();
        if (t < 128) excl[t] += v;
        __syncthreads();
    }
    if (t < 128) {
        int ex = excl[t] - hist[t];  // inclusive -> exclusive
        excl[t] = ex;
        cur[t] = ex;
    }
    __syncthreads();
    int nn = N - node0;
    if (nn > 128) nn = 128;
    if (t < nn) {
        rowptr[node0 + t] = e0 + excl[t];
        dinv[node0 + t] = 1.0f / sqrtf((float)hist[t] + 1.0f);
    }
    for (int k = t; k < cnt; k += 256) {
        unsigned p = slab[k];
        int dl = p & 127;
        int pos = atomicAdd(&cur[dl], 1);
        csr_src[e0 + pos] = (int)(p >> 7);
    }
}

// ---------------- MFMA GEMM: C[n][128] = A[n][128] @ W^T via split-bf16 ----------------
// 512 thr = 8 waves, 128 rows/block -> 64KB LDS, 2 blocks/CU = 16 waves/CU.
// two_term=0: a_hi*w_hi + a_hi*w_lo + a_lo*w_hi (error ~2^-16 rel).
// two_term=1: a_hi*(w_hi+w_lo) -- drops only the ACTIVATION low word (error ~2^-9 of |a||w|,
//             random-walked over K=128 ~ 0.003 abs; W stays ~2^-17). 64 vs 96 MFMA/wave.
__global__ __launch_bounds__(512) void gemm_mfma(const float* __restrict__ A,
                                                 const unsigned short* __restrict__ Wfrag,
                                                 const float* __restrict__ bias,
                                                 const float* __restrict__ scale,
                                                 void* __restrict__ Cout, int n, int use_bias,
                                                 int use_scale, int out_bf16, int two_term) {
    __shared__ unsigned short sB[32768];  // 64 KB: hi [0..16383], lo [16384..32767]
    int tid = threadIdx.x;
    int wave = tid >> 6;
    int lane = tid & 63;
    int wbase = blockIdx.x * 128 + wave * 16;

    {
        const float4* src = (const float4*)Wfrag;
        float4* dst = (float4*)sB;
#pragma unroll
        for (int i = 0; i < 8; ++i) dst[tid + i * 512] = src[tid + i * 512];
    }
    __syncthreads();

    f32x4 acc[8];
#pragma unroll
    for (int t = 0; t < 8; ++t) acc[t] = (f32x4){0.f, 0.f, 0.f, 0.f};

    int arow = wbase + (lane & 15);
    int kg8 = (lane >> 4) * 8;

#pragma unroll
    for (int kk = 0; kk < 4; ++kk) {
        float4 v0 = {0.f, 0.f, 0.f, 0.f}, v1 = {0.f, 0.f, 0.f, 0.f};
        if (arow < n) {
            const float* ap = A + (size_t)arow * 128 + kk * 32 + kg8;
            v0 = *(const float4*)(ap);
            v1 = *(const float4*)(ap + 4);
        }
        float fs[8] = {v0.x, v0.y, v0.z, v0.w, v1.x, v1.y, v1.z, v1.w};
        bf16x8 ahi, alo;
#pragma unroll
        for (int j = 0; j < 8; ++j) {
            unsigned short h = f2bf(fs[j]);
            ahi[j] = (short)h;
        }
        if (!two_term) {
#pragma unroll
            for (int j = 0; j < 8; ++j)
                alo[j] = (short)f2bf(fs[j] - bf2f((unsigned short)ahi[j]));
        }
#pragma unroll
        for (int t = 0; t < 8; ++t) {
            int boff = ((t * 4 + kk) * 64 + lane) * 8;  // in shorts
            bf16x8 bhi = *(const bf16x8*)(sB + boff);
            bf16x8 blo = *(const bf16x8*)(sB + 16384 + boff);
            acc[t] = __builtin_amdgcn_mfma_f32_16x16x32_bf16(ahi, bhi, acc[t], 0, 0, 0);
            acc[t] = __builtin_amdgcn_mfma_f32_16x16x32_bf16(ahi, blo, acc[t], 0, 0, 0);
            if (!two_term)
                acc[t] = __builtin_amdgcn_mfma_f32_16x16x32_bf16(alo, bhi, acc[t], 0, 0, 0);
        }
    }

    int colbase = lane & 15;
    int rquad = (lane >> 4) * 4;
    float bvs[8];
#pragma unroll
    for (int t = 0; t < 8; ++t) bvs[t] = use_bias ? bias[t * 16 + colbase] : 0.0f;
#pragma unroll
    for (int r = 0; r < 4; ++r) {
        int gr = wbase + rquad + r;
        if (gr >= n) continue;
        float s = use_scale ? scale[gr] : 1.0f;
        if (out_bf16) {
            unsigned short* crow = (unsigned short*)Cout + (size_t)gr * 128;
#pragma unroll
            for (int t = 0; t < 8; ++t) crow[t * 16 + colbase] = f2bf((acc[t][r] + bvs[t]) * s);
        } else {
            float* crow = (float*)Cout + (size_t)gr * 128;
#pragma unroll
            for (int t = 0; t < 8; ++t) crow[t * 16 + colbase] = (acc[t][r] + bvs[t]) * s;
        }
    }
}

// ---------------- fused CSR gather + self-loop + bias + LayerNorm + ReLU + residual ----------------
// At the random-request BW floor (R10 A/B: VMEM-instr reduction was perf-neutral).
__global__ __launch_bounds__(256) void gather_ln(const unsigned short* __restrict__ hws,
                                                 float* __restrict__ h,
                                                 const int* __restrict__ rowptr,
                                                 const int* __restrict__ csr_src,
                                                 const float* __restrict__ dinv,
                                                 const float* __restrict__ bc,
                                                 const float* __restrict__ gamma,
                                                 const float* __restrict__ beta, int n) {
    int wid = (blockIdx.x * 256 + threadIdx.x) >> 6;
    int lane = threadIdx.x & 63;
    if (wid >= n) return;
    int i = wid;
    int r = lane >> 4;   // row-slot 0..3
    int c = lane & 15;   // col-group: cols 8c..8c+7
    float di = dinv[i];
    int e0 = rowptr[i], e1 = rowptr[i + 1];

    float acc[8];
#pragma unroll
    for (int j = 0; j < 8; ++j) acc[j] = 0.0f;

    int e = e0;
    for (; e + 8 <= e1; e += 8) {
        int s0 = csr_src[e + r];
        int s1 = csr_src[e + 4 + r];
        u16x8 v0 = *(const u16x8*)(hws + (size_t)s0 * HIDDIM + c * 8);
        u16x8 v1 = *(const u16x8*)(hws + (size_t)s1 * HIDDIM + c * 8);
#pragma unroll
        for (int j = 0; j < 8; ++j) acc[j] += bf2f(v0[j]);
#pragma unroll
        for (int j = 0; j < 8; ++j) acc[j] += bf2f(v1[j]);
    }
    if (e + 4 <= e1) {
        int s0 = csr_src[e + r];
        u16x8 v0 = *(const u16x8*)(hws + (size_t)s0 * HIDDIM + c * 8);
#pragma unroll
        for (int j = 0; j < 8; ++j) acc[j] += bf2f(v0[j]);
        e += 4;
    }
    int rem = e1 - e;
    if (r < rem) {
        int s0 = csr_src[e + r];
        u16x8 v0 = *(const u16x8*)(hws + (size_t)s0 * HIDDIM + c * 8);
#pragma unroll
        for (int j = 0; j < 8; ++j) acc[j] += bf2f(v0[j]);
    }
    // reduce across the 4 row-slots (lanes differ only in bits 4..5)
#pragma unroll
    for (int j = 0; j < 8; ++j) {
        acc[j] += __shfl_xor(acc[j], 16);
        acc[j] += __shfl_xor(acc[j], 32);
    }
    // self-loop term (hws[i] is pre-scaled by dinv[i]); all r-slots identical from here on
    {
        u16x8 sv = *(const u16x8*)(hws + (size_t)i * HIDDIM + c * 8);
#pragma unroll
        for (int j = 0; j < 8; ++j) acc[j] += bf2f(sv[j]);
    }
    float4 bc0 = *(const float4*)(bc + c * 8);
    float4 bc1 = *(const float4*)(bc + c * 8 + 4);
    float v[8];
    v[0] = di * acc[0] + bc0.x; v[1] = di * acc[1] + bc0.y;
    v[2] = di * acc[2] + bc0.z; v[3] = di * acc[3] + bc0.w;
    v[4] = di * acc[4] + bc1.x; v[5] = di * acc[5] + bc1.y;
    v[6] = di * acc[6] + bc1.z; v[7] = di * acc[7] + bc1.w;

    float s1 = 0.0f, s2 = 0.0f;
#pragma unroll
    for (int j = 0; j < 8; ++j) { s1 += v[j]; s2 += v[j] * v[j]; }
#pragma unroll
    for (int off = 1; off <= 8; off <<= 1) {
        s1 += __shfl_xor(s1, off);
        s2 += __shfl_xor(s2, off);
    }
    float mu = s1 * (1.0f / 128.0f);
    float var = s2 * (1.0f / 128.0f) - mu * mu;
    float rs = 1.0f / sqrtf(var + 1e-5f);

    if (r == 0) {
        float4 gm0 = *(const float4*)(gamma + c * 8);
        float4 gm1 = *(const float4*)(gamma + c * 8 + 4);
        float4 bt0 = *(const float4*)(beta + c * 8);
        float4 bt1 = *(const float4*)(beta + c * 8 + 4);
        float gmv[8] = {gm0.x, gm0.y, gm0.z, gm0.w, gm1.x, gm1.y, gm1.z, gm1.w};
        float btv[8] = {bt0.x, bt0.y, bt0.z, bt0.w, bt1.x, bt1.y, bt1.z, bt1.w};
        float* hp = h + (size_t)i * HIDDIM + c * 8;
        float4 h0 = *(float4*)(hp);
        float4 h1 = *(float4*)(hp + 4);
        float hv[8] = {h0.x, h0.y, h0.z, h0.w, h1.x, h1.y, h1.z, h1.w};
#pragma unroll
        for (int j = 0; j < 8; ++j)
            hv[j] += fmaxf((v[j] - mu) * rs * gmv[j] + btv[j], 0.0f);
        *(float4*)(hp) = make_float4(hv[0], hv[1], hv[2], hv[3]);
        *(float4*)(hp + 4) = make_float4(hv[4], hv[5], hv[6], hv[7]);
    }
}

// ---------------- fused segmented mean-pool + MLP head (batch is SORTED) ----------------
__global__ __launch_bounds__(128) void pool_mlp_kernel(const float* __restrict__ h,
                                                       const int* __restrict__ gp,
                                                       const float* __restrict__ W1,
                                                       const float* __restrict__ b1,
                                                       const float* __restrict__ W2,
                                                       const float* __restrict__ b2,
                                                       float* __restrict__ out, int G) {
    __shared__ float sp[128];
    int g = blockIdx.x;
    if (g >= G) return;
    int t = threadIdx.x;
    int s = gp[g], e = gp[g + 1];
    float a0 = 0.0f, a1 = 0.0f;
    int i = s;
    for (; i + 2 <= e; i += 2) {
        a0 += h[(size_t)i * HIDDIM + t];
        a1 += h[(size_t)(i + 1) * HIDDIM + t];
    }
    if (i < e) a0 += h[(size_t)i * HIDDIM + t];
    float cnt = fmaxf((float)(e - s), 1.0f);
    sp[t] = (a0 + a1) / cnt;
    __syncthreads();
    if (t < 64) {
        const float* wr = W1 + t * HIDDIM;
        float a = 0.0f;
#pragma unroll 8
        for (int k = 0; k < HIDDIM; k += 4) {
            float4 p = *(const float4*)(sp + k);  // same addr all lanes -> LDS broadcast
            float4 w = *(const float4*)(wr + k);
            a += p.x * w.x + p.y * w.y + p.z * w.z + p.w * w.w;
        }
        float h1 = fmaxf(a + b1[t], 0.0f);
        float c = h1 * W2[t];
#pragma unroll
        for (int off = 32; off; off >>= 1) c += __shfl_xor(c, off);
        if (t == 0) out[g] = c + b2[0];
    }
}

extern "C" void kernel_launch(void* const* d_in, const int* in_sizes, int n_in,
                              void* d_out, int out_size, void* d_ws, size_t ws_size,
                              hipStream_t stream) {
    const float* x      = (const float*)d_in[0];
    const int*   ei     = (const int*)d_in[1];
    const int*   batch  = (const int*)d_in[2];
    const float* W_in   = (const float*)d_in[3];
    const float* b_in   = (const float*)d_in[4];
    const float* Wc     = (const float*)d_in[5];
    const float* bc     = (const float*)d_in[6];
    const float* gamma  = (const float*)d_in[7];
    const float* beta   = (const float*)d_in[8];
    const float* W1     = (const float*)d_in[9];
    const float* b1     = (const float*)d_in[10];
    const float* W2     = (const float*)d_in[11];
    const float* b2     = (const float*)d_in[12];
    float* out = (float*)d_out;

    const int N = in_sizes[2];
    const int E = in_sizes[1] / 2;
    const int G = out_size;  // OUT_DIM == 1
    const int NBUCK = (N + 127) >> 7;  // 128 nodes per bucket

    // workspace carve-up (256B aligned)
    char* ws = (char*)d_ws;
    size_t off = 0;
    auto alloc = [&](size_t bytes) {
        size_t o = off;
        off = (off + bytes + 255) & ~(size_t)255;
        return o;
    };
    int*      rowptr  = (int*)(ws + alloc((size_t)(N + 1) * 4));
    int*      csr_src = (int*)(ws + alloc((size_t)E * 4));
    float*    dinv    = (float*)(ws + alloc((size_t)N * 4));
    unsigned* ebuf    = (unsigned*)(ws + alloc((size_t)NBUCK * CAP * 4));
    int*      gcursor = (int*)(ws + alloc((size_t)NBUCK * 4));
    unsigned short* Wfrag = (unsigned short*)(ws + alloc((size_t)4 * 32768 * 2));
    float*    h       = (float*)(ws + alloc((size_t)N * 128 * 4));
    unsigned short* hws = (unsigned short*)(ws + alloc((size_t)N * 128 * 2));
    int*      gp      = (int*)(ws + alloc((size_t)(G + 1) * 4));
    (void)ws_size; (void)n_in;

    // ---- fused misc preprocessing + two-level bucket counting sort ----
    const int NBGP = (N + 255) / 256;
    const int NBPW = (4 * 16384 + 255) / 256;
    preproc_misc<<<2 + NBGP + NBPW, 256, 0, stream>>>(gcursor, NBUCK, batch, N, G, gp,
                                                      W_in, Wc, Wfrag, NBGP);
    bucket_scatter<<<(E + 2047) / 2048, 256, 0, stream>>>(ei, E, gcursor, ebuf, NBUCK);
    csr_build<<<NBUCK, 256, 0, stream>>>(ebuf, gcursor, N, NBUCK, rowptr, csr_src, dinv);

    // ---- input projection (MFMA split-bf16, 3-term), fp32 out ----
    int mblocks = (N + 127) / 128;
    gemm_mfma<<<mblocks, 512, 0, stream>>>(x, Wfrag, b_in, nullptr, h, N, 1, 0, 0, 0);

    // ---- 3 GCN layers (2-term layer gemms) ----
    for (int l = 0; l < 3; ++l) {
        // hws = bf16( (h @ Wc[l]^T) * dinv[row] )  (pre-scaled for the gather)
        gemm_mfma<<<mblocks, 512, 0, stream>>>(h, Wfrag + (1 + l) * 32768, nullptr, dinv,
                                               hws, N, 0, 1, 1, 1);
        gather_ln<<<(N + 3) / 4, 256, 0, stream>>>(hws, h, rowptr, csr_src, dinv,
                                                   bc + l * 128, gamma + l * 128,
                                                   beta + l * 128, N);
    }

    // ---- fused pooling + MLP head ----
    pool_mlp_kernel<<<G, 128, 0, stream>>>(h, gp, W1, b1, W2, b2, out, G);
}

// Round 12
// 292.410 us; speedup vs baseline: 2.9618x; 1.0101x over previous
//
#include <hip/hip_runtime.h>
#include <hip/hip_bf16.h>

#define HIDDIM 128
#define CAP 4096           // slab capacity per bucket (mean fill ~2046, huge headroom)

typedef short bf16x8 __attribute__((ext_vector_type(8)));
typedef float f32x4 __attribute__((ext_vector_type(4)));
typedef unsigned short u16x8 __attribute__((ext_vector_type(8)));

__device__ inline unsigned short f2bf(float f) {
    unsigned u = __float_as_uint(f);
    unsigned r = (u + 0x7fffu + ((u >> 16) & 1u)) >> 16;  // RNE
    return (unsigned short)r;
}
__device__ inline float bf2f(unsigned short s) {
    return __uint_as_float(((unsigned)s) << 16);
}

// ---------------- fused misc preprocessing (block-partitioned) ----------------
// blocks [0,2): init gcursor; [2, 2+NBGP): graph_ptr; [2+NBGP, ...): prep_wfrag.
__global__ __launch_bounds__(256) void preproc_misc(int* __restrict__ gcursor, int nbuck,
                                                    const int* __restrict__ batch, int n, int G,
                                                    int* __restrict__ gp,
                                                    const float* __restrict__ Win,
                                                    const float* __restrict__ Wc,
                                                    unsigned short* __restrict__ Wfrag,
                                                    int nbgp) {
    int bx = blockIdx.x;
    if (bx < 2) {
        int b = bx * 256 + threadIdx.x;
        if (b < nbuck) gcursor[b] = b * CAP;
        return;
    }
    bx -= 2;
    if (bx < nbgp) {
        // graph_ptr from sorted batch: gp[g] = first node with batch >= g
        int i = bx * 256 + threadIdx.x;
        if (i >= n) return;
        int bi = batch[i];
        if (i == 0) {
            for (int g = 0; g <= bi; ++g) gp[g] = 0;
        } else {
            int bp = batch[i - 1];
            for (int g = bp + 1; g <= bi; ++g) gp[g] = i;
        }
        if (i == n - 1) {
            for (int g = bi + 1; g <= G; ++g) gp[g] = n;
        }
        return;
    }
    bx -= nbgp;
    // prep_wfrag: W -> hi/lo bf16 fragments in MFMA-ready layout.
    int gid = bx * 256 + threadIdx.x;
    if (gid >= 4 * 16384) return;
    int m = gid >> 14;
    int r = gid & 16383;
    int t = r >> 11;
    int kk = (r >> 9) & 3;
    int lane = (r >> 3) & 63;
    int j = r & 7;
    int kg = lane >> 4, oc = lane & 15;
    int o = t * 16 + oc;
    int k = kk * 32 + kg * 8 + j;
    const float* src = (m == 0) ? Win : (Wc + (m - 1) * 16384);
    float w = src[o * 128 + k];
    unsigned short hi = f2bf(w);
    unsigned short lo = f2bf(w - bf2f(hi));
    Wfrag[m * 32768 + r] = hi;
    Wfrag[m * 32768 + 16384 + r] = lo;
}

// ---------------- pass 1: bucket-scatter edges into per-bucket slabs ----------------
__global__ __launch_bounds__(256) void bucket_scatter(const int* __restrict__ ei, int E,
                                                      int* __restrict__ gcursor,
                                                      unsigned* __restrict__ ebuf, int nbuck) {
    __shared__ int lcount[512];
    __shared__ int lbase[512];
    int t = threadIdx.x;
    int cb = blockIdx.x * 2048;
    lcount[t] = 0;
    lcount[t + 256] = 0;
    __syncthreads();

    int bkt[8];
    int lpos[8];
    unsigned pk[8];
#pragma unroll
    for (int j = 0; j < 8; ++j) {
        int e = cb + j * 256 + t;
        if (e < E) {
            int s_ = ei[e];
            int d_ = ei[E + e];
            bkt[j] = d_ >> 7;
            pk[j] = ((unsigned)s_ << 7) | (unsigned)(d_ & 127);
            lpos[j] = atomicAdd(&lcount[bkt[j]], 1);
        } else {
            bkt[j] = -1;
            lpos[j] = 0;
            pk[j] = 0;
        }
    }
    __syncthreads();
    for (int bb = t; bb < nbuck; bb += 256) {
        int c = lcount[bb];
        lbase[bb] = c ? atomicAdd(&gcursor[bb], c) : 0;
    }
    __syncthreads();
#pragma unroll
    for (int j = 0; j < 8; ++j) {
        if (bkt[j] >= 0) {
            unsigned idx = (unsigned)lbase[bkt[j]] + (unsigned)lpos[j];
            if (idx < (unsigned)(bkt[j] + 1) * CAP)  // slab overflow guard (never fires)
                ebuf[idx] = pk[j];
        }
    }
}

// ---------------- pass 2: per-bucket CSR build with INLINE bucket prefix scan ----------------
__global__ __launch_bounds__(256) void csr_build(const unsigned* __restrict__ ebuf,
                                                 const int* __restrict__ gcursor,
                                                 int N, int nbuck,
                                                 int* __restrict__ rowptr,
                                                 int* __restrict__ csr_src,
                                                 float* __restrict__ dinv) {
    __shared__ int hist[128];
    __shared__ int excl[128];
    __shared__ int cur[128];
    __shared__ int wsum[4];
    __shared__ int sh_e0;
    int b = blockIdx.x;
    int t = threadIdx.x;
    // prefix of counts over buckets < b
    int partial = 0;
    for (int j = t; j < b; j += 256) {
        int c = gcursor[j] - j * CAP;
        partial += (c > CAP) ? CAP : c;
    }
#pragma unroll
    for (int off = 32; off; off >>= 1) partial += __shfl_xor(partial, off);
    if ((t & 63) == 0) wsum[t >> 6] = partial;
    if (t < 128) hist[t] = 0;
    __syncthreads();
    if (t == 0) sh_e0 = wsum[0] + wsum[1] + wsum[2] + wsum[3];
    __syncthreads();
    int e0 = sh_e0;
    int cnt = gcursor[b] - b * CAP;
    if (cnt > CAP) cnt = CAP;
    if (b == nbuck - 1 && t == 0) rowptr[N] = e0 + cnt;

    int node0 = b << 7;
    const unsigned* slab = ebuf + (size_t)b * CAP;
    for (int k = t; k < cnt; k += 256) atomicAdd(&hist[slab[k] & 127], 1);
    __syncthreads();
    if (t < 128) excl[t] = hist[t];
    __syncthreads();
    for (int off = 1; off < 128; off <<= 1) {
        int v = (t < 128 && t >= off) ? excl[t - off] : 0;
        __syncthreads();
        if (t < 128) excl[t] += v;
        __syncthreads();
    }
    if (t < 128) {
        int ex = excl[t] - hist[t];  // inclusive -> exclusive
        excl[t] = ex;
        cur[t] = ex;
    }
    __syncthreads();
    int nn = N - node0;
    if (nn > 128) nn = 128;
    if (t < nn) {
        rowptr[node0 + t] = e0 + excl[t];
        dinv[node0 + t] = 1.0f / sqrtf((float)hist[t] + 1.0f);
    }
    for (int k = t; k < cnt; k += 256) {
        unsigned p = slab[k];
        int dl = p & 127;
        int pos = atomicAdd(&cur[dl], 1);
        csr_src[e0 + pos] = (int)(p >> 7);
    }
}

// ---------------- MFMA GEMM: C[n][128] = A[n][128] @ W^T via split-bf16 ----------------
// 512 thr = 8 waves, 128 rows/block -> 64KB LDS, 2 blocks/CU = 16 waves/CU.
// in_bf16=1: A rows are bf16 (the residual stream h) -> a is EXACTLY representable;
//            acc = a*w_hi + a*w_lo is exact w.r.t. stored A. 64 MFMA/wave.
// in_bf16=0 (fp32 A): two_term=0 -> + a_lo*w_hi 3-term split (~2^-16 rel).
__global__ __launch_bounds__(512) void gemm_mfma(const void* __restrict__ Ain,
                                                 const unsigned short* __restrict__ Wfrag,
                                                 const float* __restrict__ bias,
                                                 const float* __restrict__ scale,
                                                 void* __restrict__ Cout, int n, int use_bias,
                                                 int use_scale, int out_bf16, int two_term,
                                                 int in_bf16) {
    __shared__ unsigned short sB[32768];  // 64 KB: hi [0..16383], lo [16384..32767]
    int tid = threadIdx.x;
    int wave = tid >> 6;
    int lane = tid & 63;
    int wbase = blockIdx.x * 128 + wave * 16;

    {
        const float4* src = (const float4*)Wfrag;
        float4* dst = (float4*)sB;
#pragma unroll
        for (int i = 0; i < 8; ++i) dst[tid + i * 512] = src[tid + i * 512];
    }
    __syncthreads();

    f32x4 acc[8];
#pragma unroll
    for (int t = 0; t < 8; ++t) acc[t] = (f32x4){0.f, 0.f, 0.f, 0.f};

    int arow = wbase + (lane & 15);
    int kg8 = (lane >> 4) * 8;

#pragma unroll
    for (int kk = 0; kk < 4; ++kk) {
        bf16x8 ahi, alo;
        bool have_lo = false;
        if (in_bf16) {
            u16x8 av = {0, 0, 0, 0, 0, 0, 0, 0};
            if (arow < n)
                av = *(const u16x8*)((const unsigned short*)Ain + (size_t)arow * 128 +
                                     kk * 32 + kg8);
#pragma unroll
            for (int j = 0; j < 8; ++j) ahi[j] = (short)av[j];
        } else {
            float4 v0 = {0.f, 0.f, 0.f, 0.f}, v1 = {0.f, 0.f, 0.f, 0.f};
            if (arow < n) {
                const float* ap = (const float*)Ain + (size_t)arow * 128 + kk * 32 + kg8;
                v0 = *(const float4*)(ap);
                v1 = *(const float4*)(ap + 4);
            }
            float fs[8] = {v0.x, v0.y, v0.z, v0.w, v1.x, v1.y, v1.z, v1.w};
#pragma unroll
            for (int j = 0; j < 8; ++j) {
                unsigned short h = f2bf(fs[j]);
                ahi[j] = (short)h;
            }
            if (!two_term) {
                have_lo = true;
#pragma unroll
                for (int j = 0; j < 8; ++j)
                    alo[j] = (short)f2bf(fs[j] - bf2f((unsigned short)ahi[j]));
            }
        }
#pragma unroll
        for (int t = 0; t < 8; ++t) {
            int boff = ((t * 4 + kk) * 64 + lane) * 8;  // in shorts
            bf16x8 bhi = *(const bf16x8*)(sB + boff);
            bf16x8 blo = *(const bf16x8*)(sB + 16384 + boff);
            acc[t] = __builtin_amdgcn_mfma_f32_16x16x32_bf16(ahi, bhi, acc[t], 0, 0, 0);
            acc[t] = __builtin_amdgcn_mfma_f32_16x16x32_bf16(ahi, blo, acc[t], 0, 0, 0);
            if (have_lo)
                acc[t] = __builtin_amdgcn_mfma_f32_16x16x32_bf16(alo, bhi, acc[t], 0, 0, 0);
        }
    }

    int colbase = lane & 15;
    int rquad = (lane >> 4) * 4;
    float bvs[8];
#pragma unroll
    for (int t = 0; t < 8; ++t) bvs[t] = use_bias ? bias[t * 16 + colbase] : 0.0f;
#pragma unroll
    for (int r = 0; r < 4; ++r) {
        int gr = wbase + rquad + r;
        if (gr >= n) continue;
        float s = use_scale ? scale[gr] : 1.0f;
        if (out_bf16) {
            unsigned short* crow = (unsigned short*)Cout + (size_t)gr * 128;
#pragma unroll
            for (int t = 0; t < 8; ++t) crow[t * 16 + colbase] = f2bf((acc[t][r] + bvs[t]) * s);
        } else {
            float* crow = (float*)Cout + (size_t)gr * 128;
#pragma unroll
            for (int t = 0; t < 8; ++t) crow[t * 16 + colbase] = (acc[t][r] + bvs[t]) * s;
        }
    }
}

// ---------------- fused CSR gather + self-loop + bias + LayerNorm + ReLU + residual ----------------
// At the random-request BW floor for hws (R10 A/B). h residual stream is now bf16:
// halves the h read+write traffic. fp32 accumulation/LN throughout.
__global__ __launch_bounds__(256) void gather_ln(const unsigned short* __restrict__ hws,
                                                 unsigned short* __restrict__ h,
                                                 const int* __restrict__ rowptr,
                                                 const int* __restrict__ csr_src,
                                                 const float* __restrict__ dinv,
                                                 const float* __restrict__ bc,
                                                 const float* __restrict__ gamma,
                                                 const float* __restrict__ beta, int n) {
    int wid = (blockIdx.x * 256 + threadIdx.x) >> 6;
    int lane = threadIdx.x & 63;
    if (wid >= n) return;
    int i = wid;
    int r = lane >> 4;   // row-slot 0..3
    int c = lane & 15;   // col-group: cols 8c..8c+7
    float di = dinv[i];
    int e0 = rowptr[i], e1 = rowptr[i + 1];

    float acc[8];
#pragma unroll
    for (int j = 0; j < 8; ++j) acc[j] = 0.0f;

    int e = e0;
    for (; e + 8 <= e1; e += 8) {
        int s0 = csr_src[e + r];
        int s1 = csr_src[e + 4 + r];
        u16x8 v0 = *(const u16x8*)(hws + (size_t)s0 * HIDDIM + c * 8);
        u16x8 v1 = *(const u16x8*)(hws + (size_t)s1 * HIDDIM + c * 8);
#pragma unroll
        for (int j = 0; j < 8; ++j) acc[j] += bf2f(v0[j]);
#pragma unroll
        for (int j = 0; j < 8; ++j) acc[j] += bf2f(v1[j]);
    }
    if (e + 4 <= e1) {
        int s0 = csr_src[e + r];
        u16x8 v0 = *(const u16x8*)(hws + (size_t)s0 * HIDDIM + c * 8);
#pragma unroll
        for (int j = 0; j < 8; ++j) acc[j] += bf2f(v0[j]);
        e += 4;
    }
    int rem = e1 - e;
    if (r < rem) {
        int s0 = csr_src[e + r];
        u16x8 v0 = *(const u16x8*)(hws + (size_t)s0 * HIDDIM + c * 8);
#pragma unroll
        for (int j = 0; j < 8; ++j) acc[j] += bf2f(v0[j]);
    }
    // reduce across the 4 row-slots (lanes differ only in bits 4..5)
#pragma unroll
    for (int j = 0; j < 8; ++j) {
        acc[j] += __shfl_xor(acc[j], 16);
        acc[j] += __shfl_xor(acc[j], 32);
    }
    // self-loop term (hws[i] is pre-scaled by dinv[i]); all r-slots identical from here on
    {
        u16x8 sv = *(const u16x8*)(hws + (size_t)i * HIDDIM + c * 8);
#pragma unroll
        for (int j = 0; j < 8; ++j) acc[j] += bf2f(sv[j]);
    }
    float4 bc0 = *(const float4*)(bc + c * 8);
    float4 bc1 = *(const float4*)(bc + c * 8 + 4);
    float v[8];
    v[0] = di * acc[0] + bc0.x; v[1] = di * acc[1] + bc0.y;
    v[2] = di * acc[2] + bc0.z; v[3] = di * acc[3] + bc0.w;
    v[4] = di * acc[4] + bc1.x; v[5] = di * acc[5] + bc1.y;
    v[6] = di * acc[6] + bc1.z; v[7] = di * acc[7] + bc1.w;

    float s1 = 0.0f, s2 = 0.0f;
#pragma unroll
    for (int j = 0; j < 8; ++j) { s1 += v[j]; s2 += v[j] * v[j]; }
#pragma unroll
    for (int off = 1; off <= 8; off <<= 1) {
        s1 += __shfl_xor(s1, off);
        s2 += __shfl_xor(s2, off);
    }
    float mu = s1 * (1.0f / 128.0f);
    float var = s2 * (1.0f / 128.0f) - mu * mu;
    float rs = 1.0f / sqrtf(var + 1e-5f);

    if (r == 0) {
        float4 gm0 = *(const float4*)(gamma + c * 8);
        float4 gm1 = *(const float4*)(gamma + c * 8 + 4);
        float4 bt0 = *(const float4*)(beta + c * 8);
        float4 bt1 = *(const float4*)(beta + c * 8 + 4);
        float gmv[8] = {gm0.x, gm0.y, gm0.z, gm0.w, gm1.x, gm1.y, gm1.z, gm1.w};
        float btv[8] = {bt0.x, bt0.y, bt0.z, bt0.w, bt1.x, bt1.y, bt1.z, bt1.w};
        unsigned short* hp = h + (size_t)i * HIDDIM + c * 8;
        u16x8 h8 = *(const u16x8*)hp;
        u16x8 o8;
#pragma unroll
        for (int j = 0; j < 8; ++j) {
            float hv = bf2f(h8[j]) + fmaxf((v[j] - mu) * rs * gmv[j] + btv[j], 0.0f);
            o8[j] = f2bf(hv);
        }
        *(u16x8*)hp = o8;
    }
}

// ---------------- fused segmented mean-pool + MLP head (batch is SORTED; h is bf16) ----------------
__global__ __launch_bounds__(128) void pool_mlp_kernel(const unsigned short* __restrict__ h,
                                                       const int* __restrict__ gp,
                                                       const float* __restrict__ W1,
                                                       const float* __restrict__ b1,
                                                       const float* __restrict__ W2,
                                                       const float* __restrict__ b2,
                                                       float* __restrict__ out, int G) {
    __shared__ float sp[128];
    int g = blockIdx.x;
    if (g >= G) return;
    int t = threadIdx.x;
    int s = gp[g], e = gp[g + 1];
    float a0 = 0.0f, a1 = 0.0f;
    int i = s;
    for (; i + 2 <= e; i += 2) {
        a0 += bf2f(h[(size_t)i * HIDDIM + t]);
        a1 += bf2f(h[(size_t)(i + 1) * HIDDIM + t]);
    }
    if (i < e) a0 += bf2f(h[(size_t)i * HIDDIM + t]);
    float cnt = fmaxf((float)(e - s), 1.0f);
    sp[t] = (a0 + a1) / cnt;
    __syncthreads();
    if (t < 64) {
        const float* wr = W1 + t * HIDDIM;
        float a = 0.0f;
#pragma unroll 8
        for (int k = 0; k < HIDDIM; k += 4) {
            float4 p = *(const float4*)(sp + k);  // same addr all lanes -> LDS broadcast
            float4 w = *(const float4*)(wr + k);
            a += p.x * w.x + p.y * w.y + p.z * w.z + p.w * w.w;
        }
        float h1 = fmaxf(a + b1[t], 0.0f);
        float c = h1 * W2[t];
#pragma unroll
        for (int off = 32; off; off >>= 1) c += __shfl_xor(c, off);
        if (t == 0) out[g] = c + b2[0];
    }
}

extern "C" void kernel_launch(void* const* d_in, const int* in_sizes, int n_in,
                              void* d_out, int out_size, void* d_ws, size_t ws_size,
                              hipStream_t stream) {
    const float* x      = (const float*)d_in[0];
    const int*   ei     = (const int*)d_in[1];
    const int*   batch  = (const int*)d_in[2];
    const float* W_in   = (const float*)d_in[3];
    const float* b_in   = (const float*)d_in[4];
    const float* Wc     = (const float*)d_in[5];
    const float* bc     = (const float*)d_in[6];
    const float* gamma  = (const float*)d_in[7];
    const float* beta   = (const float*)d_in[8];
    const float* W1     = (const float*)d_in[9];
    const float* b1     = (const float*)d_in[10];
    const float* W2     = (const float*)d_in[11];
    const float* b2     = (const float*)d_in[12];
    float* out = (float*)d_out;

    const int N = in_sizes[2];
    const int E = in_sizes[1] / 2;
    const int G = out_size;  // OUT_DIM == 1
    const int NBUCK = (N + 127) >> 7;  // 128 nodes per bucket

    // workspace carve-up (256B aligned)
    char* ws = (char*)d_ws;
    size_t off = 0;
    auto alloc = [&](size_t bytes) {
        size_t o = off;
        off = (off + bytes + 255) & ~(size_t)255;
        return o;
    };
    int*      rowptr  = (int*)(ws + alloc((size_t)(N + 1) * 4));
    int*      csr_src = (int*)(ws + alloc((size_t)E * 4));
    float*    dinv    = (float*)(ws + alloc((size_t)N * 4));
    unsigned* ebuf    = (unsigned*)(ws + alloc((size_t)NBUCK * CAP * 4));
    int*      gcursor = (int*)(ws + alloc((size_t)NBUCK * 4));
    unsigned short* Wfrag = (unsigned short*)(ws + alloc((size_t)4 * 32768 * 2));
    unsigned short* h   = (unsigned short*)(ws + alloc((size_t)N * 128 * 2));
    unsigned short* hws = (unsigned short*)(ws + alloc((size_t)N * 128 * 2));
    int*      gp      = (int*)(ws + alloc((size_t)(G + 1) * 4));
    (void)ws_size; (void)n_in;

    // ---- fused misc preprocessing + two-level bucket counting sort ----
    const int NBGP = (N + 255) / 256;
    const int NBPW = (4 * 16384 + 255) / 256;
    preproc_misc<<<2 + NBGP + NBPW, 256, 0, stream>>>(gcursor, NBUCK, batch, N, G, gp,
                                                      W_in, Wc, Wfrag, NBGP);
    bucket_scatter<<<(E + 2047) / 2048, 256, 0, stream>>>(ei, E, gcursor, ebuf, NBUCK);
    csr_build<<<NBUCK, 256, 0, stream>>>(ebuf, gcursor, N, NBUCK, rowptr, csr_src, dinv);

    // ---- input projection (fp32 in, 3-term split), h out in bf16 ----
    int mblocks = (N + 127) / 128;
    gemm_mfma<<<mblocks, 512, 0, stream>>>(x, Wfrag, b_in, nullptr, h, N, 1, 0, 1, 0, 0);

    // ---- 3 GCN layers (bf16 in -> exact 2-term layer gemms) ----
    for (int l = 0; l < 3; ++l) {
        // hws = bf16( (h @ Wc[l]^T) * dinv[row] )  (pre-scaled for the gather)
        gemm_mfma<<<mblocks, 512, 0, stream>>>(h, Wfrag + (1 + l) * 32768, nullptr, dinv,
                                               hws, N, 0, 1, 1, 1, 1);
        gather_ln<<<(N + 3) / 4, 256, 0, stream>>>(hws, h, rowptr, csr_src, dinv,
                                                   bc + l * 128, gamma + l * 128,
                                                   beta + l * 128, N);
    }

    // ---- fused pooling + MLP head ----
    pool_mlp_kernel<<<G, 128, 0, stream>>>(h, gp, W1, b1, W2, b2, out, G);
}